// Round 3
// baseline (30157.666 us; speedup 1.0000x reference)
//
#include <hip/hip_runtime.h>
#include <hip/hip_bf16.h>
#include <math.h>

// ---------------- constants ----------------
#define BB 128
#define FF 243
#define JJ 17
#define ERR 32
#define EE 544
#define NHH 8
#define HDD 68
#define HIDD 1088
#define ROWS 31104          // B*F
#define QSTRIDE 16920576ULL // ROWS*EE

typedef __hip_bfloat16 bf16;
static __device__ __forceinline__ float b2f(bf16 v) { return __bfloat162float(v); }
static __device__ __forceinline__ bf16 f2b(float v) { return __float2bfloat16(v); }

// ---------------- adjacency softmax precompute ----------------
__global__ void computeA_kernel(const float* __restrict__ gc_e, float* __restrict__ A)
{
    __shared__ float a1[17][17], a2[17][17], a3[17][17];
    int tid = threadIdx.x;
    const int parents[17] = {-1,0,1,2,0,4,5,0,7,8,9,8,11,12,8,14,15};
    if (tid == 0) {
        for (int i=0;i<17;++i) for (int j=0;j<17;++j) a1[i][j]=0.f;
        for (int c=0;c<17;++c){ int p=parents[c]; if(p>=0){ a1[c][p]=1.f; a1[p][c]=1.f; } }
        for (int i=0;i<17;++i) for (int j=0;j<17;++j){ float s=0; for(int k=0;k<17;++k) s+=a1[i][k]*a1[k][j]; a2[i][j]=s; }
        for (int i=0;i<17;++i) for (int j=0;j<17;++j){ float s=0; for(int k=0;k<17;++k) s+=a2[i][k]*a1[k][j]; a3[i][j]=s; }
    }
    __syncthreads();
    for (int p = tid; p < 68; p += 64) {
        int n = p / 17, i = p % 17;
        bool msk[17];
        float m = -1e30f;
        for (int j=0;j<17;++j) {
            bool mm;
            if (n==0) mm = (i==j);
            else if (n==1) mm = a1[i][j] > 0.f;
            else if (n==2) mm = a2[i][j] > 0.f;
            else mm = a3[i][j] > 0.f;
            msk[j] = mm;
            if (mm) m = fmaxf(m, gc_e[(n*17+i)*17+j]);
        }
        float ex[17]; float s=0.f;
        for (int j=0;j<17;++j){ ex[j] = msk[j] ? expf(gc_e[(n*17+i)*17+j]-m) : 0.f; s+=ex[j]; }
        float inv = 1.f/s;
        for (int j=0;j<17;++j) A[(n*17+i)*17+j] = ex[j]*inv;
    }
}

// ---------------- fused graph conv (one block per token row) ----------------
__global__ __launch_bounds__(128) void gc_kernel(
    const float* __restrict__ x, const float* __restrict__ A,
    const float* __restrict__ gc_W, const float* __restrict__ gc_bias,
    const float* __restrict__ qw, const float* __restrict__ qb,
    const float* __restrict__ kw, const float* __restrict__ kb,
    const float* __restrict__ aw, const float* __restrict__ ab,
    const float* __restrict__ lng, const float* __restrict__ lnb,
    const float* __restrict__ pos_embed,
    float* __restrict__ xe)
{
    __shared__ float xf[34];
    __shared__ float As[4][17][17];
    __shared__ float Ws[4][2][32];
    __shared__ float h[4][17][32];
    __shared__ float outs[17][4][32];
    __shared__ float qws[32][32], kws[32][32];
    __shared__ float sc[17][4];
    __shared__ float wsoft[17][4];
    int r = blockIdx.x, tid = threadIdx.x;

    for (int i = tid; i < 34; i += 128) xf[i] = x[(size_t)r*34 + i];
    for (int i = tid; i < 1156; i += 128) ((float*)As)[i] = A[i];
    for (int i = tid; i < 256; i += 128) ((float*)Ws)[i] = gc_W[i];
    for (int i = tid; i < 1024; i += 128) { ((float*)qws)[i] = qw[i]; ((float*)kws)[i] = kw[i]; }
    __syncthreads();

    for (int idx = tid; idx < 2176; idx += 128) {      // h[n][j][o]
        int n = idx / 544, j = (idx / 32) % 17, o = idx & 31;
        h[n][j][o] = xf[j*2+0]*Ws[n][0][o] + xf[j*2+1]*Ws[n][1][o];
    }
    __syncthreads();
    for (int idx = tid; idx < 2176; idx += 128) {      // outs[i][n][o]
        int i0 = idx / 128, n = (idx / 32) & 3, o = idx & 31;
        float acc = 0.f;
        #pragma unroll
        for (int j = 0; j < 17; ++j) acc += As[n][i0][j] * h[n][j][o];
        outs[i0][n][o] = acc;
    }
    __syncthreads();
    for (int p = tid; p < 68; p += 128) {              // score per (i,n)
        int i0 = p >> 2, n = p & 3;
        float accsc = 0.f;
        for (int o2 = 0; o2 < 32; ++o2) {
            float qv = qb[o2], kv = kb[o2];
            #pragma unroll
            for (int o = 0; o < 32; ++o) { float ov = outs[i0][n][o]; qv += ov*qws[o][o2]; kv += ov*kws[o][o2]; }
            accsc += tanhf(qv+kv) * aw[o2];
        }
        sc[i0][n] = accsc + ab[0];
    }
    __syncthreads();
    if (tid < 4) {                                     // softmax over joints per order
        int n = tid; float m = -1e30f;
        for (int i0=0;i0<17;++i0) m = fmaxf(m, sc[i0][n]);
        float s = 0.f;
        for (int i0=0;i0<17;++i0){ float e0=expf(sc[i0][n]-m); wsoft[i0][n]=e0; s+=e0; }
        float inv = 1.f/s;
        for (int i0=0;i0<17;++i0) wsoft[i0][n] *= inv;
    }
    __syncthreads();
    if (tid < 17) {                                    // aggregate + LN(32) + relu + pos
        int j = tid;
        float att[32]; float mu = 0.f;
        for (int o=0;o<32;++o){
            float a0 = gc_bias[o];
            #pragma unroll
            for (int n=0;n<4;++n) a0 += outs[j][n][o]*wsoft[j][n];
            att[o]=a0; mu+=a0;
        }
        mu *= (1.f/32.f);
        float var=0.f;
        for (int o=0;o<32;++o){ float d0=att[o]-mu; var += d0*d0; }
        float rstd = rsqrtf(var*(1.f/32.f) + 1e-5f);
        int f = r % FF;
        for (int o=0;o<32;++o){
            float g0 = (att[o]-mu)*rstd*lng[o] + lnb[o];
            g0 = fmaxf(g0, 0.f);
            int e = j*32+o;
            xe[(size_t)r*EE + e] = g0 + pos_embed[(size_t)f*EE + e];
        }
    }
}

// ---------------- LN1 + per-joint LN + pooling-score (fused, one block per row) ----
__global__ __launch_bounds__(256) void ln1_prelude_kernel(
    const float* __restrict__ xe,
    const float* __restrict__ g1, const float* __restrict__ b1,
    const float* __restrict__ ang, const float* __restrict__ anb,
    const float* __restrict__ apw, const float* __restrict__ apb,
    bf16* __restrict__ xr_out, float* __restrict__ s_out)
{
    __shared__ float row[544]; __shared__ float red[256];
    __shared__ float jm[17], jrs[17];
    int r = blockIdx.x, tid = threadIdx.x;
    float ls = 0.f;
    for (int e=tid;e<EE;e+=256){ float v=xe[(size_t)r*EE+e]; row[e]=v; ls+=v; }
    red[tid]=ls; __syncthreads();
    for(int st=128;st>0;st>>=1){ if(tid<st) red[tid]+=red[tid+st]; __syncthreads(); }
    float mean = red[0]*(1.f/544.f); __syncthreads();
    float lv = 0.f;
    for (int e=tid;e<EE;e+=256){ float d0=row[e]-mean; lv+=d0*d0; }
    red[tid]=lv; __syncthreads();
    for(int st=128;st>0;st>>=1){ if(tid<st) red[tid]+=red[tid+st]; __syncthreads(); }
    float rstd = rsqrtf(red[0]*(1.f/544.f)+1e-6f);
    for (int e=tid;e<EE;e+=256)
        row[e] = (row[e]-mean)*rstd*g1[e] + b1[e];
    __syncthreads();
    if (tid < 17) {
        float s0=0.f, s1=0.f;
        for (int o=0;o<32;++o){ float v=row[tid*32+o]; s0+=v; s1+=v*v; }
        float mu = s0*(1.f/32.f);
        jm[tid]=mu; jrs[tid]=rsqrtf(s1*(1.f/32.f)-mu*mu+1e-5f);
    }
    __syncthreads();
    for (int e=tid;e<EE;e+=256){
        int j=e>>5, o=e&31;
        float v = (row[e]-jm[j])*jrs[j]*ang[o] + anb[o];
        xr_out[(size_t)r*EE+e] = f2b(v);
        row[e] = v;
    }
    __syncthreads();
    if (tid < 17) {
        float acc = apb[0];
        for (int o=0;o<32;++o) acc += row[tid*32+o]*apw[o];
        s_out[(size_t)r*JJ+tid] = acc;
    }
}

// ---------------- softmax over frames (per (b,joint), in place) ----------------
__global__ __launch_bounds__(256) void softmax_frames_kernel(float* __restrict__ s)
{
    int bid = blockIdx.x; int b = bid/JJ, j = bid%JJ;
    float* base = s + (size_t)b*FF*JJ + j;
    __shared__ float red[256];
    int tid = threadIdx.x;
    float v = -1e30f;
    if (tid < FF) v = base[(size_t)tid*JJ];
    red[tid]=v; __syncthreads();
    for(int st=128;st>0;st>>=1){ if(tid<st) red[tid]=fmaxf(red[tid],red[tid+st]); __syncthreads(); }
    float m = red[0]; __syncthreads();
    float e0 = (tid<FF) ? expf(v-m) : 0.f;
    red[tid]=e0; __syncthreads();
    for(int st=128;st>0;st>>=1){ if(tid<st) red[tid]+=red[tid+st]; __syncthreads(); }
    float inv = 1.f/red[0];
    if (tid<FF) base[(size_t)tid*JJ] = e0*inv;
}

// ---------------- xa = LN544(xr * wf) ----------------
__global__ __launch_bounds__(256) void lnC_kernel(
    const bf16* __restrict__ xr, const float* __restrict__ wf,
    const float* __restrict__ g, const float* __restrict__ b,
    bf16* __restrict__ xa)
{
    __shared__ float row[544]; __shared__ float red[256]; __shared__ float wloc[17];
    int r = blockIdx.x, tid = threadIdx.x;
    if (tid < 17) wloc[tid] = wf[(size_t)r*JJ + tid];
    __syncthreads();
    float ls = 0.f;
    for (int e=tid;e<EE;e+=256){ float v = b2f(xr[(size_t)r*EE+e])*wloc[e>>5]; row[e]=v; ls+=v; }
    red[tid]=ls; __syncthreads();
    for(int st=128;st>0;st>>=1){ if(tid<st) red[tid]+=red[tid+st]; __syncthreads(); }
    float mean = red[0]*(1.f/544.f); __syncthreads();
    float lv = 0.f;
    for (int e=tid;e<EE;e+=256){ float d0=row[e]-mean; lv+=d0*d0; }
    red[tid]=lv; __syncthreads();
    for(int st=128;st>0;st>>=1){ if(tid<st) red[tid]+=red[tid+st]; __syncthreads(); }
    float rstd = rsqrtf(red[0]*(1.f/544.f)+1e-5f);
    for (int e=tid;e<EE;e+=256)
        xa[(size_t)r*EE+e] = f2b((row[e]-mean)*rstd*g[e] + b[e]);
}

// ---------------- generic LN over 544 (fp32 in, bf16 out) ----------------
__global__ __launch_bounds__(256) void ln_row_kernel(
    const float* __restrict__ in, const float* __restrict__ g,
    const float* __restrict__ b, bf16* __restrict__ out, float eps)
{
    __shared__ float row[544]; __shared__ float red[256];
    int r = blockIdx.x, tid = threadIdx.x;
    float ls = 0.f;
    for (int e=tid;e<EE;e+=256){ float v=in[(size_t)r*EE+e]; row[e]=v; ls+=v; }
    red[tid]=ls; __syncthreads();
    for(int st=128;st>0;st>>=1){ if(tid<st) red[tid]+=red[tid+st]; __syncthreads(); }
    float mean = red[0]*(1.f/544.f); __syncthreads();
    float lv = 0.f;
    for (int e=tid;e<EE;e+=256){ float d0=row[e]-mean; lv+=d0*d0; }
    red[tid]=lv; __syncthreads();
    for(int st=128;st>0;st>>=1){ if(tid<st) red[tid]+=red[tid+st]; __syncthreads(); }
    float rstd = rsqrtf(red[0]*(1.f/544.f)+eps);
    for (int e=tid;e<EE;e+=256)
        out[(size_t)r*EE+e] = f2b((row[e]-mean)*rstd*g[e] + b[e]);
}

// ---------------- tiled GEMM: C = A[MxK](bf16) * B[KxN](fp32 weights) + bias ------
// mode 1: qkv scatter (bf16) to [B,H,F,HD] x3
// mode 2: out_f32 += v (residual accumulate, fp32)
// mode 3: exact gelu, store bf16
// mode 4: store fp32 (final output)
__global__ __launch_bounds__(256) void gemm_kernel(
    const bf16* __restrict__ A, const float* __restrict__ B,
    const float* __restrict__ bias,
    float* __restrict__ out_f32, bf16* __restrict__ qbuf,
    bf16* __restrict__ out_bf,
    int M, int N, int K, int mode)
{
    __shared__ float As[16][65];
    __shared__ float Bs[16][65];
    int tid = threadIdx.x;
    int bm0 = blockIdx.y * 64;
    int bn0 = blockIdx.x * 64;
    int tx = tid & 15, ty = tid >> 4;
    float acc[4][4] = {{0.f}};
    for (int k0 = 0; k0 < K; k0 += 16) {
        #pragma unroll
        for (int i = 0; i < 4; ++i) {
            int l = tid + i*256;
            int rr = l >> 4, cc = l & 15;
            As[cc][rr] = b2f(A[(size_t)(bm0 + rr)*K + k0 + cc]);
        }
        #pragma unroll
        for (int i = 0; i < 4; ++i) {
            int l = tid + i*256;
            int rr = l >> 6, cc = l & 63;
            int col = bn0 + cc;
            Bs[rr][cc] = (col < N) ? B[(size_t)(k0 + rr)*N + col] : 0.f;
        }
        __syncthreads();
        #pragma unroll
        for (int kk = 0; kk < 16; ++kk) {
            float a0[4], b0[4];
            #pragma unroll
            for (int i=0;i<4;++i) a0[i] = As[kk][ty*4+i];
            #pragma unroll
            for (int j=0;j<4;++j) b0[j] = Bs[kk][tx*4+j];
            #pragma unroll
            for (int i=0;i<4;++i)
                #pragma unroll
                for (int j=0;j<4;++j) acc[i][j] = fmaf(a0[i], b0[j], acc[i][j]);
        }
        __syncthreads();
    }
    #pragma unroll
    for (int i=0;i<4;++i) {
        int r = bm0 + ty*4 + i;
        #pragma unroll
        for (int j=0;j<4;++j) {
            int c = bn0 + tx*4 + j;
            if (c >= N) continue;
            float v = acc[i][j] + bias[c];
            if (mode == 1) {
                int which = c / 544, rem = c % 544;
                int hh = rem / 68, dd = rem % 68;
                int b = r / FF, f = r % FF;
                bf16* dst = qbuf + (size_t)which * QSTRIDE;
                dst[((size_t)(b*NHH + hh)*FF + f)*HDD + dd] = f2b(v);
            } else if (mode == 2) out_f32[(size_t)r*N + c] += v;
            else if (mode == 3) {
                float g = 0.5f * v * (1.0f + erff(v * 0.70710678118654752f));
                out_bf[(size_t)r*N + c] = f2b(g);
            } else {
                out_f32[(size_t)r*N + c] = v;
            }
        }
    }
}

// ---------------- attention: one block per (b,h,query-row) ----------------
__global__ __launch_bounds__(256) void attn_kernel(
    const bf16* __restrict__ q, const bf16* __restrict__ k, const bf16* __restrict__ v,
    const float* __restrict__ scaling_ptr, bf16* __restrict__ ao)
{
    int gid = blockIdx.x;            // (b*8+h)*243 + qi
    int qi = gid % FF, bh = gid / FF;
    __shared__ float qrow[HDD];
    __shared__ float sc[FF];
    __shared__ float red[256];
    int tid = threadIdx.x;
    float scaling = scaling_ptr[0];
    if (tid < HDD) qrow[tid] = b2f(q[(size_t)gid*HDD + tid]);
    __syncthreads();
    const bf16* kbase = k + (size_t)bh*FF*HDD;
    const float SCALE = 0.12126781251816648f;  // 68^-0.5
    for (int kk = tid; kk < FF; kk += 256) {
        const bf16* kr = kbase + (size_t)kk*HDD;
        float d = 0.f;
        #pragma unroll 4
        for (int dd = 0; dd < HDD; ++dd) d = fmaf(qrow[dd], b2f(kr[dd]), d);
        float pos = kk * (1.0f/242.0f) - 0.5f;
        float ps = expf(-scaling * pos * pos);
        sc[kk] = d * (SCALE * ps);
    }
    __syncthreads();
    float lm = -1e30f;
    for (int kk=tid; kk<FF; kk+=256) lm = fmaxf(lm, sc[kk]);
    red[tid]=lm; __syncthreads();
    for(int st=128;st>0;st>>=1){ if(tid<st) red[tid]=fmaxf(red[tid],red[tid+st]); __syncthreads(); }
    float m = red[0]; __syncthreads();
    float lsum = 0.f;
    for (int kk=tid; kk<FF; kk+=256){ float e0=expf(sc[kk]-m); sc[kk]=e0; lsum+=e0; }
    red[tid]=lsum; __syncthreads();
    for(int st=128;st>0;st>>=1){ if(tid<st) red[tid]+=red[tid+st]; __syncthreads(); }
    float inv = 1.0f/red[0];
    const bf16* vbase = v + (size_t)bh*FF*HDD;
    int b = bh >> 3, hh = bh & 7;
    for (int dd = tid; dd < HDD; dd += 256) {
        float acc = 0.f;
        for (int kk=0; kk<FF; ++kk) acc = fmaf(sc[kk], b2f(vbase[(size_t)kk*HDD+dd]), acc);
        ao[((size_t)(b*FF + qi))*EE + hh*HDD + dd] = f2b(acc * inv);
    }
}

// ---------------- host launch ----------------
extern "C" void kernel_launch(void* const* d_in, const int* in_sizes, int n_in,
                              void* d_out, int out_size, void* d_ws, size_t ws_size,
                              hipStream_t stream) {
    typedef const float* fp;
    fp x          = (fp)d_in[0];
    // d_in[1] adj_masks: unused (recomputed from hardcoded skeleton)
    fp gc_W       = (fp)d_in[2];
    fp gc_e       = (fp)d_in[3];
    fp gc_bias    = (fp)d_in[4];
    fp gc_q_w     = (fp)d_in[5];
    fp gc_q_b     = (fp)d_in[6];
    fp gc_k_w     = (fp)d_in[7];
    fp gc_k_b     = (fp)d_in[8];
    fp gc_attn_w  = (fp)d_in[9];
    fp gc_attn_b  = (fp)d_in[10];
    fp gc_ln_g    = (fp)d_in[11];
    fp gc_ln_b    = (fp)d_in[12];
    fp pos_embed  = (fp)d_in[13];
    fp blk1_g     = (fp)d_in[14];
    fp blk1_b     = (fp)d_in[15];
    fp at_g       = (fp)d_in[16];
    fp at_b       = (fp)d_in[17];
    fp at_pw      = (fp)d_in[18];
    fp at_pb      = (fp)d_in[19];
    fp at2_g      = (fp)d_in[20];
    fp at2_b      = (fp)d_in[21];
    fp at_scaling = (fp)d_in[22];
    fp qkv_w      = (fp)d_in[23];
    fp qkv_b      = (fp)d_in[24];
    fp proj_w     = (fp)d_in[25];
    fp proj_b     = (fp)d_in[26];
    fp blk2_g     = (fp)d_in[27];
    fp blk2_b     = (fp)d_in[28];
    fp fc1_w      = (fp)d_in[29];
    fp fc1_b      = (fp)d_in[30];
    fp fc2_w      = (fp)d_in[31];
    fp fc2_b      = (fp)d_in[32];
    fp fin_g      = (fp)d_in[33];
    fp fin_b      = (fp)d_in[34];
    fp head_w     = (fp)d_in[35];
    fp head_b     = (fp)d_in[36];

    // ---- workspace layout (bytes, 256-aligned), total ~239 MB ----
    char* wsb = (char*)d_ws;
    size_t off = 0;
    auto alloc = [&](size_t bytes) { size_t cur = off; off += (bytes + 255) & ~(size_t)255; return cur; };
    float* Aw   = (float*)(wsb + alloc(1156 * 4));            // adjacency softmax
    float* xe   = (float*)(wsb + alloc(QSTRIDE * 4));         // residual, fp32
    float* sbuf = (float*)(wsb + alloc((size_t)ROWS*JJ * 4)); // pooling scores
    bf16*  xr   = (bf16*) (wsb + alloc(QSTRIDE * 2));         // xr; reused as ao
    bf16*  xa   = (bf16*) (wsb + alloc(QSTRIDE * 2));         // xa; reused as xn2/xo
    bf16*  qkv  = (bf16*) (wsb + alloc(3 * QSTRIDE * 2));     // q,k,v; reused as hm
    (void)ws_size;

    computeA_kernel<<<1, 64, 0, stream>>>(gc_e, Aw);
    gc_kernel<<<ROWS, 128, 0, stream>>>(x, Aw, gc_W, gc_bias, gc_q_w, gc_q_b,
                                        gc_k_w, gc_k_b, gc_attn_w, gc_attn_b,
                                        gc_ln_g, gc_ln_b, pos_embed, xe);
    for (int d = 0; d < 4; ++d) {
        ln1_prelude_kernel<<<ROWS, 256, 0, stream>>>(
            xe, blk1_g + d*EE, blk1_b + d*EE, at_g + d*ERR, at_b + d*ERR,
            at_pw + d*ERR, at_pb + d, xr, sbuf);
        softmax_frames_kernel<<<BB*JJ, 256, 0, stream>>>(sbuf);
        lnC_kernel<<<ROWS, 256, 0, stream>>>(xr, sbuf, at2_g + d*EE, at2_b + d*EE, xa);
        gemm_kernel<<<dim3(26, 486), 256, 0, stream>>>(
            xa, qkv_w + (size_t)d*EE*3*EE, qkv_b + d*3*EE,
            nullptr, qkv, nullptr, ROWS, 3*EE, EE, 1);
        attn_kernel<<<BB*NHH*FF, 256, 0, stream>>>(
            qkv, qkv + QSTRIDE, qkv + 2*QSTRIDE, at_scaling + d, xr);
        gemm_kernel<<<dim3(9, 486), 256, 0, stream>>>(
            xr, proj_w + (size_t)d*EE*EE, proj_b + d*EE,
            xe, nullptr, nullptr, ROWS, EE, EE, 2);
        ln_row_kernel<<<ROWS, 256, 0, stream>>>(xe, blk2_g + d*EE, blk2_b + d*EE, xa, 1e-6f);
        gemm_kernel<<<dim3(17, 486), 256, 0, stream>>>(
            xa, fc1_w + (size_t)d*EE*HIDD, fc1_b + d*HIDD,
            nullptr, nullptr, qkv, ROWS, HIDD, EE, 3);      // hm (bf16) into qkv region
        gemm_kernel<<<dim3(9, 486), 256, 0, stream>>>(
            qkv, fc2_w + (size_t)d*HIDD*EE, fc2_b + d*EE,
            xe, nullptr, nullptr, ROWS, EE, HIDD, 2);
    }
    ln_row_kernel<<<ROWS, 256, 0, stream>>>(xe, fin_g, fin_b, xa, 1e-6f);
    gemm_kernel<<<dim3(1, 486), 256, 0, stream>>>(
        xa, head_w, head_b, (float*)d_out, nullptr, nullptr,
        ROWS, 51, EE, 4);
}

// Round 4
// 5555.882 us; speedup vs baseline: 5.4281x; 5.4281x over previous
//
#include <hip/hip_runtime.h>
#include <hip/hip_bf16.h>
#include <math.h>

// ---------------- constants ----------------
#define BB 128
#define FF 243
#define JJ 17
#define ERR 32
#define EE 544
#define NHH 8
#define HDD 68
#define HIDD 1088
#define ROWS 31104          // B*F
#define QSTRIDE 16920576ULL // ROWS*EE

typedef __hip_bfloat16 bf16;
typedef __bf16 bf16x8 __attribute__((ext_vector_type(8)));
typedef float floatx4 __attribute__((ext_vector_type(4)));

static __device__ __forceinline__ float b2f(bf16 v) { return __bfloat162float(v); }
static __device__ __forceinline__ bf16 f2b(float v) { return __float2bfloat16(v); }
static __device__ __forceinline__ unsigned short f2bu(float v) {
    bf16 h = __float2bfloat16(v);
    return *(unsigned short*)&h;
}

// ---------------- adjacency softmax precompute ----------------
__global__ void computeA_kernel(const float* __restrict__ gc_e, float* __restrict__ A)
{
    __shared__ float a1[17][17], a2[17][17], a3[17][17];
    int tid = threadIdx.x;
    const int parents[17] = {-1,0,1,2,0,4,5,0,7,8,9,8,11,12,8,14,15};
    if (tid == 0) {
        for (int i=0;i<17;++i) for (int j=0;j<17;++j) a1[i][j]=0.f;
        for (int c=0;c<17;++c){ int p=parents[c]; if(p>=0){ a1[c][p]=1.f; a1[p][c]=1.f; } }
        for (int i=0;i<17;++i) for (int j=0;j<17;++j){ float s=0; for(int k=0;k<17;++k) s+=a1[i][k]*a1[k][j]; a2[i][j]=s; }
        for (int i=0;i<17;++i) for (int j=0;j<17;++j){ float s=0; for(int k=0;k<17;++k) s+=a2[i][k]*a1[k][j]; a3[i][j]=s; }
    }
    __syncthreads();
    for (int p = tid; p < 68; p += 64) {
        int n = p / 17, i = p % 17;
        bool msk[17];
        float m = -1e30f;
        for (int j=0;j<17;++j) {
            bool mm;
            if (n==0) mm = (i==j);
            else if (n==1) mm = a1[i][j] > 0.f;
            else if (n==2) mm = a2[i][j] > 0.f;
            else mm = a3[i][j] > 0.f;
            msk[j] = mm;
            if (mm) m = fmaxf(m, gc_e[(n*17+i)*17+j]);
        }
        float ex[17]; float s=0.f;
        for (int j=0;j<17;++j){ ex[j] = msk[j] ? expf(gc_e[(n*17+i)*17+j]-m) : 0.f; s+=ex[j]; }
        float inv = 1.f/s;
        for (int j=0;j<17;++j) A[(n*17+i)*17+j] = ex[j]*inv;
    }
}

// ---------------- fused graph conv (one block per token row) ----------------
__global__ __launch_bounds__(128) void gc_kernel(
    const float* __restrict__ x, const float* __restrict__ A,
    const float* __restrict__ gc_W, const float* __restrict__ gc_bias,
    const float* __restrict__ qw, const float* __restrict__ qb,
    const float* __restrict__ kw, const float* __restrict__ kb,
    const float* __restrict__ aw, const float* __restrict__ ab,
    const float* __restrict__ lng, const float* __restrict__ lnb,
    const float* __restrict__ pos_embed,
    float* __restrict__ xe)
{
    __shared__ float xf[34];
    __shared__ float As[4][17][17];
    __shared__ float Ws[4][2][32];
    __shared__ float h[4][17][32];
    __shared__ float outs[17][4][32];
    __shared__ float qws[32][32], kws[32][32];
    __shared__ float sc[17][4];
    __shared__ float wsoft[17][4];
    int r = blockIdx.x, tid = threadIdx.x;

    for (int i = tid; i < 34; i += 128) xf[i] = x[(size_t)r*34 + i];
    for (int i = tid; i < 1156; i += 128) ((float*)As)[i] = A[i];
    for (int i = tid; i < 256; i += 128) ((float*)Ws)[i] = gc_W[i];
    for (int i = tid; i < 1024; i += 128) { ((float*)qws)[i] = qw[i]; ((float*)kws)[i] = kw[i]; }
    __syncthreads();

    for (int idx = tid; idx < 2176; idx += 128) {
        int n = idx / 544, j = (idx / 32) % 17, o = idx & 31;
        h[n][j][o] = xf[j*2+0]*Ws[n][0][o] + xf[j*2+1]*Ws[n][1][o];
    }
    __syncthreads();
    for (int idx = tid; idx < 2176; idx += 128) {
        int i0 = idx / 128, n = (idx / 32) & 3, o = idx & 31;
        float acc = 0.f;
        #pragma unroll
        for (int j = 0; j < 17; ++j) acc += As[n][i0][j] * h[n][j][o];
        outs[i0][n][o] = acc;
    }
    __syncthreads();
    for (int p = tid; p < 68; p += 128) {
        int i0 = p >> 2, n = p & 3;
        float accsc = 0.f;
        for (int o2 = 0; o2 < 32; ++o2) {
            float qv = qb[o2], kv = kb[o2];
            #pragma unroll
            for (int o = 0; o < 32; ++o) { float ov = outs[i0][n][o]; qv += ov*qws[o][o2]; kv += ov*kws[o][o2]; }
            accsc += tanhf(qv+kv) * aw[o2];
        }
        sc[i0][n] = accsc + ab[0];
    }
    __syncthreads();
    if (tid < 4) {
        int n = tid; float m = -1e30f;
        for (int i0=0;i0<17;++i0) m = fmaxf(m, sc[i0][n]);
        float s = 0.f;
        for (int i0=0;i0<17;++i0){ float e0=expf(sc[i0][n]-m); wsoft[i0][n]=e0; s+=e0; }
        float inv = 1.f/s;
        for (int i0=0;i0<17;++i0) wsoft[i0][n] *= inv;
    }
    __syncthreads();
    if (tid < 17) {
        int j = tid;
        float att[32]; float mu = 0.f;
        for (int o=0;o<32;++o){
            float a0 = gc_bias[o];
            #pragma unroll
            for (int n=0;n<4;++n) a0 += outs[j][n][o]*wsoft[j][n];
            att[o]=a0; mu+=a0;
        }
        mu *= (1.f/32.f);
        float var=0.f;
        for (int o=0;o<32;++o){ float d0=att[o]-mu; var += d0*d0; }
        float rstd = rsqrtf(var*(1.f/32.f) + 1e-5f);
        int f = r % FF;
        for (int o=0;o<32;++o){
            float g0 = (att[o]-mu)*rstd*lng[o] + lnb[o];
            g0 = fmaxf(g0, 0.f);
            int e = j*32+o;
            xe[(size_t)r*EE + e] = g0 + pos_embed[(size_t)f*EE + e];
        }
    }
}

// ---------------- LN1 + per-joint LN + pooling-score ----------------
__global__ __launch_bounds__(256) void ln1_prelude_kernel(
    const float* __restrict__ xe,
    const float* __restrict__ g1, const float* __restrict__ b1,
    const float* __restrict__ ang, const float* __restrict__ anb,
    const float* __restrict__ apw, const float* __restrict__ apb,
    bf16* __restrict__ xr_out, float* __restrict__ s_out)
{
    __shared__ float row[544]; __shared__ float red[256];
    __shared__ float jm[17], jrs[17];
    int r = blockIdx.x, tid = threadIdx.x;
    float ls = 0.f;
    for (int e=tid;e<EE;e+=256){ float v=xe[(size_t)r*EE+e]; row[e]=v; ls+=v; }
    red[tid]=ls; __syncthreads();
    for(int st=128;st>0;st>>=1){ if(tid<st) red[tid]+=red[tid+st]; __syncthreads(); }
    float mean = red[0]*(1.f/544.f); __syncthreads();
    float lv = 0.f;
    for (int e=tid;e<EE;e+=256){ float d0=row[e]-mean; lv+=d0*d0; }
    red[tid]=lv; __syncthreads();
    for(int st=128;st>0;st>>=1){ if(tid<st) red[tid]+=red[tid+st]; __syncthreads(); }
    float rstd = rsqrtf(red[0]*(1.f/544.f)+1e-6f);
    for (int e=tid;e<EE;e+=256)
        row[e] = (row[e]-mean)*rstd*g1[e] + b1[e];
    __syncthreads();
    if (tid < 17) {
        float s0=0.f, s1=0.f;
        for (int o=0;o<32;++o){ float v=row[tid*32+o]; s0+=v; s1+=v*v; }
        float mu = s0*(1.f/32.f);
        jm[tid]=mu; jrs[tid]=rsqrtf(s1*(1.f/32.f)-mu*mu+1e-5f);
    }
    __syncthreads();
    for (int e=tid;e<EE;e+=256){
        int j=e>>5, o=e&31;
        float v = (row[e]-jm[j])*jrs[j]*ang[o] + anb[o];
        xr_out[(size_t)r*EE+e] = f2b(v);
        row[e] = v;
    }
    __syncthreads();
    if (tid < 17) {
        float acc = apb[0];
        for (int o=0;o<32;++o) acc += row[tid*32+o]*apw[o];
        s_out[(size_t)r*JJ+tid] = acc;
    }
}

// ---------------- softmax over frames ----------------
__global__ __launch_bounds__(256) void softmax_frames_kernel(float* __restrict__ s)
{
    int bid = blockIdx.x; int b = bid/JJ, j = bid%JJ;
    float* base = s + (size_t)b*FF*JJ + j;
    __shared__ float red[256];
    int tid = threadIdx.x;
    float v = -1e30f;
    if (tid < FF) v = base[(size_t)tid*JJ];
    red[tid]=v; __syncthreads();
    for(int st=128;st>0;st>>=1){ if(tid<st) red[tid]=fmaxf(red[tid],red[tid+st]); __syncthreads(); }
    float m = red[0]; __syncthreads();
    float e0 = (tid<FF) ? expf(v-m) : 0.f;
    red[tid]=e0; __syncthreads();
    for(int st=128;st>0;st>>=1){ if(tid<st) red[tid]+=red[tid+st]; __syncthreads(); }
    float inv = 1.f/red[0];
    if (tid<FF) base[(size_t)tid*JJ] = e0*inv;
}

// ---------------- xa = LN544(xr * wf) ----------------
__global__ __launch_bounds__(256) void lnC_kernel(
    const bf16* __restrict__ xr, const float* __restrict__ wf,
    const float* __restrict__ g, const float* __restrict__ b,
    bf16* __restrict__ xa)
{
    __shared__ float row[544]; __shared__ float red[256]; __shared__ float wloc[17];
    int r = blockIdx.x, tid = threadIdx.x;
    if (tid < 17) wloc[tid] = wf[(size_t)r*JJ + tid];
    __syncthreads();
    float ls = 0.f;
    for (int e=tid;e<EE;e+=256){ float v = b2f(xr[(size_t)r*EE+e])*wloc[e>>5]; row[e]=v; ls+=v; }
    red[tid]=ls; __syncthreads();
    for(int st=128;st>0;st>>=1){ if(tid<st) red[tid]+=red[tid+st]; __syncthreads(); }
    float mean = red[0]*(1.f/544.f); __syncthreads();
    float lv = 0.f;
    for (int e=tid;e<EE;e+=256){ float d0=row[e]-mean; lv+=d0*d0; }
    red[tid]=lv; __syncthreads();
    for(int st=128;st>0;st>>=1){ if(tid<st) red[tid]+=red[tid+st]; __syncthreads(); }
    float rstd = rsqrtf(red[0]*(1.f/544.f)+1e-5f);
    for (int e=tid;e<EE;e+=256)
        xa[(size_t)r*EE+e] = f2b((row[e]-mean)*rstd*g[e] + b[e]);
}

// ---------------- generic LN over 544 (fp32 in, bf16 out) ----------------
__global__ __launch_bounds__(256) void ln_row_kernel(
    const float* __restrict__ in, const float* __restrict__ g,
    const float* __restrict__ b, bf16* __restrict__ out, float eps)
{
    __shared__ float row[544]; __shared__ float red[256];
    int r = blockIdx.x, tid = threadIdx.x;
    float ls = 0.f;
    for (int e=tid;e<EE;e+=256){ float v=in[(size_t)r*EE+e]; row[e]=v; ls+=v; }
    red[tid]=ls; __syncthreads();
    for(int st=128;st>0;st>>=1){ if(tid<st) red[tid]+=red[tid+st]; __syncthreads(); }
    float mean = red[0]*(1.f/544.f); __syncthreads();
    float lv = 0.f;
    for (int e=tid;e<EE;e+=256){ float d0=row[e]-mean; lv+=d0*d0; }
    red[tid]=lv; __syncthreads();
    for(int st=128;st>0;st>>=1){ if(tid<st) red[tid]+=red[tid+st]; __syncthreads(); }
    float rstd = rsqrtf(red[0]*(1.f/544.f)+eps);
    for (int e=tid;e<EE;e+=256)
        out[(size_t)r*EE+e] = f2b((row[e]-mean)*rstd*g[e] + b[e]);
}

// ---------------- weight convert: fp32 [K][N] -> bf16 [Npad][K] (transpose+pad) ----
__global__ __launch_bounds__(256) void wconv_kernel(
    const float* __restrict__ W, unsigned short* __restrict__ out,
    int N, int K, int Npad)
{
    int idx = blockIdx.x * 256 + threadIdx.x;
    if (idx >= Npad * K) return;
    int n = idx % Npad, k = idx / Npad;
    float v = (n < N) ? W[(size_t)k*N + n] : 0.f;
    out[(size_t)n*K + k] = f2bu(v);
}

// ---------------- MFMA GEMM: C[M x N] = A[M x K](bf16) * Bt[Npad x K](bf16)^T ------
// tile 128x128, BK=32, 4 waves of 4x4 16x16x32 fragments
// mode 1: qkv scatter (bf16); mode 2: out_f32 += v; mode 3: gelu -> bf16; mode 4: fp32
__global__ __launch_bounds__(256) void mgemm_kernel(
    const unsigned short* __restrict__ A, const unsigned short* __restrict__ Bt,
    const float* __restrict__ bias,
    float* __restrict__ out_f32, unsigned short* __restrict__ qbuf,
    unsigned short* __restrict__ out_bf,
    int N, int K, int mode)
{
    __shared__ unsigned short As[128][40];
    __shared__ unsigned short Bs[128][40];
    int tid = threadIdx.x;
    int bm0 = blockIdx.y * 128, bn0 = blockIdx.x * 128;
    int wave = tid >> 6, lane = tid & 63;
    int wm = (wave >> 1) * 64, wn = (wave & 1) * 64;
    int quad = lane >> 4, l16 = lane & 15;
    floatx4 acc[4][4] = {};

    for (int k0 = 0; k0 < K; k0 += 32) {
        #pragma unroll
        for (int i = 0; i < 2; ++i) {
            int c = tid + i*256;
            int r = c >> 2, k8 = (c & 3) * 8;
            *(uint4*)&As[r][k8] = *(const uint4*)&A[(size_t)(bm0 + r)*K + k0 + k8];
            *(uint4*)&Bs[r][k8] = *(const uint4*)&Bt[(size_t)(bn0 + r)*K + k0 + k8];
        }
        __syncthreads();
        bf16x8 af[4], bfr[4];
        #pragma unroll
        for (int mi=0;mi<4;++mi) af[mi]  = *(const bf16x8*)&As[wm + mi*16 + l16][quad*8];
        #pragma unroll
        for (int ni=0;ni<4;++ni) bfr[ni] = *(const bf16x8*)&Bs[wn + ni*16 + l16][quad*8];
        #pragma unroll
        for (int mi=0;mi<4;++mi)
            #pragma unroll
            for (int ni=0;ni<4;++ni)
                acc[mi][ni] = __builtin_amdgcn_mfma_f32_16x16x32_bf16(af[mi], bfr[ni], acc[mi][ni], 0, 0, 0);
        __syncthreads();
    }

    #pragma unroll
    for (int mi=0;mi<4;++mi) {
        #pragma unroll
        for (int ni=0;ni<4;++ni) {
            #pragma unroll
            for (int r4=0;r4<4;++r4) {
                int gm = bm0 + wm + mi*16 + quad*4 + r4;
                int gn = bn0 + wn + ni*16 + l16;
                if (gn >= N) continue;
                float v = acc[mi][ni][r4] + bias[gn];
                if (mode == 1) {
                    int which = gn / 544, rem = gn % 544;
                    int hh = rem / 68, dd = rem % 68;
                    int b = gm / FF, f = gm % FF;
                    unsigned short* dst = qbuf + (size_t)which * QSTRIDE;
                    dst[((size_t)(b*NHH + hh)*FF + f)*HDD + dd] = f2bu(v);
                } else if (mode == 2) {
                    out_f32[(size_t)gm*N + gn] += v;
                } else if (mode == 3) {
                    float g = 0.5f * v * (1.0f + erff(v * 0.70710678118654752f));
                    out_bf[(size_t)gm*N + gn] = f2bu(g);
                } else {
                    out_f32[(size_t)gm*N + gn] = v;
                }
            }
        }
    }
}

// ---------------- flash attention: one block per (b,h), thread = query ----------
__global__ __launch_bounds__(256) void fattn_kernel(
    const unsigned short* __restrict__ q, const unsigned short* __restrict__ k,
    const unsigned short* __restrict__ v,
    const float* __restrict__ scaling_ptr, bf16* __restrict__ ao)
{
    __shared__ float Ksf[64][68];
    __shared__ float Vsf[64][68];
    __shared__ float ps_s[FF];
    int bh = blockIdx.x, tid = threadIdx.x;
    int b = bh >> 3, h = bh & 7;
    float scaling = scaling_ptr[0];
    const float SCALE = 0.12126781251816648f;  // 68^-0.5

    for (int i = tid; i < FF; i += 256) {
        float pos = i * (1.0f/242.0f) - 0.5f;
        ps_s[i] = SCALE * __expf(-scaling * pos * pos);
    }

    // load my query row (68 bf16 -> fp32 regs)
    float qreg[68];
    int qi = tid;
    if (qi < FF) {
        const unsigned short* qp = q + ((size_t)bh*FF + qi)*HDD;
        #pragma unroll
        for (int d2 = 0; d2 < 34; ++d2) {
            unsigned u = *(const unsigned*)&qp[d2*2];
            qreg[d2*2]   = __uint_as_float(u << 16);
            qreg[d2*2+1] = __uint_as_float(u & 0xffff0000u);
        }
    }
    float acc[68];
    #pragma unroll
    for (int dd = 0; dd < 68; ++dd) acc[dd] = 0.f;
    float mmax = -1e30f, lsum = 0.f;

    const unsigned short* kbase = k + (size_t)bh*FF*HDD;
    const unsigned short* vbase = v + (size_t)bh*FF*HDD;

    for (int t = 0; t < 4; ++t) {
        int nk = (t == 3) ? (FF - 192) : 64;
        __syncthreads();
        for (int idx = tid; idx < nk*34; idx += 256) {
            int row = idx / 34, d2 = idx % 34;
            unsigned uk = *(const unsigned*)&kbase[((size_t)(t*64 + row))*HDD + d2*2];
            unsigned uv = *(const unsigned*)&vbase[((size_t)(t*64 + row))*HDD + d2*2];
            Ksf[row][d2*2]   = __uint_as_float(uk << 16);
            Ksf[row][d2*2+1] = __uint_as_float(uk & 0xffff0000u);
            Vsf[row][d2*2]   = __uint_as_float(uv << 16);
            Vsf[row][d2*2+1] = __uint_as_float(uv & 0xffff0000u);
        }
        __syncthreads();
        if (qi < FF) {
            for (int kk = 0; kk < nk; ++kk) {
                float d = 0.f;
                #pragma unroll
                for (int dq = 0; dq < 17; ++dq) {
                    float4 kvec = *(const float4*)&Ksf[kk][dq*4];
                    d = fmaf(qreg[dq*4+0], kvec.x, d);
                    d = fmaf(qreg[dq*4+1], kvec.y, d);
                    d = fmaf(qreg[dq*4+2], kvec.z, d);
                    d = fmaf(qreg[dq*4+3], kvec.w, d);
                }
                float s = d * ps_s[t*64 + kk];
                if (s > mmax) {
                    float corr = __expf(mmax - s);
                    lsum *= corr;
                    #pragma unroll
                    for (int dd = 0; dd < 68; ++dd) acc[dd] *= corr;
                    mmax = s;
                }
                float p = __expf(s - mmax);
                lsum += p;
                #pragma unroll
                for (int dq = 0; dq < 17; ++dq) {
                    float4 vv = *(const float4*)&Vsf[kk][dq*4];
                    acc[dq*4+0] = fmaf(p, vv.x, acc[dq*4+0]);
                    acc[dq*4+1] = fmaf(p, vv.y, acc[dq*4+1]);
                    acc[dq*4+2] = fmaf(p, vv.z, acc[dq*4+2]);
                    acc[dq*4+3] = fmaf(p, vv.w, acc[dq*4+3]);
                }
            }
        }
    }
    if (qi < FF) {
        float inv = 1.f / lsum;
        bf16* dst = ao + ((size_t)b*FF + qi)*EE + h*HDD;
        #pragma unroll
        for (int dd = 0; dd < 68; ++dd) dst[dd] = f2b(acc[dd] * inv);
    }
}

// ---------------- host launch ----------------
extern "C" void kernel_launch(void* const* d_in, const int* in_sizes, int n_in,
                              void* d_out, int out_size, void* d_ws, size_t ws_size,
                              hipStream_t stream) {
    typedef const float* fp;
    fp x          = (fp)d_in[0];
    fp gc_W       = (fp)d_in[2];
    fp gc_e       = (fp)d_in[3];
    fp gc_bias    = (fp)d_in[4];
    fp gc_q_w     = (fp)d_in[5];
    fp gc_q_b     = (fp)d_in[6];
    fp gc_k_w     = (fp)d_in[7];
    fp gc_k_b     = (fp)d_in[8];
    fp gc_attn_w  = (fp)d_in[9];
    fp gc_attn_b  = (fp)d_in[10];
    fp gc_ln_g    = (fp)d_in[11];
    fp gc_ln_b    = (fp)d_in[12];
    fp pos_embed  = (fp)d_in[13];
    fp blk1_g     = (fp)d_in[14];
    fp blk1_b     = (fp)d_in[15];
    fp at_g       = (fp)d_in[16];
    fp at_b       = (fp)d_in[17];
    fp at_pw      = (fp)d_in[18];
    fp at_pb      = (fp)d_in[19];
    fp at2_g      = (fp)d_in[20];
    fp at2_b      = (fp)d_in[21];
    fp at_scaling = (fp)d_in[22];
    fp qkv_w      = (fp)d_in[23];
    fp qkv_b      = (fp)d_in[24];
    fp proj_w     = (fp)d_in[25];
    fp proj_b     = (fp)d_in[26];
    fp blk2_g     = (fp)d_in[27];
    fp blk2_b     = (fp)d_in[28];
    fp fc1_w      = (fp)d_in[29];
    fp fc1_b      = (fp)d_in[30];
    fp fc2_w      = (fp)d_in[31];
    fp fc2_b      = (fp)d_in[32];
    fp fin_g      = (fp)d_in[33];
    fp fin_b      = (fp)d_in[34];
    fp head_w     = (fp)d_in[35];
    fp head_b     = (fp)d_in[36];

    // ---- workspace layout (bytes, 256-aligned), total ~244.5 MB ----
    char* wsb = (char*)d_ws;
    size_t off = 0;
    auto alloc = [&](size_t bytes) { size_t cur = off; off += (bytes + 255) & ~(size_t)255; return cur; };
    float* Aw   = (float*)(wsb + alloc(1156 * 4));
    float* xe   = (float*)(wsb + alloc(QSTRIDE * 4));
    float* sbuf = (float*)(wsb + alloc((size_t)ROWS*JJ * 4));
    bf16*  xr   = (bf16*) (wsb + alloc(QSTRIDE * 2));          // xr; reused as ao
    bf16*  xa   = (bf16*) (wsb + alloc(QSTRIDE * 2));          // xa; reused as xn2/xo
    bf16*  qkv  = (bf16*) (wsb + alloc(3 * QSTRIDE * 2));      // q,k,v; reused as hm
    unsigned short* wq = (unsigned short*)(wsb + alloc((size_t)1664*544 * 2));
    unsigned short* wp = (unsigned short*)(wsb + alloc((size_t)640*544 * 2));
    unsigned short* w1 = (unsigned short*)(wsb + alloc((size_t)1152*544 * 2));
    unsigned short* w2 = (unsigned short*)(wsb + alloc((size_t)640*1088 * 2));
    (void)ws_size;

    computeA_kernel<<<1, 64, 0, stream>>>(gc_e, Aw);
    gc_kernel<<<ROWS, 128, 0, stream>>>(x, Aw, gc_W, gc_bias, gc_q_w, gc_q_b,
                                        gc_k_w, gc_k_b, gc_attn_w, gc_attn_b,
                                        gc_ln_g, gc_ln_b, pos_embed, xe);
    for (int d = 0; d < 4; ++d) {
        wconv_kernel<<<(1664*544 + 255)/256, 256, 0, stream>>>(
            qkv_w + (size_t)d*EE*3*EE, wq, 1632, 544, 1664);
        wconv_kernel<<<(640*544 + 255)/256, 256, 0, stream>>>(
            proj_w + (size_t)d*EE*EE, wp, 544, 544, 640);
        wconv_kernel<<<(1152*544 + 255)/256, 256, 0, stream>>>(
            fc1_w + (size_t)d*EE*HIDD, w1, 1088, 544, 1152);
        wconv_kernel<<<(640*1088 + 255)/256, 256, 0, stream>>>(
            fc2_w + (size_t)d*HIDD*EE, w2, 544, 1088, 640);

        ln1_prelude_kernel<<<ROWS, 256, 0, stream>>>(
            xe, blk1_g + d*EE, blk1_b + d*EE, at_g + d*ERR, at_b + d*ERR,
            at_pw + d*ERR, at_pb + d, xr, sbuf);
        softmax_frames_kernel<<<BB*JJ, 256, 0, stream>>>(sbuf);
        lnC_kernel<<<ROWS, 256, 0, stream>>>(xr, sbuf, at2_g + d*EE, at2_b + d*EE, xa);
        mgemm_kernel<<<dim3(13, 243), 256, 0, stream>>>(
            (const unsigned short*)xa, wq, qkv_b + d*3*EE,
            nullptr, (unsigned short*)qkv, nullptr, 1632, 544, 1);
        fattn_kernel<<<BB*NHH, 256, 0, stream>>>(
            (const unsigned short*)qkv, (const unsigned short*)qkv + QSTRIDE,
            (const unsigned short*)qkv + 2*QSTRIDE, at_scaling + d, xr);
        mgemm_kernel<<<dim3(5, 243), 256, 0, stream>>>(
            (const unsigned short*)xr, wp, proj_b + d*EE,
            xe, nullptr, nullptr, 544, 544, 2);
        ln_row_kernel<<<ROWS, 256, 0, stream>>>(xe, blk2_g + d*EE, blk2_b + d*EE, xa, 1e-6f);
        mgemm_kernel<<<dim3(9, 243), 256, 0, stream>>>(
            (const unsigned short*)xa, w1, fc1_b + d*HIDD,
            nullptr, nullptr, (unsigned short*)qkv, 1088, 544, 3);   // hm into qkv region
        mgemm_kernel<<<dim3(5, 243), 256, 0, stream>>>(
            (const unsigned short*)qkv, w2, fc2_b + d*EE,
            xe, nullptr, nullptr, 544, 1088, 2);
    }
    ln_row_kernel<<<ROWS, 256, 0, stream>>>(xe, fin_g, fin_b, xa, 1e-6f);
    wconv_kernel<<<(128*544 + 255)/256, 256, 0, stream>>>(head_w, wq, 51, 544, 128);
    mgemm_kernel<<<dim3(1, 243), 256, 0, stream>>>(
        (const unsigned short*)xa, wq, head_b,
        (float*)d_out, nullptr, nullptr, 51, 544, 4);
}

// Round 6
// 4836.002 us; speedup vs baseline: 6.2361x; 1.1489x over previous
//
#include <hip/hip_runtime.h>
#include <hip/hip_bf16.h>
#include <math.h>

// ---------------- constants ----------------
#define BB 128
#define FF 243
#define JJ 17
#define ERR 32
#define EE 544
#define NHH 8
#define HDD 68
#define HIDD 1088
#define ROWS 31104          // B*F
#define QSTRIDE 16920576ULL // ROWS*EE
#define GROWS 16            // rows per gc2 block

typedef __hip_bfloat16 bf16;
typedef __bf16 bf16x8 __attribute__((ext_vector_type(8)));
typedef float floatx4 __attribute__((ext_vector_type(4)));

static __device__ __forceinline__ float b2f(bf16 v) { return __bfloat162float(v); }
static __device__ __forceinline__ bf16 f2b(float v) { return __float2bfloat16(v); }
static __device__ __forceinline__ unsigned short f2bu(float v) {
    bf16 h = __float2bfloat16(v);
    return *(unsigned short*)&h;
}

// ---------------- prep: adjacency softmax + folded q/k projection ----------------
// A: [4][17][17] softmaxed adjacency
// Sg: [0..127]=S0[n][o2], [128..255]=S1[n][o2], [256..287]=qb+kb
__global__ __launch_bounds__(256) void prep_kernel(
    const float* __restrict__ gc_e, const float* __restrict__ gc_W,
    const float* __restrict__ qw, const float* __restrict__ kw,
    const float* __restrict__ qb, const float* __restrict__ kb,
    float* __restrict__ A, float* __restrict__ Sg)
{
    __shared__ float a1[17][17], a2[17][17], a3[17][17];
    int tid = threadIdx.x;
    const int parents[17] = {-1,0,1,2,0,4,5,0,7,8,9,8,11,12,8,14,15};
    if (tid == 0) {
        for (int i=0;i<17;++i) for (int j=0;j<17;++j) a1[i][j]=0.f;
        for (int c=0;c<17;++c){ int p=parents[c]; if(p>=0){ a1[c][p]=1.f; a1[p][c]=1.f; } }
        for (int i=0;i<17;++i) for (int j=0;j<17;++j){ float s=0; for(int k=0;k<17;++k) s+=a1[i][k]*a1[k][j]; a2[i][j]=s; }
        for (int i=0;i<17;++i) for (int j=0;j<17;++j){ float s=0; for(int k=0;k<17;++k) s+=a2[i][k]*a1[k][j]; a3[i][j]=s; }
    }
    __syncthreads();
    for (int p = tid; p < 68; p += 256) {
        int n = p / 17, i = p % 17;
        bool msk[17];
        float m = -1e30f;
        for (int j=0;j<17;++j) {
            bool mm;
            if (n==0) mm = (i==j);
            else if (n==1) mm = a1[i][j] > 0.f;
            else if (n==2) mm = a2[i][j] > 0.f;
            else mm = a3[i][j] > 0.f;
            msk[j] = mm;
            if (mm) m = fmaxf(m, gc_e[(n*17+i)*17+j]);
        }
        float ex[17]; float s=0.f;
        for (int j=0;j<17;++j){ ex[j] = msk[j] ? expf(gc_e[(n*17+i)*17+j]-m) : 0.f; s+=ex[j]; }
        float inv = 1.f/s;
        for (int j=0;j<17;++j) A[(n*17+i)*17+j] = ex[j]*inv;
    }
    // S[c][n][o2] = sum_o gc_W[n][c][o] * (qw[o][o2]+kw[o][o2])
    if (tid < 256) {
        int c = tid >> 7, n = (tid >> 5) & 3, o2 = tid & 31;
        float s = 0.f;
        for (int o = 0; o < 32; ++o)
            s += gc_W[(n*2+c)*32 + o] * (qw[o*32+o2] + kw[o*32+o2]);
        Sg[tid] = s;
    }
    if (tid < 32) Sg[256 + tid] = qb[tid] + kb[tid];
}

// ---------------- gc2: fused graph conv, 16 rows per block ----------------
__global__ __launch_bounds__(256) void gc2_kernel(
    const float* __restrict__ x, const float* __restrict__ A, const float* __restrict__ Sg,
    const float* __restrict__ gc_W, const float* __restrict__ gc_bias,
    const float* __restrict__ aw, const float* __restrict__ ab,
    const float* __restrict__ lng, const float* __restrict__ lnb,
    const float* __restrict__ pos_embed, float* __restrict__ xe)
{
    __shared__ float As[4][17][17];      // 1156
    __shared__ float S0[4][32], S1[4][32], bqk[32];
    __shared__ float Ws[4][2][32];
    __shared__ float aws[32], lngs[32], lnbs[32], gbias[32];
    __shared__ float xf[GROWS][34];
    __shared__ float c0[GROWS][68], c1[GROWS][68];
    __shared__ float sc[GROWS][68];
    int tid = threadIdx.x;
    int r0 = blockIdx.x * GROWS;

    for (int i = tid; i < 1156; i += 256) ((float*)As)[i] = A[i];
    if (tid < 128) ((float*)S0)[tid] = Sg[tid];
    else ((float*)S1)[tid-128] = Sg[tid];      // tid in [128,256)
    if (tid < 32) bqk[tid] = Sg[256+tid];
    if (tid >= 32 && tid < 64)  aws[tid-32]  = aw[tid-32];
    if (tid >= 64 && tid < 96)  lngs[tid-64] = lng[tid-64];
    if (tid >= 96 && tid < 128) lnbs[tid-96] = lnb[tid-96];
    if (tid >= 128 && tid < 160) gbias[tid-128] = gc_bias[tid-128];
    ((float*)Ws)[tid] = gc_W[tid];             // 256 threads, 256 elements (BUGFIX)
    for (int i = tid; i < GROWS*34; i += 256) ((float*)xf)[i] = x[(size_t)r0*34 + i];
    __syncthreads();

    // P1: c0/c1 per (row, i, n)
    for (int u = tid; u < GROWS*68; u += 256) {
        int row = u / 68, t = u % 68, i = t >> 2, n = t & 3;
        float a0 = 0.f, a1v = 0.f;
        #pragma unroll
        for (int j = 0; j < 17; ++j) {
            float a = As[n][i][j];
            a0  = fmaf(a, xf[row][2*j],   a0);
            a1v = fmaf(a, xf[row][2*j+1], a1v);
        }
        c0[row][t] = a0; c1[row][t] = a1v;
    }
    __syncthreads();

    // P2: scores
    float abv = ab[0];
    for (int u = tid; u < GROWS*68; u += 256) {
        int row = u / 68, t = u % 68, n = t & 3;
        float v0 = c0[row][t], v1 = c1[row][t];
        float acc = abv;
        #pragma unroll
        for (int o2 = 0; o2 < 32; ++o2) {
            float z = fmaf(v0, S0[n][o2], fmaf(v1, S1[n][o2], bqk[o2]));
            acc = fmaf(tanhf(z), aws[o2], acc);
        }
        sc[row][t] = acc;
    }
    __syncthreads();

    // P3: softmax over joints per (row, n); fold weight into c0/c1 in place
    if (tid < GROWS*4) {
        int row = tid >> 2, n = tid & 3;
        float m = -1e30f;
        for (int i = 0; i < 17; ++i) m = fmaxf(m, sc[row][i*4+n]);
        float w[17]; float s = 0.f;
        for (int i = 0; i < 17; ++i) { w[i] = expf(sc[row][i*4+n] - m); s += w[i]; }
        float inv = 1.f / s;
        for (int i = 0; i < 17; ++i) {
            float ww = w[i] * inv;
            c0[row][i*4+n] *= ww;
            c1[row][i*4+n] *= ww;
        }
    }
    __syncthreads();

    // P4: att + LN(32) + relu + pos_embed + store
    for (int u = tid; u < GROWS*JJ; u += 256) {
        int row = u / JJ, j = u % JJ;
        float e00=c0[row][j*4+0], e01=c0[row][j*4+1], e02=c0[row][j*4+2], e03=c0[row][j*4+3];
        float e10=c1[row][j*4+0], e11=c1[row][j*4+1], e12=c1[row][j*4+2], e13=c1[row][j*4+3];
        float att[32]; float mu = 0.f;
        #pragma unroll
        for (int o = 0; o < 32; ++o) {
            float a = gbias[o];
            a = fmaf(e00, Ws[0][0][o], a); a = fmaf(e10, Ws[0][1][o], a);
            a = fmaf(e01, Ws[1][0][o], a); a = fmaf(e11, Ws[1][1][o], a);
            a = fmaf(e02, Ws[2][0][o], a); a = fmaf(e12, Ws[2][1][o], a);
            a = fmaf(e03, Ws[3][0][o], a); a = fmaf(e13, Ws[3][1][o], a);
            att[o] = a; mu += a;
        }
        mu *= (1.f/32.f);
        float var = 0.f;
        #pragma unroll
        for (int o = 0; o < 32; ++o) { float d0 = att[o]-mu; var = fmaf(d0,d0,var); }
        float rstd = rsqrtf(var*(1.f/32.f) + 1e-5f);
        int r = r0 + row, f = r % FF;
        const float* pe = pos_embed + (size_t)f*EE + j*32;
        float* dst = xe + (size_t)r*EE + j*32;
        #pragma unroll
        for (int o = 0; o < 32; ++o) {
            float g0 = fmaxf((att[o]-mu)*rstd*lngs[o] + lnbs[o], 0.f);
            dst[o] = g0 + pe[o];
        }
    }
}

// ---------------- LN1 + per-joint LN + pooling-score ----------------
__global__ __launch_bounds__(256) void ln1_prelude_kernel(
    const float* __restrict__ xe,
    const float* __restrict__ g1, const float* __restrict__ b1,
    const float* __restrict__ ang, const float* __restrict__ anb,
    const float* __restrict__ apw, const float* __restrict__ apb,
    bf16* __restrict__ xr_out, float* __restrict__ s_out)
{
    __shared__ float row[544]; __shared__ float red[256];
    __shared__ float jm[17], jrs[17];
    int r = blockIdx.x, tid = threadIdx.x;
    float ls = 0.f;
    for (int e=tid;e<EE;e+=256){ float v=xe[(size_t)r*EE+e]; row[e]=v; ls+=v; }
    red[tid]=ls; __syncthreads();
    for(int st=128;st>0;st>>=1){ if(tid<st) red[tid]+=red[tid+st]; __syncthreads(); }
    float mean = red[0]*(1.f/544.f); __syncthreads();
    float lv = 0.f;
    for (int e=tid;e<EE;e+=256){ float d0=row[e]-mean; lv+=d0*d0; }
    red[tid]=lv; __syncthreads();
    for(int st=128;st>0;st>>=1){ if(tid<st) red[tid]+=red[tid+st]; __syncthreads(); }
    float rstd = rsqrtf(red[0]*(1.f/544.f)+1e-6f);
    for (int e=tid;e<EE;e+=256)
        row[e] = (row[e]-mean)*rstd*g1[e] + b1[e];
    __syncthreads();
    if (tid < 17) {
        float s0=0.f, s1=0.f;
        for (int o=0;o<32;++o){ float v=row[tid*32+o]; s0+=v; s1+=v*v; }
        float mu = s0*(1.f/32.f);
        jm[tid]=mu; jrs[tid]=rsqrtf(s1*(1.f/32.f)-mu*mu+1e-5f);
    }
    __syncthreads();
    for (int e=tid;e<EE;e+=256){
        int j=e>>5, o=e&31;
        float v = (row[e]-jm[j])*jrs[j]*ang[o] + anb[o];
        xr_out[(size_t)r*EE+e] = f2b(v);
        row[e] = v;
    }
    __syncthreads();
    if (tid < 17) {
        float acc = apb[0];
        for (int o=0;o<32;++o) acc += row[tid*32+o]*apw[o];
        s_out[(size_t)r*JJ+tid] = acc;
    }
}

// ---------------- softmax over frames ----------------
__global__ __launch_bounds__(256) void softmax_frames_kernel(float* __restrict__ s)
{
    int bid = blockIdx.x; int b = bid/JJ, j = bid%JJ;
    float* base = s + (size_t)b*FF*JJ + j;
    __shared__ float red[256];
    int tid = threadIdx.x;
    float v = -1e30f;
    if (tid < FF) v = base[(size_t)tid*JJ];
    red[tid]=v; __syncthreads();
    for(int st=128;st>0;st>>=1){ if(tid<st) red[tid]=fmaxf(red[tid],red[tid+st]); __syncthreads(); }
    float m = red[0]; __syncthreads();
    float e0 = (tid<FF) ? expf(v-m) : 0.f;
    red[tid]=e0; __syncthreads();
    for(int st=128;st>0;st>>=1){ if(tid<st) red[tid]+=red[tid+st]; __syncthreads(); }
    float inv = 1.f/red[0];
    if (tid<FF) base[(size_t)tid*JJ] = e0*inv;
}

// ---------------- xa = LN544(xr * wf) ----------------
__global__ __launch_bounds__(256) void lnC_kernel(
    const bf16* __restrict__ xr, const float* __restrict__ wf,
    const float* __restrict__ g, const float* __restrict__ b,
    bf16* __restrict__ xa)
{
    __shared__ float row[544]; __shared__ float red[256]; __shared__ float wloc[17];
    int r = blockIdx.x, tid = threadIdx.x;
    if (tid < 17) wloc[tid] = wf[(size_t)r*JJ + tid];
    __syncthreads();
    float ls = 0.f;
    for (int e=tid;e<EE;e+=256){ float v = b2f(xr[(size_t)r*EE+e])*wloc[e>>5]; row[e]=v; ls+=v; }
    red[tid]=ls; __syncthreads();
    for(int st=128;st>0;st>>=1){ if(tid<st) red[tid]+=red[tid+st]; __syncthreads(); }
    float mean = red[0]*(1.f/544.f); __syncthreads();
    float lv = 0.f;
    for (int e=tid;e<EE;e+=256){ float d0=row[e]-mean; lv+=d0*d0; }
    red[tid]=lv; __syncthreads();
    for(int st=128;st>0;st>>=1){ if(tid<st) red[tid]+=red[tid+st]; __syncthreads(); }
    float rstd = rsqrtf(red[0]*(1.f/544.f)+1e-5f);
    for (int e=tid;e<EE;e+=256)
        xa[(size_t)r*EE+e] = f2b((row[e]-mean)*rstd*g[e] + b[e]);
}

// ---------------- generic LN over 544 (fp32 in, bf16 out) ----------------
__global__ __launch_bounds__(256) void ln_row_kernel(
    const float* __restrict__ in, const float* __restrict__ g,
    const float* __restrict__ b, bf16* __restrict__ out, float eps)
{
    __shared__ float row[544]; __shared__ float red[256];
    int r = blockIdx.x, tid = threadIdx.x;
    float ls = 0.f;
    for (int e=tid;e<EE;e+=256){ float v=in[(size_t)r*EE+e]; row[e]=v; ls+=v; }
    red[tid]=ls; __syncthreads();
    for(int st=128;st>0;st>>=1){ if(tid<st) red[tid]+=red[tid+st]; __syncthreads(); }
    float mean = red[0]*(1.f/544.f); __syncthreads();
    float lv = 0.f;
    for (int e=tid;e<EE;e+=256){ float d0=row[e]-mean; lv+=d0*d0; }
    red[tid]=lv; __syncthreads();
    for(int st=128;st>0;st>>=1){ if(tid<st) red[tid]+=red[tid+st]; __syncthreads(); }
    float rstd = rsqrtf(red[0]*(1.f/544.f)+eps);
    for (int e=tid;e<EE;e+=256)
        out[(size_t)r*EE+e] = f2b((row[e]-mean)*rstd*g[e] + b[e]);
}

// ---------------- weight convert: fp32 [K][N] -> bf16 [Npad][K] (transpose+pad) ----
__global__ __launch_bounds__(256) void wconv_kernel(
    const float* __restrict__ W, unsigned short* __restrict__ out,
    int N, int K, int Npad)
{
    int idx = blockIdx.x * 256 + threadIdx.x;
    if (idx >= Npad * K) return;
    int n = idx % Npad, k = idx / Npad;
    float v = (n < N) ? W[(size_t)k*N + n] : 0.f;
    out[(size_t)n*K + k] = f2bu(v);
}

// ---------------- MFMA GEMM: C[M x N] = A[M x K](bf16) * Bt[Npad x K](bf16)^T ------
// tile 128x128, BK=32, 4 waves of 4x4 16x16x32 fragments
// mode 1: qkv scatter (bf16); mode 2: out_f32 += v; mode 3: gelu -> bf16; mode 4: fp32
__global__ __launch_bounds__(256) void mgemm_kernel(
    const unsigned short* __restrict__ A, const unsigned short* __restrict__ Bt,
    const float* __restrict__ bias,
    float* __restrict__ out_f32, unsigned short* __restrict__ qbuf,
    unsigned short* __restrict__ out_bf,
    int N, int K, int mode)
{
    __shared__ unsigned short As[128][40];
    __shared__ unsigned short Bs[128][40];
    int tid = threadIdx.x;
    int bm0 = blockIdx.y * 128, bn0 = blockIdx.x * 128;
    int wave = tid >> 6, lane = tid & 63;
    int wm = (wave >> 1) * 64, wn = (wave & 1) * 64;
    int quad = lane >> 4, l16 = lane & 15;
    floatx4 acc[4][4] = {};

    for (int k0 = 0; k0 < K; k0 += 32) {
        #pragma unroll
        for (int i = 0; i < 2; ++i) {
            int c = tid + i*256;
            int r = c >> 2, k8 = (c & 3) * 8;
            *(uint4*)&As[r][k8] = *(const uint4*)&A[(size_t)(bm0 + r)*K + k0 + k8];
            *(uint4*)&Bs[r][k8] = *(const uint4*)&Bt[(size_t)(bn0 + r)*K + k0 + k8];
        }
        __syncthreads();
        bf16x8 af[4], bfr[4];
        #pragma unroll
        for (int mi=0;mi<4;++mi) af[mi]  = *(const bf16x8*)&As[wm + mi*16 + l16][quad*8];
        #pragma unroll
        for (int ni=0;ni<4;++ni) bfr[ni] = *(const bf16x8*)&Bs[wn + ni*16 + l16][quad*8];
        #pragma unroll
        for (int mi=0;mi<4;++mi)
            #pragma unroll
            for (int ni=0;ni<4;++ni)
                acc[mi][ni] = __builtin_amdgcn_mfma_f32_16x16x32_bf16(af[mi], bfr[ni], acc[mi][ni], 0, 0, 0);
        __syncthreads();
    }

    #pragma unroll
    for (int mi=0;mi<4;++mi) {
        #pragma unroll
        for (int ni=0;ni<4;++ni) {
            #pragma unroll
            for (int r4=0;r4<4;++r4) {
                int gm = bm0 + wm + mi*16 + quad*4 + r4;
                int gn = bn0 + wn + ni*16 + l16;
                if (gn >= N) continue;
                float v = acc[mi][ni][r4] + bias[gn];
                if (mode == 1) {
                    int which = gn / 544, rem = gn % 544;
                    int hh = rem / 68, dd = rem % 68;
                    int b = gm / FF, f = gm % FF;
                    unsigned short* dst = qbuf + (size_t)which * QSTRIDE;
                    dst[((size_t)(b*NHH + hh)*FF + f)*HDD + dd] = f2bu(v);
                } else if (mode == 2) {
                    out_f32[(size_t)gm*N + gn] += v;
                } else if (mode == 3) {
                    float g = 0.5f * v * (1.0f + erff(v * 0.70710678118654752f));
                    out_bf[(size_t)gm*N + gn] = f2bu(g);
                } else {
                    out_f32[(size_t)gm*N + gn] = v;
                }
            }
        }
    }
}

// ---------------- flash attention: one block per (b,h), thread = query ----------
__global__ __launch_bounds__(256) void fattn_kernel(
    const unsigned short* __restrict__ q, const unsigned short* __restrict__ k,
    const unsigned short* __restrict__ v,
    const float* __restrict__ scaling_ptr, bf16* __restrict__ ao)
{
    __shared__ float Ksf[64][68];
    __shared__ float Vsf[64][68];
    __shared__ float ps_s[FF];
    int bh = blockIdx.x, tid = threadIdx.x;
    int b = bh >> 3, h = bh & 7;
    float scaling = scaling_ptr[0];
    const float SCALE = 0.12126781251816648f;  // 68^-0.5

    for (int i = tid; i < FF; i += 256) {
        float pos = i * (1.0f/242.0f) - 0.5f;
        ps_s[i] = SCALE * __expf(-scaling * pos * pos);
    }

    float qreg[68];
    int qi = tid;
    if (qi < FF) {
        const unsigned short* qp = q + ((size_t)bh*FF + qi)*HDD;
        #pragma unroll
        for (int d2 = 0; d2 < 34; ++d2) {
            unsigned u = *(const unsigned*)&qp[d2*2];
            qreg[d2*2]   = __uint_as_float(u << 16);
            qreg[d2*2+1] = __uint_as_float(u & 0xffff0000u);
        }
    }
    float acc[68];
    #pragma unroll
    for (int dd = 0; dd < 68; ++dd) acc[dd] = 0.f;
    float mmax = -1e30f, lsum = 0.f;

    const unsigned short* kbase = k + (size_t)bh*FF*HDD;
    const unsigned short* vbase = v + (size_t)bh*FF*HDD;

    for (int t = 0; t < 4; ++t) {
        int nk = (t == 3) ? (FF - 192) : 64;
        __syncthreads();
        for (int idx = tid; idx < nk*34; idx += 256) {
            int row = idx / 34, d2 = idx % 34;
            unsigned uk = *(const unsigned*)&kbase[((size_t)(t*64 + row))*HDD + d2*2];
            unsigned uv = *(const unsigned*)&vbase[((size_t)(t*64 + row))*HDD + d2*2];
            Ksf[row][d2*2]   = __uint_as_float(uk << 16);
            Ksf[row][d2*2+1] = __uint_as_float(uk & 0xffff0000u);
            Vsf[row][d2*2]   = __uint_as_float(uv << 16);
            Vsf[row][d2*2+1] = __uint_as_float(uv & 0xffff0000u);
        }
        __syncthreads();
        if (qi < FF) {
            for (int kk = 0; kk < nk; ++kk) {
                float d = 0.f;
                #pragma unroll
                for (int dq = 0; dq < 17; ++dq) {
                    float4 kvec = *(const float4*)&Ksf[kk][dq*4];
                    d = fmaf(qreg[dq*4+0], kvec.x, d);
                    d = fmaf(qreg[dq*4+1], kvec.y, d);
                    d = fmaf(qreg[dq*4+2], kvec.z, d);
                    d = fmaf(qreg[dq*4+3], kvec.w, d);
                }
                float s = d * ps_s[t*64 + kk];
                if (s > mmax) {
                    float corr = __expf(mmax - s);
                    lsum *= corr;
                    #pragma unroll
                    for (int dd = 0; dd < 68; ++dd) acc[dd] *= corr;
                    mmax = s;
                }
                float p = __expf(s - mmax);
                lsum += p;
                #pragma unroll
                for (int dq = 0; dq < 17; ++dq) {
                    float4 vv = *(const float4*)&Vsf[kk][dq*4];
                    acc[dq*4+0] = fmaf(p, vv.x, acc[dq*4+0]);
                    acc[dq*4+1] = fmaf(p, vv.y, acc[dq*4+1]);
                    acc[dq*4+2] = fmaf(p, vv.z, acc[dq*4+2]);
                    acc[dq*4+3] = fmaf(p, vv.w, acc[dq*4+3]);
                }
            }
        }
    }
    if (qi < FF) {
        float inv = 1.f / lsum;
        bf16* dst = ao + ((size_t)b*FF + qi)*EE + h*HDD;
        #pragma unroll
        for (int dd = 0; dd < 68; ++dd) dst[dd] = f2b(acc[dd] * inv);
    }
}

// ---------------- host launch ----------------
extern "C" void kernel_launch(void* const* d_in, const int* in_sizes, int n_in,
                              void* d_out, int out_size, void* d_ws, size_t ws_size,
                              hipStream_t stream) {
    typedef const float* fp;
    fp x          = (fp)d_in[0];
    fp gc_W       = (fp)d_in[2];
    fp gc_e       = (fp)d_in[3];
    fp gc_bias    = (fp)d_in[4];
    fp gc_q_w     = (fp)d_in[5];
    fp gc_q_b     = (fp)d_in[6];
    fp gc_k_w     = (fp)d_in[7];
    fp gc_k_b     = (fp)d_in[8];
    fp gc_attn_w  = (fp)d_in[9];
    fp gc_attn_b  = (fp)d_in[10];
    fp gc_ln_g    = (fp)d_in[11];
    fp gc_ln_b    = (fp)d_in[12];
    fp pos_embed  = (fp)d_in[13];
    fp blk1_g     = (fp)d_in[14];
    fp blk1_b     = (fp)d_in[15];
    fp at_g       = (fp)d_in[16];
    fp at_b       = (fp)d_in[17];
    fp at_pw      = (fp)d_in[18];
    fp at_pb      = (fp)d_in[19];
    fp at2_g      = (fp)d_in[20];
    fp at2_b      = (fp)d_in[21];
    fp at_scaling = (fp)d_in[22];
    fp qkv_w      = (fp)d_in[23];
    fp qkv_b      = (fp)d_in[24];
    fp proj_w     = (fp)d_in[25];
    fp proj_b     = (fp)d_in[26];
    fp blk2_g     = (fp)d_in[27];
    fp blk2_b     = (fp)d_in[28];
    fp fc1_w      = (fp)d_in[29];
    fp fc1_b      = (fp)d_in[30];
    fp fc2_w      = (fp)d_in[31];
    fp fc2_b      = (fp)d_in[32];
    fp fin_g      = (fp)d_in[33];
    fp fin_b      = (fp)d_in[34];
    fp head_w     = (fp)d_in[35];
    fp head_b     = (fp)d_in[36];

    // ---- workspace layout (bytes, 256-aligned), total ~244.5 MB ----
    char* wsb = (char*)d_ws;
    size_t off = 0;
    auto alloc = [&](size_t bytes) { size_t cur = off; off += (bytes + 255) & ~(size_t)255; return cur; };
    float* Aw   = (float*)(wsb + alloc(1156 * 4));
    float* Sg   = (float*)(wsb + alloc(288 * 4));
    float* xe   = (float*)(wsb + alloc(QSTRIDE * 4));
    float* sbuf = (float*)(wsb + alloc((size_t)ROWS*JJ * 4));
    bf16*  xr   = (bf16*) (wsb + alloc(QSTRIDE * 2));          // xr; reused as ao
    bf16*  xa   = (bf16*) (wsb + alloc(QSTRIDE * 2));          // xa; reused as xn2/xo
    bf16*  qkv  = (bf16*) (wsb + alloc(3 * QSTRIDE * 2));      // q,k,v; reused as hm
    unsigned short* wq = (unsigned short*)(wsb + alloc((size_t)1664*544 * 2));
    unsigned short* wp = (unsigned short*)(wsb + alloc((size_t)640*544 * 2));
    unsigned short* w1 = (unsigned short*)(wsb + alloc((size_t)1152*544 * 2));
    unsigned short* w2 = (unsigned short*)(wsb + alloc((size_t)640*1088 * 2));
    (void)ws_size;

    prep_kernel<<<1, 256, 0, stream>>>(gc_e, gc_W, gc_q_w, gc_k_w, gc_q_b, gc_k_b, Aw, Sg);
    gc2_kernel<<<ROWS/GROWS, 256, 0, stream>>>(
        x, Aw, Sg, gc_W, gc_bias, gc_attn_w, gc_attn_b,
        gc_ln_g, gc_ln_b, pos_embed, xe);
    for (int d = 0; d < 4; ++d) {
        wconv_kernel<<<(1664*544 + 255)/256, 256, 0, stream>>>(
            qkv_w + (size_t)d*EE*3*EE, wq, 1632, 544, 1664);
        wconv_kernel<<<(640*544 + 255)/256, 256, 0, stream>>>(
            proj_w + (size_t)d*EE*EE, wp, 544, 544, 640);
        wconv_kernel<<<(1152*544 + 255)/256, 256, 0, stream>>>(
            fc1_w + (size_t)d*EE*HIDD, w1, 1088, 544, 1152);
        wconv_kernel<<<(640*1088 + 255)/256, 256, 0, stream>>>(
            fc2_w + (size_t)d*HIDD*EE, w2, 544, 1088, 640);

        ln1_prelude_kernel<<<ROWS, 256, 0, stream>>>(
            xe, blk1_g + d*EE, blk1_b + d*EE, at_g + d*ERR, at_b + d*ERR,
            at_pw + d*ERR, at_pb + d, xr, sbuf);
        softmax_frames_kernel<<<BB*JJ, 256, 0, stream>>>(sbuf);
        lnC_kernel<<<ROWS, 256, 0, stream>>>(xr, sbuf, at2_g + d*EE, at2_b + d*EE, xa);
        mgemm_kernel<<<dim3(13, 243), 256, 0, stream>>>(
            (const unsigned short*)xa, wq, qkv_b + d*3*EE,
            nullptr, (unsigned short*)qkv, nullptr, 1632, 544, 1);
        fattn_kernel<<<BB*NHH, 256, 0, stream>>>(
            (const unsigned short*)qkv, (const unsigned short*)qkv + QSTRIDE,
            (const unsigned short*)qkv + 2*QSTRIDE, at_scaling + d, xr);
        mgemm_kernel<<<dim3(5, 243), 256, 0, stream>>>(
            (const unsigned short*)xr, wp, proj_b + d*EE,
            xe, nullptr, nullptr, 544, 544, 2);
        ln_row_kernel<<<ROWS, 256, 0, stream>>>(xe, blk2_g + d*EE, blk2_b + d*EE, xa, 1e-6f);
        mgemm_kernel<<<dim3(9, 243), 256, 0, stream>>>(
            (const unsigned short*)xa, w1, fc1_b + d*HIDD,
            nullptr, nullptr, (unsigned short*)qkv, 1088, 544, 3);   // hm into qkv region
        mgemm_kernel<<<dim3(5, 243), 256, 0, stream>>>(
            (const unsigned short*)qkv, w2, fc2_b + d*EE,
            xe, nullptr, nullptr, 544, 1088, 2);
    }
    ln_row_kernel<<<ROWS, 256, 0, stream>>>(xe, fin_g, fin_b, xa, 1e-6f);
    wconv_kernel<<<(128*544 + 255)/256, 256, 0, stream>>>(head_w, wq, 51, 544, 128);
    mgemm_kernel<<<dim3(1, 243), 256, 0, stream>>>(
        (const unsigned short*)xa, wq, head_b,
        (float*)d_out, nullptr, nullptr, 51, 544, 4);
}

// Round 7
// 4147.239 us; speedup vs baseline: 7.2717x; 1.1661x over previous
//
#include <hip/hip_runtime.h>
#include <hip/hip_bf16.h>
#include <math.h>

// ---------------- constants ----------------
#define BB 128
#define FF 243
#define JJ 17
#define ERR 32
#define EE 544
#define NHH 8
#define HDD 68
#define HIDD 1088
#define ROWS 31104          // B*F
#define QSTRIDE 16920576ULL // ROWS*EE
#define GROWS 16            // rows per gc2 block

typedef __hip_bfloat16 bf16;
typedef __bf16 bf16x8 __attribute__((ext_vector_type(8)));
typedef float floatx4 __attribute__((ext_vector_type(4)));

static __device__ __forceinline__ float b2f(bf16 v) { return __bfloat162float(v); }
static __device__ __forceinline__ bf16 f2b(float v) { return __float2bfloat16(v); }
static __device__ __forceinline__ unsigned short f2bu(float v) {
    bf16 h = __float2bfloat16(v);
    return *(unsigned short*)&h;
}
// async global->LDS, 16B per lane; dest = wave-uniform base + lane*16
static __device__ __forceinline__ void async16(void* lds, const void* g) {
    __builtin_amdgcn_global_load_lds(
        (const __attribute__((address_space(1))) unsigned*)g,
        (__attribute__((address_space(3))) unsigned*)lds, 16, 0, 0);
}

// ---------------- prep: adjacency softmax + folded q/k projection ----------------
__global__ __launch_bounds__(256) void prep_kernel(
    const float* __restrict__ gc_e, const float* __restrict__ gc_W,
    const float* __restrict__ qw, const float* __restrict__ kw,
    const float* __restrict__ qb, const float* __restrict__ kb,
    float* __restrict__ A, float* __restrict__ Sg)
{
    __shared__ float a1[17][17], a2[17][17], a3[17][17];
    int tid = threadIdx.x;
    const int parents[17] = {-1,0,1,2,0,4,5,0,7,8,9,8,11,12,8,14,15};
    if (tid == 0) {
        for (int i=0;i<17;++i) for (int j=0;j<17;++j) a1[i][j]=0.f;
        for (int c=0;c<17;++c){ int p=parents[c]; if(p>=0){ a1[c][p]=1.f; a1[p][c]=1.f; } }
        for (int i=0;i<17;++i) for (int j=0;j<17;++j){ float s=0; for(int k=0;k<17;++k) s+=a1[i][k]*a1[k][j]; a2[i][j]=s; }
        for (int i=0;i<17;++i) for (int j=0;j<17;++j){ float s=0; for(int k=0;k<17;++k) s+=a2[i][k]*a1[k][j]; a3[i][j]=s; }
    }
    __syncthreads();
    for (int p = tid; p < 68; p += 256) {
        int n = p / 17, i = p % 17;
        bool msk[17];
        float m = -1e30f;
        for (int j=0;j<17;++j) {
            bool mm;
            if (n==0) mm = (i==j);
            else if (n==1) mm = a1[i][j] > 0.f;
            else if (n==2) mm = a2[i][j] > 0.f;
            else mm = a3[i][j] > 0.f;
            msk[j] = mm;
            if (mm) m = fmaxf(m, gc_e[(n*17+i)*17+j]);
        }
        float ex[17]; float s=0.f;
        for (int j=0;j<17;++j){ ex[j] = msk[j] ? expf(gc_e[(n*17+i)*17+j]-m) : 0.f; s+=ex[j]; }
        float inv = 1.f/s;
        for (int j=0;j<17;++j) A[(n*17+i)*17+j] = ex[j]*inv;
    }
    if (tid < 256) {
        int c = tid >> 7, n = (tid >> 5) & 3, o2 = tid & 31;
        float s = 0.f;
        for (int o = 0; o < 32; ++o)
            s += gc_W[(n*2+c)*32 + o] * (qw[o*32+o2] + kw[o*32+o2]);
        Sg[tid] = s;
    }
    if (tid < 32) Sg[256 + tid] = qb[tid] + kb[tid];
}

// ---------------- gc2: fused graph conv, 16 rows per block ----------------
__global__ __launch_bounds__(256) void gc2_kernel(
    const float* __restrict__ x, const float* __restrict__ A, const float* __restrict__ Sg,
    const float* __restrict__ gc_W, const float* __restrict__ gc_bias,
    const float* __restrict__ aw, const float* __restrict__ ab,
    const float* __restrict__ lng, const float* __restrict__ lnb,
    const float* __restrict__ pos_embed, float* __restrict__ xe)
{
    __shared__ float As[4][17][17];
    __shared__ float S0[4][32], S1[4][32], bqk[32];
    __shared__ float Ws[4][2][32];
    __shared__ float aws[32], lngs[32], lnbs[32], gbias[32];
    __shared__ float xf[GROWS][34];
    __shared__ float c0[GROWS][68], c1[GROWS][68];
    __shared__ float sc[GROWS][68];
    int tid = threadIdx.x;
    int r0 = blockIdx.x * GROWS;

    for (int i = tid; i < 1156; i += 256) ((float*)As)[i] = A[i];
    if (tid < 128) ((float*)S0)[tid] = Sg[tid];
    else ((float*)S1)[tid-128] = Sg[tid];
    if (tid < 32) bqk[tid] = Sg[256+tid];
    if (tid >= 32 && tid < 64)  aws[tid-32]  = aw[tid-32];
    if (tid >= 64 && tid < 96)  lngs[tid-64] = lng[tid-64];
    if (tid >= 96 && tid < 128) lnbs[tid-96] = lnb[tid-96];
    if (tid >= 128 && tid < 160) gbias[tid-128] = gc_bias[tid-128];
    ((float*)Ws)[tid] = gc_W[tid];
    for (int i = tid; i < GROWS*34; i += 256) ((float*)xf)[i] = x[(size_t)r0*34 + i];
    __syncthreads();

    for (int u = tid; u < GROWS*68; u += 256) {
        int row = u / 68, t = u % 68, i = t >> 2, n = t & 3;
        float a0 = 0.f, a1v = 0.f;
        #pragma unroll
        for (int j = 0; j < 17; ++j) {
            float a = As[n][i][j];
            a0  = fmaf(a, xf[row][2*j],   a0);
            a1v = fmaf(a, xf[row][2*j+1], a1v);
        }
        c0[row][t] = a0; c1[row][t] = a1v;
    }
    __syncthreads();

    float abv = ab[0];
    for (int u = tid; u < GROWS*68; u += 256) {
        int row = u / 68, t = u % 68, n = t & 3;
        float v0 = c0[row][t], v1 = c1[row][t];
        float acc = abv;
        #pragma unroll
        for (int o2 = 0; o2 < 32; ++o2) {
            float z = fmaf(v0, S0[n][o2], fmaf(v1, S1[n][o2], bqk[o2]));
            acc = fmaf(tanhf(z), aws[o2], acc);
        }
        sc[row][t] = acc;
    }
    __syncthreads();

    if (tid < GROWS*4) {
        int row = tid >> 2, n = tid & 3;
        float m = -1e30f;
        for (int i = 0; i < 17; ++i) m = fmaxf(m, sc[row][i*4+n]);
        float w[17]; float s = 0.f;
        for (int i = 0; i < 17; ++i) { w[i] = expf(sc[row][i*4+n] - m); s += w[i]; }
        float inv = 1.f / s;
        for (int i = 0; i < 17; ++i) {
            float ww = w[i] * inv;
            c0[row][i*4+n] *= ww;
            c1[row][i*4+n] *= ww;
        }
    }
    __syncthreads();

    for (int u = tid; u < GROWS*JJ; u += 256) {
        int row = u / JJ, j = u % JJ;
        float e00=c0[row][j*4+0], e01=c0[row][j*4+1], e02=c0[row][j*4+2], e03=c0[row][j*4+3];
        float e10=c1[row][j*4+0], e11=c1[row][j*4+1], e12=c1[row][j*4+2], e13=c1[row][j*4+3];
        float att[32]; float mu = 0.f;
        #pragma unroll
        for (int o = 0; o < 32; ++o) {
            float a = gbias[o];
            a = fmaf(e00, Ws[0][0][o], a); a = fmaf(e10, Ws[0][1][o], a);
            a = fmaf(e01, Ws[1][0][o], a); a = fmaf(e11, Ws[1][1][o], a);
            a = fmaf(e02, Ws[2][0][o], a); a = fmaf(e12, Ws[2][1][o], a);
            a = fmaf(e03, Ws[3][0][o], a); a = fmaf(e13, Ws[3][1][o], a);
            att[o] = a; mu += a;
        }
        mu *= (1.f/32.f);
        float var = 0.f;
        #pragma unroll
        for (int o = 0; o < 32; ++o) { float d0 = att[o]-mu; var = fmaf(d0,d0,var); }
        float rstd = rsqrtf(var*(1.f/32.f) + 1e-5f);
        int r = r0 + row, f = r % FF;
        const float* pe = pos_embed + (size_t)f*EE + j*32;
        float* dst = xe + (size_t)r*EE + j*32;
        #pragma unroll
        for (int o = 0; o < 32; ++o) {
            float g0 = fmaxf((att[o]-mu)*rstd*lngs[o] + lnbs[o], 0.f);
            dst[o] = g0 + pe[o];
        }
    }
}

// ---------------- LN1 + per-joint LN + pooling-score ----------------
__global__ __launch_bounds__(256) void ln1_prelude_kernel(
    const float* __restrict__ xe,
    const float* __restrict__ g1, const float* __restrict__ b1,
    const float* __restrict__ ang, const float* __restrict__ anb,
    const float* __restrict__ apw, const float* __restrict__ apb,
    bf16* __restrict__ xr_out, float* __restrict__ s_out)
{
    __shared__ float row[544]; __shared__ float red[256];
    __shared__ float jm[17], jrs[17];
    int r = blockIdx.x, tid = threadIdx.x;
    float ls = 0.f;
    for (int e=tid;e<EE;e+=256){ float v=xe[(size_t)r*EE+e]; row[e]=v; ls+=v; }
    red[tid]=ls; __syncthreads();
    for(int st=128;st>0;st>>=1){ if(tid<st) red[tid]+=red[tid+st]; __syncthreads(); }
    float mean = red[0]*(1.f/544.f); __syncthreads();
    float lv = 0.f;
    for (int e=tid;e<EE;e+=256){ float d0=row[e]-mean; lv+=d0*d0; }
    red[tid]=lv; __syncthreads();
    for(int st=128;st>0;st>>=1){ if(tid<st) red[tid]+=red[tid+st]; __syncthreads(); }
    float rstd = rsqrtf(red[0]*(1.f/544.f)+1e-6f);
    for (int e=tid;e<EE;e+=256)
        row[e] = (row[e]-mean)*rstd*g1[e] + b1[e];
    __syncthreads();
    if (tid < 17) {
        float s0=0.f, s1=0.f;
        for (int o=0;o<32;++o){ float v=row[tid*32+o]; s0+=v; s1+=v*v; }
        float mu = s0*(1.f/32.f);
        jm[tid]=mu; jrs[tid]=rsqrtf(s1*(1.f/32.f)-mu*mu+1e-5f);
    }
    __syncthreads();
    for (int e=tid;e<EE;e+=256){
        int j=e>>5, o=e&31;
        float v = (row[e]-jm[j])*jrs[j]*ang[o] + anb[o];
        xr_out[(size_t)r*EE+e] = f2b(v);
        row[e] = v;
    }
    __syncthreads();
    if (tid < 17) {
        float acc = apb[0];
        for (int o=0;o<32;++o) acc += row[tid*32+o]*apw[o];
        s_out[(size_t)r*JJ+tid] = acc;
    }
}

// ---------------- softmax over frames ----------------
__global__ __launch_bounds__(256) void softmax_frames_kernel(float* __restrict__ s)
{
    int bid = blockIdx.x; int b = bid/JJ, j = bid%JJ;
    float* base = s + (size_t)b*FF*JJ + j;
    __shared__ float red[256];
    int tid = threadIdx.x;
    float v = -1e30f;
    if (tid < FF) v = base[(size_t)tid*JJ];
    red[tid]=v; __syncthreads();
    for(int st=128;st>0;st>>=1){ if(tid<st) red[tid]=fmaxf(red[tid],red[tid+st]); __syncthreads(); }
    float m = red[0]; __syncthreads();
    float e0 = (tid<FF) ? expf(v-m) : 0.f;
    red[tid]=e0; __syncthreads();
    for(int st=128;st>0;st>>=1){ if(tid<st) red[tid]+=red[tid+st]; __syncthreads(); }
    float inv = 1.f/red[0];
    if (tid<FF) base[(size_t)tid*JJ] = e0*inv;
}

// ---------------- xa = LN544(xr * wf) ----------------
__global__ __launch_bounds__(256) void lnC_kernel(
    const bf16* __restrict__ xr, const float* __restrict__ wf,
    const float* __restrict__ g, const float* __restrict__ b,
    bf16* __restrict__ xa)
{
    __shared__ float row[544]; __shared__ float red[256]; __shared__ float wloc[17];
    int r = blockIdx.x, tid = threadIdx.x;
    if (tid < 17) wloc[tid] = wf[(size_t)r*JJ + tid];
    __syncthreads();
    float ls = 0.f;
    for (int e=tid;e<EE;e+=256){ float v = b2f(xr[(size_t)r*EE+e])*wloc[e>>5]; row[e]=v; ls+=v; }
    red[tid]=ls; __syncthreads();
    for(int st=128;st>0;st>>=1){ if(tid<st) red[tid]+=red[tid+st]; __syncthreads(); }
    float mean = red[0]*(1.f/544.f); __syncthreads();
    float lv = 0.f;
    for (int e=tid;e<EE;e+=256){ float d0=row[e]-mean; lv+=d0*d0; }
    red[tid]=lv; __syncthreads();
    for(int st=128;st>0;st>>=1){ if(tid<st) red[tid]+=red[tid+st]; __syncthreads(); }
    float rstd = rsqrtf(red[0]*(1.f/544.f)+1e-5f);
    for (int e=tid;e<EE;e+=256)
        xa[(size_t)r*EE+e] = f2b((row[e]-mean)*rstd*g[e] + b[e]);
}

// ---------------- generic LN over 544 (fp32 in, bf16 out) ----------------
__global__ __launch_bounds__(256) void ln_row_kernel(
    const float* __restrict__ in, const float* __restrict__ g,
    const float* __restrict__ b, bf16* __restrict__ out, float eps)
{
    __shared__ float row[544]; __shared__ float red[256];
    int r = blockIdx.x, tid = threadIdx.x;
    float ls = 0.f;
    for (int e=tid;e<EE;e+=256){ float v=in[(size_t)r*EE+e]; row[e]=v; ls+=v; }
    red[tid]=ls; __syncthreads();
    for(int st=128;st>0;st>>=1){ if(tid<st) red[tid]+=red[tid+st]; __syncthreads(); }
    float mean = red[0]*(1.f/544.f); __syncthreads();
    float lv = 0.f;
    for (int e=tid;e<EE;e+=256){ float d0=row[e]-mean; lv+=d0*d0; }
    red[tid]=lv; __syncthreads();
    for(int st=128;st>0;st>>=1){ if(tid<st) red[tid]+=red[tid+st]; __syncthreads(); }
    float rstd = rsqrtf(red[0]*(1.f/544.f)+eps);
    for (int e=tid;e<EE;e+=256)
        out[(size_t)r*EE+e] = f2b((row[e]-mean)*rstd*g[e] + b[e]);
}

// ---------------- weight convert: fp32 [K][N] -> bf16 [Npad][K] (transpose+pad) ----
__global__ __launch_bounds__(256) void wconv_kernel(
    const float* __restrict__ W, unsigned short* __restrict__ out,
    int N, int K, int Npad)
{
    int idx = blockIdx.x * 256 + threadIdx.x;
    if (idx >= Npad * K) return;
    int n = idx % Npad, k = idx / Npad;
    float v = (n < N) ? W[(size_t)k*N + n] : 0.f;
    out[(size_t)n*K + k] = f2bu(v);
}

// ---------------- MFMA GEMM with async staging ----------------
// tile 128x128, BK=32; LDS [128][32] unpadded, filled by global_load_lds(16B)
// source chunk XOR-swizzled by (row&3) to cut frag-read bank conflicts.
__global__ __launch_bounds__(256) void mgemm_kernel(
    const unsigned short* __restrict__ A, const unsigned short* __restrict__ Bt,
    const float* __restrict__ bias,
    float* __restrict__ out_f32, unsigned short* __restrict__ qbuf,
    unsigned short* __restrict__ out_bf,
    int N, int K, int mode)
{
    __shared__ unsigned short As[128][32];
    __shared__ unsigned short Bs[128][32];
    int tid = threadIdx.x;
    int bm0 = blockIdx.y * 128, bn0 = blockIdx.x * 128;
    int wave = tid >> 6, lane = tid & 63;
    int wm = (wave >> 1) * 64, wn = (wave & 1) * 64;
    int quad = lane >> 4, l16 = lane & 15;
    int srow0 = wave * 32;            // rows staged by this wave
    int lr = lane >> 2, lc = lane & 3;
    floatx4 acc[4][4] = {};

    for (int k0 = 0; k0 < K; k0 += 32) {
        #pragma unroll
        for (int i = 0; i < 2; ++i) {
            int row = srow0 + i*16 + lr;
            int gch = lc ^ (row & 3);
            async16(&As[srow0 + i*16][0], &A [(size_t)(bm0 + row)*K + k0 + gch*8]);
            async16(&Bs[srow0 + i*16][0], &Bt[(size_t)(bn0 + row)*K + k0 + gch*8]);
        }
        __syncthreads();
        bf16x8 af[4], bfr[4];
        #pragma unroll
        for (int mi=0;mi<4;++mi) {
            int r = wm + mi*16 + l16;
            af[mi] = *(const bf16x8*)&As[r][(quad ^ (r & 3))*8];
        }
        #pragma unroll
        for (int ni=0;ni<4;++ni) {
            int r = wn + ni*16 + l16;
            bfr[ni] = *(const bf16x8*)&Bs[r][(quad ^ (r & 3))*8];
        }
        #pragma unroll
        for (int mi=0;mi<4;++mi)
            #pragma unroll
            for (int ni=0;ni<4;++ni)
                acc[mi][ni] = __builtin_amdgcn_mfma_f32_16x16x32_bf16(af[mi], bfr[ni], acc[mi][ni], 0, 0, 0);
        __syncthreads();
    }

    #pragma unroll
    for (int mi=0;mi<4;++mi) {
        #pragma unroll
        for (int ni=0;ni<4;++ni) {
            #pragma unroll
            for (int r4=0;r4<4;++r4) {
                int gm = bm0 + wm + mi*16 + quad*4 + r4;
                int gn = bn0 + wn + ni*16 + l16;
                if (gn >= N) continue;
                float v = acc[mi][ni][r4] + bias[gn];
                if (mode == 1) {
                    int which = gn / 544, rem = gn % 544;
                    int hh = rem / 68, dd = rem % 68;
                    int b = gm / FF, f = gm % FF;
                    unsigned short* dst = qbuf + (size_t)which * QSTRIDE;
                    dst[((size_t)(b*NHH + hh)*FF + f)*HDD + dd] = f2bu(v);
                } else if (mode == 2) {
                    out_f32[(size_t)gm*N + gn] += v;
                } else if (mode == 3) {
                    float g = 0.5f * v * (1.0f + erff(v * 0.70710678118654752f));
                    out_bf[(size_t)gm*N + gn] = f2bu(g);
                } else {
                    out_f32[(size_t)gm*N + gn] = v;
                }
            }
        }
    }
}

// ---------------- MFMA flash attention: block = (64-query tile, bh) ------------
// Q k-padded 68->96, keys padded 243->256 (masked). P normalized in-reg, bf16.
__global__ __launch_bounds__(256) void fattn_kernel(
    const unsigned short* __restrict__ q, const unsigned short* __restrict__ k,
    const unsigned short* __restrict__ v,
    const float* __restrict__ scaling_ptr, bf16* __restrict__ ao)
{
    __shared__ unsigned short Qs[64][104];
    __shared__ unsigned short Ks[256][104];   // reused as Ps[64][264] in phase 2
    __shared__ unsigned short Vt[80][264];    // V transposed [dim][key]
    __shared__ float ps_s[256];
    typedef unsigned short (*ps_t)[264];
    ps_t Ps = (ps_t)&Ks[0][0];

    int qt = blockIdx.x, bh = blockIdx.y;
    int tid = threadIdx.x;
    int q0 = qt * 64;
    int nq = FF - q0; if (nq > 64) nq = 64;
    float scaling = scaling_ptr[0];
    const float SCALE = 0.12126781251816648f;  // 68^-0.5

    // phase 0: scale table + zero pads + stage Q,K,V^T
    if (tid < 256) {
        float pos = tid * (1.0f/242.0f) - 0.5f;
        ps_s[tid] = (tid < FF) ? SCALE * __expf(-scaling * pos * pos) : 0.f;
    }
    for (int idx = tid; idx < 64*18; idx += 256) {          // Qs cols 68..103 = 0
        int r = idx / 18, c2 = idx % 18;
        *(unsigned*)&Qs[r][68 + c2*2] = 0u;
    }
    for (int idx = tid; idx < 256*18; idx += 256) {         // Ks cols 68..103 = 0
        int r = idx / 18, c2 = idx % 18;
        *(unsigned*)&Ks[r][68 + c2*2] = 0u;
    }
    for (int idx = tid; idx < 80*13; idx += 256) {          // Vt keys 243..255 = 0
        int dd = idx / 13, kk2 = 243 + idx % 13;
        Vt[dd][kk2] = 0;
    }
    const unsigned short* qbase = q + ((size_t)bh*FF + q0)*HDD;
    for (int idx = tid; idx < nq*34; idx += 256) {
        int r = idx / 34, c2 = idx % 34;
        *(unsigned*)&Qs[r][c2*2] = *(const unsigned*)&qbase[r*HDD + c2*2];
    }
    const unsigned short* kbase = k + (size_t)bh*FF*HDD;
    for (int idx = tid; idx < FF*34; idx += 256) {
        int r = idx / 34, c2 = idx % 34;
        *(unsigned*)&Ks[r][c2*2] = *(const unsigned*)&kbase[r*HDD + c2*2];
    }
    const unsigned short* vbase = v + (size_t)bh*FF*HDD;
    for (int idx = tid; idx < FF*34; idx += 256) {
        int r = idx / 34, c2 = idx % 34;
        unsigned uv = *(const unsigned*)&vbase[r*HDD + c2*2];
        Vt[c2*2][r]   = (unsigned short)(uv & 0xffffu);
        Vt[c2*2+1][r] = (unsigned short)(uv >> 16);
    }
    __syncthreads();

    int wave = tid >> 6, lane = tid & 63;
    int quad = lane >> 4, l16 = lane & 15;

    // phase 1: S = Q K^T for this wave's 16 queries
    bf16x8 aq[3];
    #pragma unroll
    for (int kk = 0; kk < 3; ++kk)
        aq[kk] = *(const bf16x8*)&Qs[wave*16 + l16][kk*32 + quad*8];
    floatx4 sacc[16];
    #pragma unroll
    for (int nt = 0; nt < 16; ++nt) {
        floatx4 c = {};
        #pragma unroll
        for (int kk = 0; kk < 3; ++kk) {
            bf16x8 bk = *(const bf16x8*)&Ks[nt*16 + l16][kk*32 + quad*8];
            c = __builtin_amdgcn_mfma_f32_16x16x32_bf16(aq[kk], bk, c, 0, 0, 0);
        }
        sacc[nt] = c;
    }

    // scale + mask + row softmax (row = quad*4+reg; cols across l16 & nt)
    float rmax[4] = {-1e30f, -1e30f, -1e30f, -1e30f};
    #pragma unroll
    for (int nt = 0; nt < 16; ++nt) {
        float psc = ps_s[nt*16 + l16];
        bool maskc = (nt*16 + l16) >= FF;
        #pragma unroll
        for (int rg = 0; rg < 4; ++rg) {
            float s = maskc ? -1e30f : sacc[nt][rg] * psc;
            sacc[nt][rg] = s;
            rmax[rg] = fmaxf(rmax[rg], s);
        }
    }
    #pragma unroll
    for (int rg = 0; rg < 4; ++rg) {
        float m0 = rmax[rg];
        m0 = fmaxf(m0, __shfl_xor(m0, 1));
        m0 = fmaxf(m0, __shfl_xor(m0, 2));
        m0 = fmaxf(m0, __shfl_xor(m0, 4));
        m0 = fmaxf(m0, __shfl_xor(m0, 8));
        rmax[rg] = m0;
    }
    float rs[4] = {0.f, 0.f, 0.f, 0.f};
    #pragma unroll
    for (int nt = 0; nt < 16; ++nt)
        #pragma unroll
        for (int rg = 0; rg < 4; ++rg) {
            float p = __expf(sacc[nt][rg] - rmax[rg]);
            sacc[nt][rg] = p;
            rs[rg] += p;
        }
    #pragma unroll
    for (int rg = 0; rg < 4; ++rg) {
        float s0 = rs[rg];
        s0 += __shfl_xor(s0, 1);
        s0 += __shfl_xor(s0, 2);
        s0 += __shfl_xor(s0, 4);
        s0 += __shfl_xor(s0, 8);
        rs[rg] = 1.f / s0;
    }

    __syncthreads();   // all waves done reading Ks before Ps overwrites it
    #pragma unroll
    for (int nt = 0; nt < 16; ++nt)
        #pragma unroll
        for (int rg = 0; rg < 4; ++rg)
            Ps[wave*16 + quad*4 + rg][nt*16 + l16] = f2bu(sacc[nt][rg] * rs[rg]);
    __syncthreads();

    // phase 2: O = P V
    bf16x8 ap[8];
    #pragma unroll
    for (int kk = 0; kk < 8; ++kk)
        ap[kk] = *(const bf16x8*)&Ps[wave*16 + l16][kk*32 + quad*8];
    int b = bh >> 3, h = bh & 7;
    #pragma unroll
    for (int nt = 0; nt < 5; ++nt) {
        floatx4 c = {};
        #pragma unroll
        for (int kk = 0; kk < 8; ++kk) {
            bf16x8 bv = *(const bf16x8*)&Vt[nt*16 + l16][kk*32 + quad*8];
            c = __builtin_amdgcn_mfma_f32_16x16x32_bf16(ap[kk], bv, c, 0, 0, 0);
        }
        int gn = nt*16 + l16;
        if (gn < HDD) {
            #pragma unroll
            for (int rg = 0; rg < 4; ++rg) {
                int query = q0 + wave*16 + quad*4 + rg;
                if (query < FF)
                    ao[((size_t)b*FF + query)*EE + h*HDD + gn] = f2b(c[rg]);
            }
        }
    }
}

// ---------------- host launch ----------------
extern "C" void kernel_launch(void* const* d_in, const int* in_sizes, int n_in,
                              void* d_out, int out_size, void* d_ws, size_t ws_size,
                              hipStream_t stream) {
    typedef const float* fp;
    fp x          = (fp)d_in[0];
    fp gc_W       = (fp)d_in[2];
    fp gc_e       = (fp)d_in[3];
    fp gc_bias    = (fp)d_in[4];
    fp gc_q_w     = (fp)d_in[5];
    fp gc_q_b     = (fp)d_in[6];
    fp gc_k_w     = (fp)d_in[7];
    fp gc_k_b     = (fp)d_in[8];
    fp gc_attn_w  = (fp)d_in[9];
    fp gc_attn_b  = (fp)d_in[10];
    fp gc_ln_g    = (fp)d_in[11];
    fp gc_ln_b    = (fp)d_in[12];
    fp pos_embed  = (fp)d_in[13];
    fp blk1_g     = (fp)d_in[14];
    fp blk1_b     = (fp)d_in[15];
    fp at_g       = (fp)d_in[16];
    fp at_b       = (fp)d_in[17];
    fp at_pw      = (fp)d_in[18];
    fp at_pb      = (fp)d_in[19];
    fp at2_g      = (fp)d_in[20];
    fp at2_b      = (fp)d_in[21];
    fp at_scaling = (fp)d_in[22];
    fp qkv_w      = (fp)d_in[23];
    fp qkv_b      = (fp)d_in[24];
    fp proj_w     = (fp)d_in[25];
    fp proj_b     = (fp)d_in[26];
    fp blk2_g     = (fp)d_in[27];
    fp blk2_b     = (fp)d_in[28];
    fp fc1_w      = (fp)d_in[29];
    fp fc1_b      = (fp)d_in[30];
    fp fc2_w      = (fp)d_in[31];
    fp fc2_b      = (fp)d_in[32];
    fp fin_g      = (fp)d_in[33];
    fp fin_b      = (fp)d_in[34];
    fp head_w     = (fp)d_in[35];
    fp head_b     = (fp)d_in[36];

    char* wsb = (char*)d_ws;
    size_t off = 0;
    auto alloc = [&](size_t bytes) { size_t cur = off; off += (bytes + 255) & ~(size_t)255; return cur; };
    float* Aw   = (float*)(wsb + alloc(1156 * 4));
    float* Sg   = (float*)(wsb + alloc(288 * 4));
    float* xe   = (float*)(wsb + alloc(QSTRIDE * 4));
    float* sbuf = (float*)(wsb + alloc((size_t)ROWS*JJ * 4));
    bf16*  xr   = (bf16*) (wsb + alloc(QSTRIDE * 2));          // xr; reused as ao
    bf16*  xa   = (bf16*) (wsb + alloc(QSTRIDE * 2));          // xa; reused as xn2/xo
    bf16*  qkv  = (bf16*) (wsb + alloc(3 * QSTRIDE * 2));      // q,k,v; reused as hm
    unsigned short* wq = (unsigned short*)(wsb + alloc((size_t)1664*544 * 2));
    unsigned short* wp = (unsigned short*)(wsb + alloc((size_t)640*544 * 2));
    unsigned short* w1 = (unsigned short*)(wsb + alloc((size_t)1152*544 * 2));
    unsigned short* w2 = (unsigned short*)(wsb + alloc((size_t)640*1088 * 2));
    (void)ws_size;

    prep_kernel<<<1, 256, 0, stream>>>(gc_e, gc_W, gc_q_w, gc_k_w, gc_q_b, gc_k_b, Aw, Sg);
    gc2_kernel<<<ROWS/GROWS, 256, 0, stream>>>(
        x, Aw, Sg, gc_W, gc_bias, gc_attn_w, gc_attn_b,
        gc_ln_g, gc_ln_b, pos_embed, xe);
    for (int d = 0; d < 4; ++d) {
        wconv_kernel<<<(1664*544 + 255)/256, 256, 0, stream>>>(
            qkv_w + (size_t)d*EE*3*EE, wq, 1632, 544, 1664);
        wconv_kernel<<<(640*544 + 255)/256, 256, 0, stream>>>(
            proj_w + (size_t)d*EE*EE, wp, 544, 544, 640);
        wconv_kernel<<<(1152*544 + 255)/256, 256, 0, stream>>>(
            fc1_w + (size_t)d*EE*HIDD, w1, 1088, 544, 1152);
        wconv_kernel<<<(640*1088 + 255)/256, 256, 0, stream>>>(
            fc2_w + (size_t)d*HIDD*EE, w2, 544, 1088, 640);

        ln1_prelude_kernel<<<ROWS, 256, 0, stream>>>(
            xe, blk1_g + d*EE, blk1_b + d*EE, at_g + d*ERR, at_b + d*ERR,
            at_pw + d*ERR, at_pb + d, xr, sbuf);
        softmax_frames_kernel<<<BB*JJ, 256, 0, stream>>>(sbuf);
        lnC_kernel<<<ROWS, 256, 0, stream>>>(xr, sbuf, at2_g + d*EE, at2_b + d*EE, xa);
        mgemm_kernel<<<dim3(13, 243), 256, 0, stream>>>(
            (const unsigned short*)xa, wq, qkv_b + d*3*EE,
            nullptr, (unsigned short*)qkv, nullptr, 1632, 544, 1);
        fattn_kernel<<<dim3(4, BB*NHH), 256, 0, stream>>>(
            (const unsigned short*)qkv, (const unsigned short*)qkv + QSTRIDE,
            (const unsigned short*)qkv + 2*QSTRIDE, at_scaling + d, xr);
        mgemm_kernel<<<dim3(5, 243), 256, 0, stream>>>(
            (const unsigned short*)xr, wp, proj_b + d*EE,
            xe, nullptr, nullptr, 544, 544, 2);
        ln_row_kernel<<<ROWS, 256, 0, stream>>>(xe, blk2_g + d*EE, blk2_b + d*EE, xa, 1e-6f);
        mgemm_kernel<<<dim3(9, 243), 256, 0, stream>>>(
            (const unsigned short*)xa, w1, fc1_b + d*HIDD,
            nullptr, nullptr, (unsigned short*)qkv, 1088, 544, 3);   // hm into qkv region
        mgemm_kernel<<<dim3(5, 243), 256, 0, stream>>>(
            (const unsigned short*)qkv, w2, fc2_b + d*EE,
            xe, nullptr, nullptr, 544, 1088, 2);
    }
    ln_row_kernel<<<ROWS, 256, 0, stream>>>(xe, fin_g, fin_b, xa, 1e-6f);
    wconv_kernel<<<(128*544 + 255)/256, 256, 0, stream>>>(head_w, wq, 51, 544, 128);
    mgemm_kernel<<<dim3(1, 243), 256, 0, stream>>>(
        (const unsigned short*)xa, wq, head_b,
        (float*)d_out, nullptr, nullptr, 51, 544, 4);
}

// Round 8
// 3541.726 us; speedup vs baseline: 8.5150x; 1.1710x over previous
//
#include <hip/hip_runtime.h>
#include <hip/hip_bf16.h>
#include <math.h>

// ---------------- constants ----------------
#define BB 128
#define FF 243
#define JJ 17
#define ERR 32
#define EE 544
#define NHH 8
#define HDD 68
#define HIDD 1088
#define ROWS 31104          // B*F
#define QSTRIDE 16920576ULL // ROWS*EE
#define GROWS 16            // rows per gc2 block

typedef __hip_bfloat16 bf16;
typedef __bf16 bf16x8 __attribute__((ext_vector_type(8)));
typedef float floatx4 __attribute__((ext_vector_type(4)));

static __device__ __forceinline__ float b2f(bf16 v) { return __bfloat162float(v); }
static __device__ __forceinline__ bf16 f2b(float v) { return __float2bfloat16(v); }
static __device__ __forceinline__ unsigned short f2bu(float v) {
    bf16 h = __float2bfloat16(v);
    return *(unsigned short*)&h;
}
// async global->LDS, 16B per lane; dest = wave-uniform base + lane*16
static __device__ __forceinline__ void async16(void* lds, const void* g) {
    __builtin_amdgcn_global_load_lds(
        (const __attribute__((address_space(1))) unsigned*)g,
        (__attribute__((address_space(3))) unsigned*)lds, 16, 0, 0);
}

// ---------------- prep: adjacency softmax + folded q/k projection ----------------
__global__ __launch_bounds__(256) void prep_kernel(
    const float* __restrict__ gc_e, const float* __restrict__ gc_W,
    const float* __restrict__ qw, const float* __restrict__ kw,
    const float* __restrict__ qb, const float* __restrict__ kb,
    float* __restrict__ A, float* __restrict__ Sg)
{
    __shared__ float a1[17][17], a2[17][17], a3[17][17];
    int tid = threadIdx.x;
    const int parents[17] = {-1,0,1,2,0,4,5,0,7,8,9,8,11,12,8,14,15};
    if (tid == 0) {
        for (int i=0;i<17;++i) for (int j=0;j<17;++j) a1[i][j]=0.f;
        for (int c=0;c<17;++c){ int p=parents[c]; if(p>=0){ a1[c][p]=1.f; a1[p][c]=1.f; } }
        for (int i=0;i<17;++i) for (int j=0;j<17;++j){ float s=0; for(int k=0;k<17;++k) s+=a1[i][k]*a1[k][j]; a2[i][j]=s; }
        for (int i=0;i<17;++i) for (int j=0;j<17;++j){ float s=0; for(int k=0;k<17;++k) s+=a2[i][k]*a1[k][j]; a3[i][j]=s; }
    }
    __syncthreads();
    for (int p = tid; p < 68; p += 256) {
        int n = p / 17, i = p % 17;
        bool msk[17];
        float m = -1e30f;
        for (int j=0;j<17;++j) {
            bool mm;
            if (n==0) mm = (i==j);
            else if (n==1) mm = a1[i][j] > 0.f;
            else if (n==2) mm = a2[i][j] > 0.f;
            else mm = a3[i][j] > 0.f;
            msk[j] = mm;
            if (mm) m = fmaxf(m, gc_e[(n*17+i)*17+j]);
        }
        float ex[17]; float s=0.f;
        for (int j=0;j<17;++j){ ex[j] = msk[j] ? expf(gc_e[(n*17+i)*17+j]-m) : 0.f; s+=ex[j]; }
        float inv = 1.f/s;
        for (int j=0;j<17;++j) A[(n*17+i)*17+j] = ex[j]*inv;
    }
    if (tid < 256) {
        int c = tid >> 7, n = (tid >> 5) & 3, o2 = tid & 31;
        float s = 0.f;
        for (int o = 0; o < 32; ++o)
            s += gc_W[(n*2+c)*32 + o] * (qw[o*32+o2] + kw[o*32+o2]);
        Sg[tid] = s;
    }
    if (tid < 32) Sg[256 + tid] = qb[tid] + kb[tid];
}

// ---------------- gc2: fused graph conv, 16 rows per block ----------------
__global__ __launch_bounds__(256) void gc2_kernel(
    const float* __restrict__ x, const float* __restrict__ A, const float* __restrict__ Sg,
    const float* __restrict__ gc_W, const float* __restrict__ gc_bias,
    const float* __restrict__ aw, const float* __restrict__ ab,
    const float* __restrict__ lng, const float* __restrict__ lnb,
    const float* __restrict__ pos_embed, float* __restrict__ xe)
{
    __shared__ float As[4][17][17];
    __shared__ float S0[4][33], S1[4][33], bqk[32];   // padded: kill 4-way bank conflict
    __shared__ float Ws[4][2][32];
    __shared__ float aws[32], lngs[32], lnbs[32], gbias[32];
    __shared__ float xf[GROWS][34];
    __shared__ float c0[GROWS][68], c1[GROWS][68];
    __shared__ float sc[GROWS][68];
    int tid = threadIdx.x;
    int r0 = blockIdx.x * GROWS;

    for (int i = tid; i < 1156; i += 256) ((float*)As)[i] = A[i];
    if (tid < 128) S0[tid>>5][tid&31] = Sg[tid];
    else           S1[(tid-128)>>5][(tid-128)&31] = Sg[tid];
    if (tid < 32) bqk[tid] = Sg[256+tid];
    if (tid >= 32 && tid < 64)  aws[tid-32]  = aw[tid-32];
    if (tid >= 64 && tid < 96)  lngs[tid-64] = lng[tid-64];
    if (tid >= 96 && tid < 128) lnbs[tid-96] = lnb[tid-96];
    if (tid >= 128 && tid < 160) gbias[tid-128] = gc_bias[tid-128];
    ((float*)Ws)[tid] = gc_W[tid];
    for (int i = tid; i < GROWS*34; i += 256) ((float*)xf)[i] = x[(size_t)r0*34 + i];
    __syncthreads();

    // P1: c0/c1 per (row, i, n)
    for (int u = tid; u < GROWS*68; u += 256) {
        int row = u / 68, t = u % 68, i = t >> 2, n = t & 3;
        float a0 = 0.f, a1v = 0.f;
        #pragma unroll
        for (int j = 0; j < 17; ++j) {
            float a = As[n][i][j];
            a0  = fmaf(a, xf[row][2*j],   a0);
            a1v = fmaf(a, xf[row][2*j+1], a1v);
        }
        c0[row][t] = a0; c1[row][t] = a1v;
    }
    __syncthreads();

    // P2: scores
    float abv = ab[0];
    for (int u = tid; u < GROWS*68; u += 256) {
        int row = u / 68, t = u % 68, n = t & 3;
        float v0 = c0[row][t], v1 = c1[row][t];
        float acc = abv;
        #pragma unroll
        for (int o2 = 0; o2 < 32; ++o2) {
            float z = fmaf(v0, S0[n][o2], fmaf(v1, S1[n][o2], bqk[o2]));
            acc = fmaf(tanhf(z), aws[o2], acc);
        }
        sc[row][t] = acc;
    }
    __syncthreads();

    // P3: softmax over joints per (row, n); fold weight into c0/c1 in place
    if (tid < GROWS*4) {
        int row = tid >> 2, n = tid & 3;
        float m = -1e30f;
        for (int i = 0; i < 17; ++i) m = fmaxf(m, sc[row][i*4+n]);
        float w[17]; float s = 0.f;
        for (int i = 0; i < 17; ++i) { w[i] = expf(sc[row][i*4+n] - m); s += w[i]; }
        float inv = 1.f / s;
        for (int i = 0; i < 17; ++i) {
            float ww = w[i] * inv;
            c0[row][i*4+n] *= ww;
            c1[row][i*4+n] *= ww;
        }
    }
    __syncthreads();

    // P4: 16 lanes per (row,j); each lane owns outputs o and o+16.
    int g16 = tid >> 4, lg = tid & 15;
    for (int pair = g16; pair < GROWS*JJ; pair += 16) {
        int row = pair / JJ, j = pair % JJ;
        float e00=c0[row][j*4+0], e01=c0[row][j*4+1], e02=c0[row][j*4+2], e03=c0[row][j*4+3];
        float e10=c1[row][j*4+0], e11=c1[row][j*4+1], e12=c1[row][j*4+2], e13=c1[row][j*4+3];
        int o0 = lg, o1 = lg + 16;
        float a0 = gbias[o0], a1 = gbias[o1];
        a0 = fmaf(e00, Ws[0][0][o0], a0); a0 = fmaf(e10, Ws[0][1][o0], a0);
        a0 = fmaf(e01, Ws[1][0][o0], a0); a0 = fmaf(e11, Ws[1][1][o0], a0);
        a0 = fmaf(e02, Ws[2][0][o0], a0); a0 = fmaf(e12, Ws[2][1][o0], a0);
        a0 = fmaf(e03, Ws[3][0][o0], a0); a0 = fmaf(e13, Ws[3][1][o0], a0);
        a1 = fmaf(e00, Ws[0][0][o1], a1); a1 = fmaf(e10, Ws[0][1][o1], a1);
        a1 = fmaf(e01, Ws[1][0][o1], a1); a1 = fmaf(e11, Ws[1][1][o1], a1);
        a1 = fmaf(e02, Ws[2][0][o1], a1); a1 = fmaf(e12, Ws[2][1][o1], a1);
        a1 = fmaf(e03, Ws[3][0][o1], a1); a1 = fmaf(e13, Ws[3][1][o1], a1);
        float ssum = a0 + a1;
        ssum += __shfl_xor(ssum, 1); ssum += __shfl_xor(ssum, 2);
        ssum += __shfl_xor(ssum, 4); ssum += __shfl_xor(ssum, 8);
        float mu = ssum * (1.f/32.f);
        float d0 = a0 - mu, d1 = a1 - mu;
        float vv = d0*d0 + d1*d1;
        vv += __shfl_xor(vv, 1); vv += __shfl_xor(vv, 2);
        vv += __shfl_xor(vv, 4); vv += __shfl_xor(vv, 8);
        float rstd = rsqrtf(vv*(1.f/32.f) + 1e-5f);
        int r = r0 + row, f = r % FF;
        const float* pe = pos_embed + (size_t)f*EE + j*32;
        float* dst = xe + (size_t)r*EE + j*32;
        dst[o0] = fmaxf(d0*rstd*lngs[o0] + lnbs[o0], 0.f) + pe[o0];
        dst[o1] = fmaxf(d1*rstd*lngs[o1] + lnbs[o1], 0.f) + pe[o1];
    }
}

// ---------------- LN1 + per-joint LN + pooling-score (wave per row, 4 rows/block) --
__global__ __launch_bounds__(256) void ln1_prelude_kernel(
    const float* __restrict__ xe,
    const float* __restrict__ g1, const float* __restrict__ b1,
    const float* __restrict__ ang, const float* __restrict__ anb,
    const float* __restrict__ apw, const float* __restrict__ apb,
    bf16* __restrict__ xr_out, float* __restrict__ s_out)
{
    __shared__ float rowbuf[4][561];     // joint-padded stride 33
    __shared__ float jm[4][17], jrs[4][17];
    __shared__ float angs[32], anbs[32], apws[32];
    int tid = threadIdx.x, w = tid >> 6, lane = tid & 63;
    int r = blockIdx.x*4 + w;
    if (tid < 32) { angs[tid]=ang[tid]; anbs[tid]=anb[tid]; apws[tid]=apw[tid]; }
    float vals[9];
    float ls = 0.f;
    #pragma unroll
    for (int s=0;s<9;++s){ int e=s*64+lane; if(e<EE){ float v=xe[(size_t)r*EE+e]; vals[s]=v; ls+=v; } else vals[s]=0.f; }
    #pragma unroll
    for (int m=1;m<64;m<<=1) ls += __shfl_xor(ls, m);
    float mean = ls*(1.f/544.f);
    float lv = 0.f;
    #pragma unroll
    for (int s=0;s<9;++s){ int e=s*64+lane; if(e<EE){ float d=vals[s]-mean; lv+=d*d; } }
    #pragma unroll
    for (int m=1;m<64;m<<=1) lv += __shfl_xor(lv, m);
    float rstd = rsqrtf(lv*(1.f/544.f)+1e-6f);
    #pragma unroll
    for (int s=0;s<9;++s){ int e=s*64+lane; if(e<EE)
        rowbuf[w][(e>>5)*33+(e&31)] = (vals[s]-mean)*rstd*g1[e] + b1[e]; }
    __syncthreads();
    if (lane < 17) {
        float s0=0.f, s1=0.f;
        for (int o=0;o<32;++o){ float v=rowbuf[w][lane*33+o]; s0+=v; s1+=v*v; }
        float mu = s0*(1.f/32.f);
        jm[w][lane]=mu; jrs[w][lane]=rsqrtf(s1*(1.f/32.f)-mu*mu+1e-5f);
    }
    __syncthreads();
    #pragma unroll
    for (int s=0;s<9;++s){ int e=s*64+lane; if(e<EE){
        int j=e>>5, o=e&31;
        float v = (rowbuf[w][j*33+o]-jm[w][j])*jrs[w][j]*angs[o] + anbs[o];
        xr_out[(size_t)r*EE+e] = f2b(v);
        rowbuf[w][j*33+o] = v; } }
    __syncthreads();
    if (lane < 17) {
        float acc = apb[0];
        for (int o=0;o<32;++o) acc += rowbuf[w][lane*33+o]*apws[o];
        s_out[(size_t)r*JJ+lane] = acc;
    }
}

// ---------------- softmax over frames (wave per (b,joint)) ----------------
__global__ __launch_bounds__(256) void softmax_frames_kernel(float* __restrict__ s)
{
    int tid = threadIdx.x, w = tid >> 6, lane = tid & 63;
    int bid = blockIdx.x*4 + w; int b = bid/JJ, j = bid%JJ;
    float* base = s + (size_t)b*FF*JJ + j;
    float v[4]; float m = -1e30f;
    #pragma unroll
    for (int s2=0;s2<4;++s2){ int e=s2*64+lane;
        v[s2] = (e<FF) ? base[(size_t)e*JJ] : -1e30f;
        m = fmaxf(m, v[s2]); }
    #pragma unroll
    for (int mm=1;mm<64;mm<<=1) m = fmaxf(m, __shfl_xor(m, mm));
    float lsum = 0.f;
    #pragma unroll
    for (int s2=0;s2<4;++s2){ int e=s2*64+lane;
        if (e<FF){ v[s2] = __expf(v[s2]-m); lsum += v[s2]; } }
    #pragma unroll
    for (int mm=1;mm<64;mm<<=1) lsum += __shfl_xor(lsum, mm);
    float inv = 1.f/lsum;
    #pragma unroll
    for (int s2=0;s2<4;++s2){ int e=s2*64+lane;
        if (e<FF) base[(size_t)e*JJ] = v[s2]*inv; }
}

// ---------------- xa = LN544(xr * wf) (wave per row) ----------------
__global__ __launch_bounds__(256) void lnC_kernel(
    const bf16* __restrict__ xr, const float* __restrict__ wf,
    const float* __restrict__ g, const float* __restrict__ b,
    bf16* __restrict__ xa)
{
    __shared__ float wfb[4][17];
    int tid = threadIdx.x, w = tid >> 6, lane = tid & 63;
    int r = blockIdx.x*4 + w;
    if (lane < 17) wfb[w][lane] = wf[(size_t)r*JJ + lane];
    __syncthreads();
    float vals[9]; float ls = 0.f;
    #pragma unroll
    for (int s=0;s<9;++s){ int e=s*64+lane; if(e<EE){
        float v = b2f(xr[(size_t)r*EE+e])*wfb[w][e>>5]; vals[s]=v; ls+=v; } else vals[s]=0.f; }
    #pragma unroll
    for (int m=1;m<64;m<<=1) ls += __shfl_xor(ls, m);
    float mean = ls*(1.f/544.f);
    float lv = 0.f;
    #pragma unroll
    for (int s=0;s<9;++s){ int e=s*64+lane; if(e<EE){ float d=vals[s]-mean; lv+=d*d; } }
    #pragma unroll
    for (int m=1;m<64;m<<=1) lv += __shfl_xor(lv, m);
    float rstd = rsqrtf(lv*(1.f/544.f)+1e-5f);
    #pragma unroll
    for (int s=0;s<9;++s){ int e=s*64+lane; if(e<EE)
        xa[(size_t)r*EE+e] = f2b((vals[s]-mean)*rstd*g[e] + b[e]); }
}

// ---------------- generic LN over 544 (wave per row, no LDS) ----------------
__global__ __launch_bounds__(256) void ln_row_kernel(
    const float* __restrict__ in, const float* __restrict__ g,
    const float* __restrict__ b, bf16* __restrict__ out, float eps)
{
    int tid = threadIdx.x, w = tid >> 6, lane = tid & 63;
    int r = blockIdx.x*4 + w;
    float vals[9]; float ls = 0.f;
    #pragma unroll
    for (int s=0;s<9;++s){ int e=s*64+lane; if(e<EE){ float v=in[(size_t)r*EE+e]; vals[s]=v; ls+=v; } else vals[s]=0.f; }
    #pragma unroll
    for (int m=1;m<64;m<<=1) ls += __shfl_xor(ls, m);
    float mean = ls*(1.f/544.f);
    float lv = 0.f;
    #pragma unroll
    for (int s=0;s<9;++s){ int e=s*64+lane; if(e<EE){ float d=vals[s]-mean; lv+=d*d; } }
    #pragma unroll
    for (int m=1;m<64;m<<=1) lv += __shfl_xor(lv, m);
    float rstd = rsqrtf(lv*(1.f/544.f)+eps);
    #pragma unroll
    for (int s=0;s<9;++s){ int e=s*64+lane; if(e<EE)
        out[(size_t)r*EE+e] = f2b((vals[s]-mean)*rstd*g[e] + b[e]); }
}

// ---------------- weight convert: fp32 [K][N] -> bf16 [Npad][K] (transpose+pad) ----
__global__ __launch_bounds__(256) void wconv_kernel(
    const float* __restrict__ W, unsigned short* __restrict__ out,
    int N, int K, int Npad)
{
    int idx = blockIdx.x * 256 + threadIdx.x;
    if (idx >= Npad * K) return;
    int n = idx % Npad, k = idx / Npad;
    float v = (n < N) ? W[(size_t)k*N + n] : 0.f;
    out[(size_t)n*K + k] = f2bu(v);
}

// ---------------- MFMA GEMM with async staging ----------------
__global__ __launch_bounds__(256) void mgemm_kernel(
    const unsigned short* __restrict__ A, const unsigned short* __restrict__ Bt,
    const float* __restrict__ bias,
    float* __restrict__ out_f32, unsigned short* __restrict__ qbuf,
    unsigned short* __restrict__ out_bf,
    int N, int K, int mode)
{
    __shared__ unsigned short As[128][32];
    __shared__ unsigned short Bs[128][32];
    int tid = threadIdx.x;
    int bm0 = blockIdx.y * 128, bn0 = blockIdx.x * 128;
    int wave = tid >> 6, lane = tid & 63;
    int wm = (wave >> 1) * 64, wn = (wave & 1) * 64;
    int quad = lane >> 4, l16 = lane & 15;
    int srow0 = wave * 32;
    int lr = lane >> 2, lc = lane & 3;
    floatx4 acc[4][4] = {};

    for (int k0 = 0; k0 < K; k0 += 32) {
        #pragma unroll
        for (int i = 0; i < 2; ++i) {
            int row = srow0 + i*16 + lr;
            int gch = lc ^ (row & 3);
            async16(&As[srow0 + i*16][0], &A [(size_t)(bm0 + row)*K + k0 + gch*8]);
            async16(&Bs[srow0 + i*16][0], &Bt[(size_t)(bn0 + row)*K + k0 + gch*8]);
        }
        __syncthreads();
        bf16x8 af[4], bfr[4];
        #pragma unroll
        for (int mi=0;mi<4;++mi) {
            int r = wm + mi*16 + l16;
            af[mi] = *(const bf16x8*)&As[r][(quad ^ (r & 3))*8];
        }
        #pragma unroll
        for (int ni=0;ni<4;++ni) {
            int r = wn + ni*16 + l16;
            bfr[ni] = *(const bf16x8*)&Bs[r][(quad ^ (r & 3))*8];
        }
        #pragma unroll
        for (int mi=0;mi<4;++mi)
            #pragma unroll
            for (int ni=0;ni<4;++ni)
                acc[mi][ni] = __builtin_amdgcn_mfma_f32_16x16x32_bf16(af[mi], bfr[ni], acc[mi][ni], 0, 0, 0);
        __syncthreads();
    }

    #pragma unroll
    for (int mi=0;mi<4;++mi) {
        #pragma unroll
        for (int ni=0;ni<4;++ni) {
            #pragma unroll
            for (int r4=0;r4<4;++r4) {
                int gm = bm0 + wm + mi*16 + quad*4 + r4;
                int gn = bn0 + wn + ni*16 + l16;
                if (gn >= N) continue;
                float v = acc[mi][ni][r4] + bias[gn];
                if (mode == 1) {
                    int which = gn / 544, rem = gn % 544;
                    int hh = rem / 68, dd = rem % 68;
                    int b = gm / FF, f = gm % FF;
                    unsigned short* dst = qbuf + (size_t)which * QSTRIDE;
                    dst[((size_t)(b*NHH + hh)*FF + f)*HDD + dd] = f2bu(v);
                } else if (mode == 2) {
                    out_f32[(size_t)gm*N + gn] += v;
                } else if (mode == 3) {
                    float g = 0.5f * v * (1.0f + erff(v * 0.70710678118654752f));
                    out_bf[(size_t)gm*N + gn] = f2bu(g);
                } else {
                    out_f32[(size_t)gm*N + gn] = v;
                }
            }
        }
    }
}

// ---------------- MFMA flash attention: block = (64-query tile, bh) ------------
__global__ __launch_bounds__(256) void fattn_kernel(
    const unsigned short* __restrict__ q, const unsigned short* __restrict__ k,
    const unsigned short* __restrict__ v,
    const float* __restrict__ scaling_ptr, bf16* __restrict__ ao)
{
    __shared__ unsigned short Qs[64][104];
    __shared__ unsigned short Ks[256][104];   // reused as Ps[64][264] in phase 2
    __shared__ unsigned short Vt[80][264];    // V transposed [dim][key]
    __shared__ float ps_s[256];
    typedef unsigned short (*ps_t)[264];
    ps_t Ps = (ps_t)&Ks[0][0];

    int qt = blockIdx.x, bh = blockIdx.y;
    int tid = threadIdx.x;
    int q0 = qt * 64;
    int nq = FF - q0; if (nq > 64) nq = 64;
    float scaling = scaling_ptr[0];
    const float SCALE = 0.12126781251816648f;  // 68^-0.5

    if (tid < 256) {
        float pos = tid * (1.0f/242.0f) - 0.5f;
        ps_s[tid] = (tid < FF) ? SCALE * __expf(-scaling * pos * pos) : 0.f;
    }
    for (int idx = tid; idx < 64*18; idx += 256) {
        int r = idx / 18, c2 = idx % 18;
        *(unsigned*)&Qs[r][68 + c2*2] = 0u;
    }
    for (int idx = tid; idx < 256*18; idx += 256) {
        int r = idx / 18, c2 = idx % 18;
        *(unsigned*)&Ks[r][68 + c2*2] = 0u;
    }
    for (int idx = tid; idx < 80*13; idx += 256) {
        int dd = idx / 13, kk2 = 243 + idx % 13;
        Vt[dd][kk2] = 0;
    }
    const unsigned short* qbase = q + ((size_t)bh*FF + q0)*HDD;
    for (int idx = tid; idx < nq*34; idx += 256) {
        int r = idx / 34, c2 = idx % 34;
        *(unsigned*)&Qs[r][c2*2] = *(const unsigned*)&qbase[r*HDD + c2*2];
    }
    const unsigned short* kbase = k + (size_t)bh*FF*HDD;
    for (int idx = tid; idx < FF*34; idx += 256) {
        int r = idx / 34, c2 = idx % 34;
        *(unsigned*)&Ks[r][c2*2] = *(const unsigned*)&kbase[r*HDD + c2*2];
    }
    const unsigned short* vbase = v + (size_t)bh*FF*HDD;
    for (int idx = tid; idx < FF*34; idx += 256) {
        int r = idx / 34, c2 = idx % 34;
        unsigned uv = *(const unsigned*)&vbase[r*HDD + c2*2];
        Vt[c2*2][r]   = (unsigned short)(uv & 0xffffu);
        Vt[c2*2+1][r] = (unsigned short)(uv >> 16);
    }
    __syncthreads();

    int wave = tid >> 6, lane = tid & 63;
    int quad = lane >> 4, l16 = lane & 15;

    bf16x8 aq[3];
    #pragma unroll
    for (int kk = 0; kk < 3; ++kk)
        aq[kk] = *(const bf16x8*)&Qs[wave*16 + l16][kk*32 + quad*8];
    floatx4 sacc[16];
    #pragma unroll
    for (int nt = 0; nt < 16; ++nt) {
        floatx4 c = {};
        #pragma unroll
        for (int kk = 0; kk < 3; ++kk) {
            bf16x8 bk = *(const bf16x8*)&Ks[nt*16 + l16][kk*32 + quad*8];
            c = __builtin_amdgcn_mfma_f32_16x16x32_bf16(aq[kk], bk, c, 0, 0, 0);
        }
        sacc[nt] = c;
    }

    float rmax[4] = {-1e30f, -1e30f, -1e30f, -1e30f};
    #pragma unroll
    for (int nt = 0; nt < 16; ++nt) {
        float psc = ps_s[nt*16 + l16];
        bool maskc = (nt*16 + l16) >= FF;
        #pragma unroll
        for (int rg = 0; rg < 4; ++rg) {
            float s = maskc ? -1e30f : sacc[nt][rg] * psc;
            sacc[nt][rg] = s;
            rmax[rg] = fmaxf(rmax[rg], s);
        }
    }
    #pragma unroll
    for (int rg = 0; rg < 4; ++rg) {
        float m0 = rmax[rg];
        m0 = fmaxf(m0, __shfl_xor(m0, 1));
        m0 = fmaxf(m0, __shfl_xor(m0, 2));
        m0 = fmaxf(m0, __shfl_xor(m0, 4));
        m0 = fmaxf(m0, __shfl_xor(m0, 8));
        rmax[rg] = m0;
    }
    float rs[4] = {0.f, 0.f, 0.f, 0.f};
    #pragma unroll
    for (int nt = 0; nt < 16; ++nt)
        #pragma unroll
        for (int rg = 0; rg < 4; ++rg) {
            float p = __expf(sacc[nt][rg] - rmax[rg]);
            sacc[nt][rg] = p;
            rs[rg] += p;
        }
    #pragma unroll
    for (int rg = 0; rg < 4; ++rg) {
        float s0 = rs[rg];
        s0 += __shfl_xor(s0, 1);
        s0 += __shfl_xor(s0, 2);
        s0 += __shfl_xor(s0, 4);
        s0 += __shfl_xor(s0, 8);
        rs[rg] = 1.f / s0;
    }

    __syncthreads();
    #pragma unroll
    for (int nt = 0; nt < 16; ++nt)
        #pragma unroll
        for (int rg = 0; rg < 4; ++rg)
            Ps[wave*16 + quad*4 + rg][nt*16 + l16] = f2bu(sacc[nt][rg] * rs[rg]);
    __syncthreads();

    bf16x8 ap[8];
    #pragma unroll
    for (int kk = 0; kk < 8; ++kk)
        ap[kk] = *(const bf16x8*)&Ps[wave*16 + l16][kk*32 + quad*8];
    int b = bh >> 3, h = bh & 7;
    #pragma unroll
    for (int nt = 0; nt < 5; ++nt) {
        floatx4 c = {};
        #pragma unroll
        for (int kk = 0; kk < 8; ++kk) {
            bf16x8 bv = *(const bf16x8*)&Vt[nt*16 + l16][kk*32 + quad*8];
            c = __builtin_amdgcn_mfma_f32_16x16x32_bf16(ap[kk], bv, c, 0, 0, 0);
        }
        int gn = nt*16 + l16;
        if (gn < HDD) {
            #pragma unroll
            for (int rg = 0; rg < 4; ++rg) {
                int query = q0 + wave*16 + quad*4 + rg;
                if (query < FF)
                    ao[((size_t)b*FF + query)*EE + h*HDD + gn] = f2b(c[rg]);
            }
        }
    }
}

// ---------------- host launch ----------------
extern "C" void kernel_launch(void* const* d_in, const int* in_sizes, int n_in,
                              void* d_out, int out_size, void* d_ws, size_t ws_size,
                              hipStream_t stream) {
    typedef const float* fp;
    fp x          = (fp)d_in[0];
    fp gc_W       = (fp)d_in[2];
    fp gc_e       = (fp)d_in[3];
    fp gc_bias    = (fp)d_in[4];
    fp gc_q_w     = (fp)d_in[5];
    fp gc_q_b     = (fp)d_in[6];
    fp gc_k_w     = (fp)d_in[7];
    fp gc_k_b     = (fp)d_in[8];
    fp gc_attn_w  = (fp)d_in[9];
    fp gc_attn_b  = (fp)d_in[10];
    fp gc_ln_g    = (fp)d_in[11];
    fp gc_ln_b    = (fp)d_in[12];
    fp pos_embed  = (fp)d_in[13];
    fp blk1_g     = (fp)d_in[14];
    fp blk1_b     = (fp)d_in[15];
    fp at_g       = (fp)d_in[16];
    fp at_b       = (fp)d_in[17];
    fp at_pw      = (fp)d_in[18];
    fp at_pb      = (fp)d_in[19];
    fp at2_g      = (fp)d_in[20];
    fp at2_b      = (fp)d_in[21];
    fp at_scaling = (fp)d_in[22];
    fp qkv_w      = (fp)d_in[23];
    fp qkv_b      = (fp)d_in[24];
    fp proj_w     = (fp)d_in[25];
    fp proj_b     = (fp)d_in[26];
    fp blk2_g     = (fp)d_in[27];
    fp blk2_b     = (fp)d_in[28];
    fp fc1_w      = (fp)d_in[29];
    fp fc1_b      = (fp)d_in[30];
    fp fc2_w      = (fp)d_in[31];
    fp fc2_b      = (fp)d_in[32];
    fp fin_g      = (fp)d_in[33];
    fp fin_b      = (fp)d_in[34];
    fp head_w     = (fp)d_in[35];
    fp head_b     = (fp)d_in[36];

    char* wsb = (char*)d_ws;
    size_t off = 0;
    auto alloc = [&](size_t bytes) { size_t cur = off; off += (bytes + 255) & ~(size_t)255; return cur; };
    float* Aw   = (float*)(wsb + alloc(1156 * 4));
    float* Sg   = (float*)(wsb + alloc(288 * 4));
    float* xe   = (float*)(wsb + alloc(QSTRIDE * 4));
    float* sbuf = (float*)(wsb + alloc((size_t)ROWS*JJ * 4));
    bf16*  xr   = (bf16*) (wsb + alloc(QSTRIDE * 2));          // xr; reused as ao
    bf16*  xa   = (bf16*) (wsb + alloc(QSTRIDE * 2));          // xa; reused as xn2/xo
    bf16*  qkv  = (bf16*) (wsb + alloc(3 * QSTRIDE * 2));      // q,k,v; reused as hm
    unsigned short* wq = (unsigned short*)(wsb + alloc((size_t)1664*544 * 2));
    unsigned short* wp = (unsigned short*)(wsb + alloc((size_t)640*544 * 2));
    unsigned short* w1 = (unsigned short*)(wsb + alloc((size_t)1152*544 * 2));
    unsigned short* w2 = (unsigned short*)(wsb + alloc((size_t)640*1088 * 2));
    (void)ws_size;

    prep_kernel<<<1, 256, 0, stream>>>(gc_e, gc_W, gc_q_w, gc_k_w, gc_q_b, gc_k_b, Aw, Sg);
    gc2_kernel<<<ROWS/GROWS, 256, 0, stream>>>(
        x, Aw, Sg, gc_W, gc_bias, gc_attn_w, gc_attn_b,
        gc_ln_g, gc_ln_b, pos_embed, xe);
    for (int d = 0; d < 4; ++d) {
        wconv_kernel<<<(1664*544 + 255)/256, 256, 0, stream>>>(
            qkv_w + (size_t)d*EE*3*EE, wq, 1632, 544, 1664);
        wconv_kernel<<<(640*544 + 255)/256, 256, 0, stream>>>(
            proj_w + (size_t)d*EE*EE, wp, 544, 544, 640);
        wconv_kernel<<<(1152*544 + 255)/256, 256, 0, stream>>>(
            fc1_w + (size_t)d*EE*HIDD, w1, 1088, 544, 1152);
        wconv_kernel<<<(640*1088 + 255)/256, 256, 0, stream>>>(
            fc2_w + (size_t)d*HIDD*EE, w2, 544, 1088, 640);

        ln1_prelude_kernel<<<ROWS/4, 256, 0, stream>>>(
            xe, blk1_g + d*EE, blk1_b + d*EE, at_g + d*ERR, at_b + d*ERR,
            at_pw + d*ERR, at_pb + d, xr, sbuf);
        softmax_frames_kernel<<<BB*JJ/4, 256, 0, stream>>>(sbuf);
        lnC_kernel<<<ROWS/4, 256, 0, stream>>>(xr, sbuf, at2_g + d*EE, at2_b + d*EE, xa);
        mgemm_kernel<<<dim3(13, 243), 256, 0, stream>>>(
            (const unsigned short*)xa, wq, qkv_b + d*3*EE,
            nullptr, (unsigned short*)qkv, nullptr, 1632, 544, 1);
        fattn_kernel<<<dim3(4, BB*NHH), 256, 0, stream>>>(
            (const unsigned short*)qkv, (const unsigned short*)qkv + QSTRIDE,
            (const unsigned short*)qkv + 2*QSTRIDE, at_scaling + d, xr);
        mgemm_kernel<<<dim3(5, 243), 256, 0, stream>>>(
            (const unsigned short*)xr, wp, proj_b + d*EE,
            xe, nullptr, nullptr, 544, 544, 2);
        ln_row_kernel<<<ROWS/4, 256, 0, stream>>>(xe, blk2_g + d*EE, blk2_b + d*EE, xa, 1e-6f);
        mgemm_kernel<<<dim3(9, 243), 256, 0, stream>>>(
            (const unsigned short*)xa, w1, fc1_b + d*HIDD,
            nullptr, nullptr, (unsigned short*)qkv, 1088, 544, 3);   // hm into qkv region
        mgemm_kernel<<<dim3(5, 243), 256, 0, stream>>>(
            (const unsigned short*)qkv, w2, fc2_b + d*EE,
            xe, nullptr, nullptr, 544, 1088, 2);
    }
    ln_row_kernel<<<ROWS/4, 256, 0, stream>>>(xe, fin_g, fin_b, xa, 1e-6f);
    wconv_kernel<<<(128*544 + 255)/256, 256, 0, stream>>>(head_w, wq, 51, 544, 128);
    mgemm_kernel<<<dim3(1, 243), 256, 0, stream>>>(
        (const unsigned short*)xa, wq, head_b,
        (float*)d_out, nullptr, nullptr, 51, 544, 4);
}

// Round 9
// 3083.419 us; speedup vs baseline: 9.7806x; 1.1486x over previous
//
#include <hip/hip_runtime.h>
#include <hip/hip_bf16.h>
#include <math.h>

// ---------------- constants ----------------
#define BB 128
#define FF 243
#define JJ 17
#define ERR 32
#define EE 544
#define EE3 1632
#define NHH 8
#define HDD 68
#define HIDD 1088
#define ROWS 31104          // B*F
#define QSTRIDE 16920576ULL // ROWS*EE
#define GROWS 16            // rows per gc2 block

typedef __hip_bfloat16 bf16;
typedef __bf16 bf16x8 __attribute__((ext_vector_type(8)));
typedef float floatx4 __attribute__((ext_vector_type(4)));

static __device__ __forceinline__ float b2f(bf16 v) { return __bfloat162float(v); }
static __device__ __forceinline__ bf16 f2b(float v) { return __float2bfloat16(v); }
static __device__ __forceinline__ unsigned short f2bu(float v) {
    bf16 h = __float2bfloat16(v);
    return *(unsigned short*)&h;
}
// async global->LDS, 16B per lane; dest = wave-uniform base + lane*16
static __device__ __forceinline__ void async16(void* lds, const void* g) {
    __builtin_amdgcn_global_load_lds(
        (const __attribute__((address_space(1))) unsigned*)g,
        (__attribute__((address_space(3))) unsigned*)lds, 16, 0, 0);
}

// ---------------- prep: adjacency softmax + folded q/k projection ----------------
__global__ __launch_bounds__(256) void prep_kernel(
    const float* __restrict__ gc_e, const float* __restrict__ gc_W,
    const float* __restrict__ qw, const float* __restrict__ kw,
    const float* __restrict__ qb, const float* __restrict__ kb,
    float* __restrict__ A, float* __restrict__ Sg)
{
    __shared__ float a1[17][17], a2[17][17], a3[17][17];
    int tid = threadIdx.x;
    const int parents[17] = {-1,0,1,2,0,4,5,0,7,8,9,8,11,12,8,14,15};
    if (tid == 0) {
        for (int i=0;i<17;++i) for (int j=0;j<17;++j) a1[i][j]=0.f;
        for (int c=0;c<17;++c){ int p=parents[c]; if(p>=0){ a1[c][p]=1.f; a1[p][c]=1.f; } }
        for (int i=0;i<17;++i) for (int j=0;j<17;++j){ float s=0; for(int k=0;k<17;++k) s+=a1[i][k]*a1[k][j]; a2[i][j]=s; }
        for (int i=0;i<17;++i) for (int j=0;j<17;++j){ float s=0; for(int k=0;k<17;++k) s+=a2[i][k]*a1[k][j]; a3[i][j]=s; }
    }
    __syncthreads();
    for (int p = tid; p < 68; p += 256) {
        int n = p / 17, i = p % 17;
        bool msk[17];
        float m = -1e30f;
        for (int j=0;j<17;++j) {
            bool mm;
            if (n==0) mm = (i==j);
            else if (n==1) mm = a1[i][j] > 0.f;
            else if (n==2) mm = a2[i][j] > 0.f;
            else mm = a3[i][j] > 0.f;
            msk[j] = mm;
            if (mm) m = fmaxf(m, gc_e[(n*17+i)*17+j]);
        }
        float ex[17]; float s=0.f;
        for (int j=0;j<17;++j){ ex[j] = msk[j] ? expf(gc_e[(n*17+i)*17+j]-m) : 0.f; s+=ex[j]; }
        float inv = 1.f/s;
        for (int j=0;j<17;++j) A[(n*17+i)*17+j] = ex[j]*inv;
    }
    if (tid < 256) {
        int c = tid >> 7, n = (tid >> 5) & 3, o2 = tid & 31;
        float s = 0.f;
        for (int o = 0; o < 32; ++o)
            s += gc_W[(n*2+c)*32 + o] * (qw[o*32+o2] + kw[o*32+o2]);
        Sg[tid] = s;
    }
    if (tid < 32) Sg[256 + tid] = qb[tid] + kb[tid];
}

// ---------------- gc2: fused graph conv, 16 rows per block ----------------
__global__ __launch_bounds__(256) void gc2_kernel(
    const float* __restrict__ x, const float* __restrict__ A, const float* __restrict__ Sg,
    const float* __restrict__ gc_W, const float* __restrict__ gc_bias,
    const float* __restrict__ aw, const float* __restrict__ ab,
    const float* __restrict__ lng, const float* __restrict__ lnb,
    const float* __restrict__ pos_embed, float* __restrict__ xe)
{
    __shared__ float As[4][17][17];
    __shared__ float S0[4][33], S1[4][33], bqk[32];   // padded: kill 4-way bank conflict
    __shared__ float Ws[4][2][32];
    __shared__ float aws[32], lngs[32], lnbs[32], gbias[32];
    __shared__ float xf[GROWS][34];
    __shared__ float c0[GROWS][68], c1[GROWS][68];
    __shared__ float sc[GROWS][68];
    int tid = threadIdx.x;
    int r0 = blockIdx.x * GROWS;

    for (int i = tid; i < 1156; i += 256) ((float*)As)[i] = A[i];
    if (tid < 128) S0[tid>>5][tid&31] = Sg[tid];
    else           S1[(tid-128)>>5][(tid-128)&31] = Sg[tid];
    if (tid < 32) bqk[tid] = Sg[256+tid];
    if (tid >= 32 && tid < 64)  aws[tid-32]  = aw[tid-32];
    if (tid >= 64 && tid < 96)  lngs[tid-64] = lng[tid-64];
    if (tid >= 96 && tid < 128) lnbs[tid-96] = lnb[tid-96];
    if (tid >= 128 && tid < 160) gbias[tid-128] = gc_bias[tid-128];
    ((float*)Ws)[tid] = gc_W[tid];
    for (int i = tid; i < GROWS*34; i += 256) ((float*)xf)[i] = x[(size_t)r0*34 + i];
    __syncthreads();

    for (int u = tid; u < GROWS*68; u += 256) {
        int row = u / 68, t = u % 68, i = t >> 2, n = t & 3;
        float a0 = 0.f, a1v = 0.f;
        #pragma unroll
        for (int j = 0; j < 17; ++j) {
            float a = As[n][i][j];
            a0  = fmaf(a, xf[row][2*j],   a0);
            a1v = fmaf(a, xf[row][2*j+1], a1v);
        }
        c0[row][t] = a0; c1[row][t] = a1v;
    }
    __syncthreads();

    float abv = ab[0];
    for (int u = tid; u < GROWS*68; u += 256) {
        int row = u / 68, t = u % 68, n = t & 3;
        float v0 = c0[row][t], v1 = c1[row][t];
        float acc = abv;
        #pragma unroll
        for (int o2 = 0; o2 < 32; ++o2) {
            float z = fmaf(v0, S0[n][o2], fmaf(v1, S1[n][o2], bqk[o2]));
            acc = fmaf(tanhf(z), aws[o2], acc);
        }
        sc[row][t] = acc;
    }
    __syncthreads();

    if (tid < GROWS*4) {
        int row = tid >> 2, n = tid & 3;
        float m = -1e30f;
        for (int i = 0; i < 17; ++i) m = fmaxf(m, sc[row][i*4+n]);
        float w[17]; float s = 0.f;
        for (int i = 0; i < 17; ++i) { w[i] = expf(sc[row][i*4+n] - m); s += w[i]; }
        float inv = 1.f / s;
        for (int i = 0; i < 17; ++i) {
            float ww = w[i] * inv;
            c0[row][i*4+n] *= ww;
            c1[row][i*4+n] *= ww;
        }
    }
    __syncthreads();

    int g16 = tid >> 4, lg = tid & 15;
    for (int pair = g16; pair < GROWS*JJ; pair += 16) {
        int row = pair / JJ, j = pair % JJ;
        float e00=c0[row][j*4+0], e01=c0[row][j*4+1], e02=c0[row][j*4+2], e03=c0[row][j*4+3];
        float e10=c1[row][j*4+0], e11=c1[row][j*4+1], e12=c1[row][j*4+2], e13=c1[row][j*4+3];
        int o0 = lg, o1 = lg + 16;
        float a0 = gbias[o0], a1 = gbias[o1];
        a0 = fmaf(e00, Ws[0][0][o0], a0); a0 = fmaf(e10, Ws[0][1][o0], a0);
        a0 = fmaf(e01, Ws[1][0][o0], a0); a0 = fmaf(e11, Ws[1][1][o0], a0);
        a0 = fmaf(e02, Ws[2][0][o0], a0); a0 = fmaf(e12, Ws[2][1][o0], a0);
        a0 = fmaf(e03, Ws[3][0][o0], a0); a0 = fmaf(e13, Ws[3][1][o0], a0);
        a1 = fmaf(e00, Ws[0][0][o1], a1); a1 = fmaf(e10, Ws[0][1][o1], a1);
        a1 = fmaf(e01, Ws[1][0][o1], a1); a1 = fmaf(e11, Ws[1][1][o1], a1);
        a1 = fmaf(e02, Ws[2][0][o1], a1); a1 = fmaf(e12, Ws[2][1][o1], a1);
        a1 = fmaf(e03, Ws[3][0][o1], a1); a1 = fmaf(e13, Ws[3][1][o1], a1);
        float ssum = a0 + a1;
        ssum += __shfl_xor(ssum, 1); ssum += __shfl_xor(ssum, 2);
        ssum += __shfl_xor(ssum, 4); ssum += __shfl_xor(ssum, 8);
        float mu = ssum * (1.f/32.f);
        float d0 = a0 - mu, d1 = a1 - mu;
        float vv = d0*d0 + d1*d1;
        vv += __shfl_xor(vv, 1); vv += __shfl_xor(vv, 2);
        vv += __shfl_xor(vv, 4); vv += __shfl_xor(vv, 8);
        float rstd = rsqrtf(vv*(1.f/32.f) + 1e-5f);
        int r = r0 + row, f = r % FF;
        const float* pe = pos_embed + (size_t)f*EE + j*32;
        float* dst = xe + (size_t)r*EE + j*32;
        dst[o0] = fmaxf(d0*rstd*lngs[o0] + lnbs[o0], 0.f) + pe[o0];
        dst[o1] = fmaxf(d1*rstd*lngs[o1] + lnbs[o1], 0.f) + pe[o1];
    }
}

// ---------------- LN1 + per-joint LN + pooling-score (wave per row, 4 rows/block) --
__global__ __launch_bounds__(256) void ln1_prelude_kernel(
    const float* __restrict__ xe,
    const float* __restrict__ g1, const float* __restrict__ b1,
    const float* __restrict__ ang, const float* __restrict__ anb,
    const float* __restrict__ apw, const float* __restrict__ apb,
    bf16* __restrict__ xr_out, float* __restrict__ s_out)
{
    __shared__ float rowbuf[4][561];     // joint-padded stride 33
    __shared__ float jm[4][17], jrs[4][17];
    __shared__ float angs[32], anbs[32], apws[32];
    int tid = threadIdx.x, w = tid >> 6, lane = tid & 63;
    int r = blockIdx.x*4 + w;
    if (tid < 32) { angs[tid]=ang[tid]; anbs[tid]=anb[tid]; apws[tid]=apw[tid]; }
    float vals[9];
    float ls = 0.f;
    #pragma unroll
    for (int s=0;s<9;++s){ int e=s*64+lane; if(e<EE){ float v=xe[(size_t)r*EE+e]; vals[s]=v; ls+=v; } else vals[s]=0.f; }
    #pragma unroll
    for (int m=1;m<64;m<<=1) ls += __shfl_xor(ls, m);
    float mean = ls*(1.f/544.f);
    float lv = 0.f;
    #pragma unroll
    for (int s=0;s<9;++s){ int e=s*64+lane; if(e<EE){ float d=vals[s]-mean; lv+=d*d; } }
    #pragma unroll
    for (int m=1;m<64;m<<=1) lv += __shfl_xor(lv, m);
    float rstd = rsqrtf(lv*(1.f/544.f)+1e-6f);
    #pragma unroll
    for (int s=0;s<9;++s){ int e=s*64+lane; if(e<EE)
        rowbuf[w][(e>>5)*33+(e&31)] = (vals[s]-mean)*rstd*g1[e] + b1[e]; }
    __syncthreads();
    if (lane < 17) {
        float s0=0.f, s1=0.f;
        for (int o=0;o<32;++o){ float v=rowbuf[w][lane*33+o]; s0+=v; s1+=v*v; }
        float mu = s0*(1.f/32.f);
        jm[w][lane]=mu; jrs[w][lane]=rsqrtf(s1*(1.f/32.f)-mu*mu+1e-5f);
    }
    __syncthreads();
    #pragma unroll
    for (int s=0;s<9;++s){ int e=s*64+lane; if(e<EE){
        int j=e>>5, o=e&31;
        float v = (rowbuf[w][j*33+o]-jm[w][j])*jrs[w][j]*angs[o] + anbs[o];
        xr_out[(size_t)r*EE+e] = f2b(v);
        rowbuf[w][j*33+o] = v; } }
    __syncthreads();
    if (lane < 17) {
        float acc = apb[0];
        for (int o=0;o<32;++o) acc += rowbuf[w][lane*33+o]*apws[o];
        s_out[(size_t)r*JJ+lane] = acc;
    }
}

// ---------------- softmax over frames (wave per (b,joint)) ----------------
__global__ __launch_bounds__(256) void softmax_frames_kernel(float* __restrict__ s)
{
    int tid = threadIdx.x, w = tid >> 6, lane = tid & 63;
    int bid = blockIdx.x*4 + w; int b = bid/JJ, j = bid%JJ;
    float* base = s + (size_t)b*FF*JJ + j;
    float v[4]; float m = -1e30f;
    #pragma unroll
    for (int s2=0;s2<4;++s2){ int e=s2*64+lane;
        v[s2] = (e<FF) ? base[(size_t)e*JJ] : -1e30f;
        m = fmaxf(m, v[s2]); }
    #pragma unroll
    for (int mm=1;mm<64;mm<<=1) m = fmaxf(m, __shfl_xor(m, mm));
    float lsum = 0.f;
    #pragma unroll
    for (int s2=0;s2<4;++s2){ int e=s2*64+lane;
        if (e<FF){ v[s2] = __expf(v[s2]-m); lsum += v[s2]; } }
    #pragma unroll
    for (int mm=1;mm<64;mm<<=1) lsum += __shfl_xor(lsum, mm);
    float inv = 1.f/lsum;
    #pragma unroll
    for (int s2=0;s2<4;++s2){ int e=s2*64+lane;
        if (e<FF) base[(size_t)e*JJ] = v[s2]*inv; }
}

// ---------------- xa = LN544(xr * wf) (wave per row) ----------------
__global__ __launch_bounds__(256) void lnC_kernel(
    const bf16* __restrict__ xr, const float* __restrict__ wf,
    const float* __restrict__ g, const float* __restrict__ b,
    bf16* __restrict__ xa)
{
    __shared__ float wfb[4][17];
    int tid = threadIdx.x, w = tid >> 6, lane = tid & 63;
    int r = blockIdx.x*4 + w;
    if (lane < 17) wfb[w][lane] = wf[(size_t)r*JJ + lane];
    __syncthreads();
    float vals[9]; float ls = 0.f;
    #pragma unroll
    for (int s=0;s<9;++s){ int e=s*64+lane; if(e<EE){
        float v = b2f(xr[(size_t)r*EE+e])*wfb[w][e>>5]; vals[s]=v; ls+=v; } else vals[s]=0.f; }
    #pragma unroll
    for (int m=1;m<64;m<<=1) ls += __shfl_xor(ls, m);
    float mean = ls*(1.f/544.f);
    float lv = 0.f;
    #pragma unroll
    for (int s=0;s<9;++s){ int e=s*64+lane; if(e<EE){ float d=vals[s]-mean; lv+=d*d; } }
    #pragma unroll
    for (int m=1;m<64;m<<=1) lv += __shfl_xor(lv, m);
    float rstd = rsqrtf(lv*(1.f/544.f)+1e-5f);
    #pragma unroll
    for (int s=0;s<9;++s){ int e=s*64+lane; if(e<EE)
        xa[(size_t)r*EE+e] = f2b((vals[s]-mean)*rstd*g[e] + b[e]); }
}

// ---------------- generic LN over 544 (wave per row, no LDS) ----------------
__global__ __launch_bounds__(256) void ln_row_kernel(
    const float* __restrict__ in, const float* __restrict__ g,
    const float* __restrict__ b, bf16* __restrict__ out, float eps)
{
    int tid = threadIdx.x, w = tid >> 6, lane = tid & 63;
    int r = blockIdx.x*4 + w;
    float vals[9]; float ls = 0.f;
    #pragma unroll
    for (int s=0;s<9;++s){ int e=s*64+lane; if(e<EE){ float v=in[(size_t)r*EE+e]; vals[s]=v; ls+=v; } else vals[s]=0.f; }
    #pragma unroll
    for (int m=1;m<64;m<<=1) ls += __shfl_xor(ls, m);
    float mean = ls*(1.f/544.f);
    float lv = 0.f;
    #pragma unroll
    for (int s=0;s<9;++s){ int e=s*64+lane; if(e<EE){ float d=vals[s]-mean; lv+=d*d; } }
    #pragma unroll
    for (int m=1;m<64;m<<=1) lv += __shfl_xor(lv, m);
    float rstd = rsqrtf(lv*(1.f/544.f)+eps);
    #pragma unroll
    for (int s=0;s<9;++s){ int e=s*64+lane; if(e<EE)
        out[(size_t)r*EE+e] = f2b((vals[s]-mean)*rstd*g[e] + b[e]); }
}

// ---------------- weight convert: fp32 [K][N] -> bf16 [Npad][K] (transpose+pad) ----
__global__ __launch_bounds__(256) void wconv_kernel(
    const float* __restrict__ W, unsigned short* __restrict__ out,
    int N, int K, int Npad)
{
    int idx = blockIdx.x * 256 + threadIdx.x;
    if (idx >= Npad * K) return;
    int n = idx % Npad, k = idx / Npad;
    float v = (n < N) ? W[(size_t)k*N + n] : 0.f;
    out[(size_t)n*K + k] = f2bu(v);
}

// ---------------- MFMA GEMM with async staging ----------------
// mode 1: plain bf16 row-major store; mode 2: out_f32 += v; mode 3: gelu->bf16; mode 4: fp32
__global__ __launch_bounds__(256) void mgemm_kernel(
    const unsigned short* __restrict__ A, const unsigned short* __restrict__ Bt,
    const float* __restrict__ bias,
    float* __restrict__ out_f32, unsigned short* __restrict__ out_bf,
    int N, int K, int mode)
{
    __shared__ unsigned short As[128][32];
    __shared__ unsigned short Bs[128][32];
    int tid = threadIdx.x;
    int bm0 = blockIdx.y * 128, bn0 = blockIdx.x * 128;
    int wave = tid >> 6, lane = tid & 63;
    int wm = (wave >> 1) * 64, wn = (wave & 1) * 64;
    int quad = lane >> 4, l16 = lane & 15;
    int srow0 = wave * 32;
    int lr = lane >> 2, lc = lane & 3;
    floatx4 acc[4][4] = {};

    for (int k0 = 0; k0 < K; k0 += 32) {
        #pragma unroll
        for (int i = 0; i < 2; ++i) {
            int row = srow0 + i*16 + lr;
            int gch = lc ^ (row & 3);
            async16(&As[srow0 + i*16][0], &A [(size_t)(bm0 + row)*K + k0 + gch*8]);
            async16(&Bs[srow0 + i*16][0], &Bt[(size_t)(bn0 + row)*K + k0 + gch*8]);
        }
        __syncthreads();
        bf16x8 af[4], bfr[4];
        #pragma unroll
        for (int mi=0;mi<4;++mi) {
            int r = wm + mi*16 + l16;
            af[mi] = *(const bf16x8*)&As[r][(quad ^ (r & 3))*8];
        }
        #pragma unroll
        for (int ni=0;ni<4;++ni) {
            int r = wn + ni*16 + l16;
            bfr[ni] = *(const bf16x8*)&Bs[r][(quad ^ (r & 3))*8];
        }
        #pragma unroll
        for (int mi=0;mi<4;++mi)
            #pragma unroll
            for (int ni=0;ni<4;++ni)
                acc[mi][ni] = __builtin_amdgcn_mfma_f32_16x16x32_bf16(af[mi], bfr[ni], acc[mi][ni], 0, 0, 0);
        __syncthreads();
    }

    #pragma unroll
    for (int mi=0;mi<4;++mi) {
        #pragma unroll
        for (int ni=0;ni<4;++ni) {
            #pragma unroll
            for (int r4=0;r4<4;++r4) {
                int gm = bm0 + wm + mi*16 + quad*4 + r4;
                int gn = bn0 + wn + ni*16 + l16;
                if (gn >= N) continue;
                float v = acc[mi][ni][r4] + bias[gn];
                if (mode == 1) {
                    out_bf[(size_t)gm*N + gn] = f2bu(v);
                } else if (mode == 2) {
                    out_f32[(size_t)gm*N + gn] += v;
                } else if (mode == 3) {
                    float g = 0.5f * v * (1.0f + erff(v * 0.70710678118654752f));
                    out_bf[(size_t)gm*N + gn] = f2bu(g);
                } else {
                    out_f32[(size_t)gm*N + gn] = v;
                }
            }
        }
    }
}

// ---------------- MFMA flash attention v3: one block per (b,h) ----------------
// qkv row-major [ROWS][1632]; K,V^T staged once; 4 q-tiles looped barrier-free.
__global__ __launch_bounds__(256) void fattn_kernel(
    const unsigned short* __restrict__ qkv,
    const float* __restrict__ scaling_ptr, bf16* __restrict__ ao)
{
    __shared__ unsigned short Ks[256][104];
    __shared__ unsigned short Vt[80][264];    // V transposed [dim][key]
    __shared__ unsigned short Ps[64][264];    // per-wave disjoint rows
    __shared__ float ps_s[256];

    int bh = blockIdx.x, tid = threadIdx.x;
    int b = bh >> 3, h = bh & 7;
    float scaling = scaling_ptr[0];
    const float SCALE = 0.12126781251816648f;  // 68^-0.5

    const unsigned short* base = qkv + (size_t)(b*FF)*EE3;
    const unsigned short* qb_ = base + h*HDD;
    const unsigned short* kb_ = base + EE + h*HDD;
    const unsigned short* vb_ = base + 2*EE + h*HDD;

    if (tid < 256) {
        float pos = tid * (1.0f/242.0f) - 0.5f;
        ps_s[tid] = (tid < FF) ? SCALE * __expf(-scaling * pos * pos) : 0.f;
    }
    for (int idx = tid; idx < 256*18; idx += 256) {         // Ks cols 68..103 = 0
        int r = idx / 18, c2 = idx % 18;
        *(unsigned*)&Ks[r][68 + c2*2] = 0u;
    }
    for (int idx = tid; idx < 80*13; idx += 256) {          // Vt keys 243..255 = 0
        int dd = idx / 13, kk2 = 243 + idx % 13;
        Vt[dd][kk2] = 0;
    }
    for (int idx = tid; idx < FF*34; idx += 256) {          // stage K
        int r = idx / 34, c2 = idx % 34;
        *(unsigned*)&Ks[r][c2*2] = *(const unsigned*)&kb_[(size_t)r*EE3 + c2*2];
    }
    for (int idx = tid; idx < FF*34; idx += 256) {          // stage V^T
        int r = idx / 34, c2 = idx % 34;
        unsigned uv = *(const unsigned*)&vb_[(size_t)r*EE3 + c2*2];
        Vt[c2*2][r]   = (unsigned short)(uv & 0xffffu);
        Vt[c2*2+1][r] = (unsigned short)(uv >> 16);
    }
    __syncthreads();   // the only barrier

    int wave = tid >> 6, lane = tid & 63;
    int quad = lane >> 4, l16 = lane & 15;

    for (int t = 0; t < 4; ++t) {
        int q0 = t * 64;
        // A fragments: this lane's query row (clamped; edge rows masked at store)
        int qi = q0 + wave*16 + l16;
        int qc = (qi < FF) ? qi : (FF-1);
        const unsigned short* qrow = qb_ + (size_t)qc*EE3;
        union { bf16x8 v; uint2 u2[2]; unsigned u[4]; } t0, t1, t2;
        t0.u2[0] = *(const uint2*)&qrow[quad*8];
        t0.u2[1] = *(const uint2*)&qrow[quad*8 + 4];
        t1.u2[0] = *(const uint2*)&qrow[32 + quad*8];
        t1.u2[1] = *(const uint2*)&qrow[32 + quad*8 + 4];
        t2.u[0] = 0; t2.u[1] = 0; t2.u[2] = 0; t2.u[3] = 0;
        if (quad == 0) {                       // dims 64..67 only
            t2.u[0] = *(const unsigned*)&qrow[64];
            t2.u[1] = *(const unsigned*)&qrow[66];
        }
        bf16x8 aq0 = t0.v, aq1 = t1.v, aq2 = t2.v;

        // S = Q K^T
        floatx4 sacc[16];
        #pragma unroll
        for (int nt = 0; nt < 16; ++nt) {
            floatx4 c = {};
            c = __builtin_amdgcn_mfma_f32_16x16x32_bf16(aq0, *(const bf16x8*)&Ks[nt*16 + l16][quad*8], c, 0, 0, 0);
            c = __builtin_amdgcn_mfma_f32_16x16x32_bf16(aq1, *(const bf16x8*)&Ks[nt*16 + l16][32 + quad*8], c, 0, 0, 0);
            c = __builtin_amdgcn_mfma_f32_16x16x32_bf16(aq2, *(const bf16x8*)&Ks[nt*16 + l16][64 + quad*8], c, 0, 0, 0);
            sacc[nt] = c;
        }

        // scale + mask + softmax (row = quad*4+rg, cols across l16 & nt)
        float rmax[4] = {-1e30f, -1e30f, -1e30f, -1e30f};
        #pragma unroll
        for (int nt = 0; nt < 16; ++nt) {
            float psc = ps_s[nt*16 + l16];
            bool maskc = (nt*16 + l16) >= FF;
            #pragma unroll
            for (int rg = 0; rg < 4; ++rg) {
                float s = maskc ? -1e30f : sacc[nt][rg] * psc;
                sacc[nt][rg] = s;
                rmax[rg] = fmaxf(rmax[rg], s);
            }
        }
        #pragma unroll
        for (int rg = 0; rg < 4; ++rg) {
            float m0 = rmax[rg];
            m0 = fmaxf(m0, __shfl_xor(m0, 1));
            m0 = fmaxf(m0, __shfl_xor(m0, 2));
            m0 = fmaxf(m0, __shfl_xor(m0, 4));
            m0 = fmaxf(m0, __shfl_xor(m0, 8));
            rmax[rg] = m0;
        }
        float rs[4] = {0.f, 0.f, 0.f, 0.f};
        #pragma unroll
        for (int nt = 0; nt < 16; ++nt)
            #pragma unroll
            for (int rg = 0; rg < 4; ++rg) {
                float p = __expf(sacc[nt][rg] - rmax[rg]);
                sacc[nt][rg] = p;
                rs[rg] += p;
            }
        #pragma unroll
        for (int rg = 0; rg < 4; ++rg) {
            float s0 = rs[rg];
            s0 += __shfl_xor(s0, 1);
            s0 += __shfl_xor(s0, 2);
            s0 += __shfl_xor(s0, 4);
            s0 += __shfl_xor(s0, 8);
            rs[rg] = 1.f / s0;
        }

        // P -> LDS (wave-private rows; no barrier needed)
        #pragma unroll
        for (int nt = 0; nt < 16; ++nt)
            #pragma unroll
            for (int rg = 0; rg < 4; ++rg)
                Ps[wave*16 + quad*4 + rg][nt*16 + l16] = f2bu(sacc[nt][rg] * rs[rg]);

        // O = P V
        bf16x8 ap[8];
        #pragma unroll
        for (int kk = 0; kk < 8; ++kk)
            ap[kk] = *(const bf16x8*)&Ps[wave*16 + l16][kk*32 + quad*8];
        #pragma unroll
        for (int nt = 0; nt < 5; ++nt) {
            floatx4 c = {};
            #pragma unroll
            for (int kk = 0; kk < 8; ++kk) {
                bf16x8 bv = *(const bf16x8*)&Vt[nt*16 + l16][kk*32 + quad*8];
                c = __builtin_amdgcn_mfma_f32_16x16x32_bf16(ap[kk], bv, c, 0, 0, 0);
            }
            int gn = nt*16 + l16;
            if (gn < HDD) {
                #pragma unroll
                for (int rg = 0; rg < 4; ++rg) {
                    int query = q0 + wave*16 + quad*4 + rg;
                    if (query < FF)
                        ao[((size_t)b*FF + query)*EE + h*HDD + gn] = f2b(c[rg]);
                }
            }
        }
    }
}

// ---------------- host launch ----------------
extern "C" void kernel_launch(void* const* d_in, const int* in_sizes, int n_in,
                              void* d_out, int out_size, void* d_ws, size_t ws_size,
                              hipStream_t stream) {
    typedef const float* fp;
    fp x          = (fp)d_in[0];
    fp gc_W       = (fp)d_in[2];
    fp gc_e       = (fp)d_in[3];
    fp gc_bias    = (fp)d_in[4];
    fp gc_q_w     = (fp)d_in[5];
    fp gc_q_b     = (fp)d_in[6];
    fp gc_k_w     = (fp)d_in[7];
    fp gc_k_b     = (fp)d_in[8];
    fp gc_attn_w  = (fp)d_in[9];
    fp gc_attn_b  = (fp)d_in[10];
    fp gc_ln_g    = (fp)d_in[11];
    fp gc_ln_b    = (fp)d_in[12];
    fp pos_embed  = (fp)d_in[13];
    fp blk1_g     = (fp)d_in[14];
    fp blk1_b     = (fp)d_in[15];
    fp at_g       = (fp)d_in[16];
    fp at_b       = (fp)d_in[17];
    fp at_pw      = (fp)d_in[18];
    fp at_pb      = (fp)d_in[19];
    fp at2_g      = (fp)d_in[20];
    fp at2_b      = (fp)d_in[21];
    fp at_scaling = (fp)d_in[22];
    fp qkv_w      = (fp)d_in[23];
    fp qkv_b      = (fp)d_in[24];
    fp proj_w     = (fp)d_in[25];
    fp proj_b     = (fp)d_in[26];
    fp blk2_g     = (fp)d_in[27];
    fp blk2_b     = (fp)d_in[28];
    fp fc1_w      = (fp)d_in[29];
    fp fc1_b      = (fp)d_in[30];
    fp fc2_w      = (fp)d_in[31];
    fp fc2_b      = (fp)d_in[32];
    fp fin_g      = (fp)d_in[33];
    fp fin_b      = (fp)d_in[34];
    fp head_w     = (fp)d_in[35];
    fp head_b     = (fp)d_in[36];

    char* wsb = (char*)d_ws;
    size_t off = 0;
    auto alloc = [&](size_t bytes) { size_t cur = off; off += (bytes + 255) & ~(size_t)255; return cur; };
    float* Aw   = (float*)(wsb + alloc(1156 * 4));
    float* Sg   = (float*)(wsb + alloc(288 * 4));
    float* xe   = (float*)(wsb + alloc(QSTRIDE * 4));
    float* sbuf = (float*)(wsb + alloc((size_t)ROWS*JJ * 4));
    bf16*  xr   = (bf16*) (wsb + alloc(QSTRIDE * 2));          // xr; reused as ao
    bf16*  xa   = (bf16*) (wsb + alloc(QSTRIDE * 2));          // xa; reused as xn2/xo
    bf16*  qkv  = (bf16*) (wsb + alloc(3 * QSTRIDE * 2));      // [ROWS][1632] row-major; reused as hm
    unsigned short* wq = (unsigned short*)(wsb + alloc((size_t)1664*544 * 2));
    unsigned short* wp = (unsigned short*)(wsb + alloc((size_t)640*544 * 2));
    unsigned short* w1 = (unsigned short*)(wsb + alloc((size_t)1152*544 * 2));
    unsigned short* w2 = (unsigned short*)(wsb + alloc((size_t)640*1088 * 2));
    (void)ws_size;

    prep_kernel<<<1, 256, 0, stream>>>(gc_e, gc_W, gc_q_w, gc_k_w, gc_q_b, gc_k_b, Aw, Sg);
    gc2_kernel<<<ROWS/GROWS, 256, 0, stream>>>(
        x, Aw, Sg, gc_W, gc_bias, gc_attn_w, gc_attn_b,
        gc_ln_g, gc_ln_b, pos_embed, xe);
    for (int d = 0; d < 4; ++d) {
        wconv_kernel<<<(1664*544 + 255)/256, 256, 0, stream>>>(
            qkv_w + (size_t)d*EE*3*EE, wq, 1632, 544, 1664);
        wconv_kernel<<<(640*544 + 255)/256, 256, 0, stream>>>(
            proj_w + (size_t)d*EE*EE, wp, 544, 544, 640);
        wconv_kernel<<<(1152*544 + 255)/256, 256, 0, stream>>>(
            fc1_w + (size_t)d*EE*HIDD, w1, 1088, 544, 1152);
        wconv_kernel<<<(640*1088 + 255)/256, 256, 0, stream>>>(
            fc2_w + (size_t)d*HIDD*EE, w2, 544, 1088, 640);

        ln1_prelude_kernel<<<ROWS/4, 256, 0, stream>>>(
            xe, blk1_g + d*EE, blk1_b + d*EE, at_g + d*ERR, at_b + d*ERR,
            at_pw + d*ERR, at_pb + d, xr, sbuf);
        softmax_frames_kernel<<<BB*JJ/4, 256, 0, stream>>>(sbuf);
        lnC_kernel<<<ROWS/4, 256, 0, stream>>>(xr, sbuf, at2_g + d*EE, at2_b + d*EE, xa);
        mgemm_kernel<<<dim3(13, 243), 256, 0, stream>>>(
            (const unsigned short*)xa, wq, qkv_b + d*3*EE,
            nullptr, (unsigned short*)qkv, 1632, 544, 1);
        fattn_kernel<<<BB*NHH, 256, 0, stream>>>(
            (const unsigned short*)qkv, at_scaling + d, xr);
        mgemm_kernel<<<dim3(5, 243), 256, 0, stream>>>(
            (const unsigned short*)xr, wp, proj_b + d*EE,
            xe, nullptr, 544, 544, 2);
        ln_row_kernel<<<ROWS/4, 256, 0, stream>>>(xe, blk2_g + d*EE, blk2_b + d*EE, xa, 1e-6f);
        mgemm_kernel<<<dim3(9, 243), 256, 0, stream>>>(
            (const unsigned short*)xa, w1, fc1_b + d*HIDD,
            nullptr, (unsigned short*)qkv, 1088, 544, 3);   // hm into qkv region
        mgemm_kernel<<<dim3(5, 243), 256, 0, stream>>>(
            (const unsigned short*)qkv, w2, fc2_b + d*EE,
            xe, nullptr, 544, 1088, 2);
    }
    ln_row_kernel<<<ROWS/4, 256, 0, stream>>>(xe, fin_g, fin_b, xa, 1e-6f);
    wconv_kernel<<<(128*544 + 255)/256, 256, 0, stream>>>(head_w, wq, 51, 544, 128);
    mgemm_kernel<<<dim3(1, 243), 256, 0, stream>>>(
        (const unsigned short*)xa, wq, head_b,
        (float*)d_out, nullptr, 51, 544, 4);
}

// Round 11
// 2872.134 us; speedup vs baseline: 10.5001x; 1.0736x over previous
//
#include <hip/hip_runtime.h>
#include <hip/hip_bf16.h>
#include <math.h>

// ---------------- constants ----------------
#define BB 128
#define FF 243
#define JJ 17
#define ERR 32
#define EE 544
#define EE3 1632
#define NHH 8
#define HDD 68
#define HIDD 1088
#define ROWS 31104          // B*F
#define QSTRIDE 16920576ULL // ROWS*EE
#define GROWS 16            // rows per gc2 block

typedef __hip_bfloat16 bf16;
typedef __bf16 bf16x8 __attribute__((ext_vector_type(8)));
typedef float floatx4 __attribute__((ext_vector_type(4)));

static __device__ __forceinline__ float b2f(bf16 v) { return __bfloat162float(v); }
static __device__ __forceinline__ bf16 f2b(float v) { return __float2bfloat16(v); }
static __device__ __forceinline__ unsigned short f2bu(float v) {
    bf16 h = __float2bfloat16(v);
    return *(unsigned short*)&h;
}
// async global->LDS, 16B per lane; dest = wave-uniform base + lane*16
static __device__ __forceinline__ void async16(void* lds, const void* g) {
    __builtin_amdgcn_global_load_lds(
        (const __attribute__((address_space(1))) unsigned*)g,
        (__attribute__((address_space(3))) unsigned*)lds, 16, 0, 0);
}

// ---------------- prep: adjacency softmax + folded q/k projection (parallel) ------
__global__ __launch_bounds__(256) void prep_kernel(
    const float* __restrict__ gc_e, const float* __restrict__ gc_W,
    const float* __restrict__ qw, const float* __restrict__ kw,
    const float* __restrict__ qb, const float* __restrict__ kb,
    float* __restrict__ A, float* __restrict__ Sg)
{
    __shared__ float a1[17][17], a2[17][17], a3[17][17];
    int tid = threadIdx.x;
    const int parents[17] = {-1,0,1,2,0,4,5,0,7,8,9,8,11,12,8,14,15};
    // 289 entries > 256 threads: MUST be strided loops (round-10 bug: `if (tid<289)`)
    for (int t = tid; t < 289; t += 256) {
        int i = t / 17, j = t % 17;
        bool e = (parents[i] == j) || (parents[j] == i);
        a1[i][j] = e ? 1.f : 0.f;
    }
    __syncthreads();
    for (int t = tid; t < 289; t += 256) {
        int i = t / 17, j = t % 17;
        float s = 0.f;
        #pragma unroll
        for (int k = 0; k < 17; ++k) s += a1[i][k] * a1[k][j];
        a2[i][j] = s;
    }
    __syncthreads();
    for (int t = tid; t < 289; t += 256) {
        int i = t / 17, j = t % 17;
        float s = 0.f;
        #pragma unroll
        for (int k = 0; k < 17; ++k) s += a2[i][k] * a1[k][j];
        a3[i][j] = s;
    }
    __syncthreads();
    for (int p = tid; p < 68; p += 256) {
        int n = p / 17, i = p % 17;
        bool msk[17];
        float m = -1e30f;
        for (int j=0;j<17;++j) {
            bool mm;
            if (n==0) mm = (i==j);
            else if (n==1) mm = a1[i][j] > 0.f;
            else if (n==2) mm = a2[i][j] > 0.f;
            else mm = a3[i][j] > 0.f;
            msk[j] = mm;
            if (mm) m = fmaxf(m, gc_e[(n*17+i)*17+j]);
        }
        float ex[17]; float s=0.f;
        for (int j=0;j<17;++j){ ex[j] = msk[j] ? expf(gc_e[(n*17+i)*17+j]-m) : 0.f; s+=ex[j]; }
        float inv = 1.f/s;
        for (int j=0;j<17;++j) A[(n*17+i)*17+j] = ex[j]*inv;
    }
    if (tid < 256) {
        int c = tid >> 7, n = (tid >> 5) & 3, o2 = tid & 31;
        float s = 0.f;
        for (int o = 0; o < 32; ++o)
            s += gc_W[(n*2+c)*32 + o] * (qw[o*32+o2] + kw[o*32+o2]);
        Sg[tid] = s;
    }
    if (tid < 32) Sg[256 + tid] = qb[tid] + kb[tid];
}

// ---------------- gc2: fused graph conv, 16 rows per block ----------------
__global__ __launch_bounds__(256) void gc2_kernel(
    const float* __restrict__ x, const float* __restrict__ A, const float* __restrict__ Sg,
    const float* __restrict__ gc_W, const float* __restrict__ gc_bias,
    const float* __restrict__ aw, const float* __restrict__ ab,
    const float* __restrict__ lng, const float* __restrict__ lnb,
    const float* __restrict__ pos_embed, float* __restrict__ xe)
{
    __shared__ float As[4][17][17];
    __shared__ float S0[4][33], S1[4][33], bqk[32];   // padded: kill 4-way bank conflict
    __shared__ float Ws[4][2][32];
    __shared__ float aws[32], lngs[32], lnbs[32], gbias[32];
    __shared__ float xf[GROWS][34];
    __shared__ float c0[GROWS][68], c1[GROWS][68];
    __shared__ float sc[GROWS][68];
    int tid = threadIdx.x;
    int r0 = blockIdx.x * GROWS;

    for (int i = tid; i < 1156; i += 256) ((float*)As)[i] = A[i];
    if (tid < 128) S0[tid>>5][tid&31] = Sg[tid];
    else           S1[(tid-128)>>5][(tid-128)&31] = Sg[tid];
    if (tid < 32) bqk[tid] = Sg[256+tid];
    if (tid >= 32 && tid < 64)  aws[tid-32]  = aw[tid-32];
    if (tid >= 64 && tid < 96)  lngs[tid-64] = lng[tid-64];
    if (tid >= 96 && tid < 128) lnbs[tid-96] = lnb[tid-96];
    if (tid >= 128 && tid < 160) gbias[tid-128] = gc_bias[tid-128];
    ((float*)Ws)[tid] = gc_W[tid];
    for (int i = tid; i < GROWS*34; i += 256) ((float*)xf)[i] = x[(size_t)r0*34 + i];
    __syncthreads();

    for (int u = tid; u < GROWS*68; u += 256) {
        int row = u / 68, t = u % 68, i = t >> 2, n = t & 3;
        float a0 = 0.f, a1v = 0.f;
        #pragma unroll
        for (int j = 0; j < 17; ++j) {
            float a = As[n][i][j];
            a0  = fmaf(a, xf[row][2*j],   a0);
            a1v = fmaf(a, xf[row][2*j+1], a1v);
        }
        c0[row][t] = a0; c1[row][t] = a1v;
    }
    __syncthreads();

    float abv = ab[0];
    for (int u = tid; u < GROWS*68; u += 256) {
        int row = u / 68, t = u % 68, n = t & 3;
        float v0 = c0[row][t], v1 = c1[row][t];
        float acc = abv;
        #pragma unroll
        for (int o2 = 0; o2 < 32; ++o2) {
            float z = fmaf(v0, S0[n][o2], fmaf(v1, S1[n][o2], bqk[o2]));
            acc = fmaf(tanhf(z), aws[o2], acc);
        }
        sc[row][t] = acc;
    }
    __syncthreads();

    if (tid < GROWS*4) {
        int row = tid >> 2, n = tid & 3;
        float m = -1e30f;
        for (int i = 0; i < 17; ++i) m = fmaxf(m, sc[row][i*4+n]);
        float w[17]; float s = 0.f;
        for (int i = 0; i < 17; ++i) { w[i] = expf(sc[row][i*4+n] - m); s += w[i]; }
        float inv = 1.f / s;
        for (int i = 0; i < 17; ++i) {
            float ww = w[i] * inv;
            c0[row][i*4+n] *= ww;
            c1[row][i*4+n] *= ww;
        }
    }
    __syncthreads();

    int g16 = tid >> 4, lg = tid & 15;
    for (int pair = g16; pair < GROWS*JJ; pair += 16) {
        int row = pair / JJ, j = pair % JJ;
        float e00=c0[row][j*4+0], e01=c0[row][j*4+1], e02=c0[row][j*4+2], e03=c0[row][j*4+3];
        float e10=c1[row][j*4+0], e11=c1[row][j*4+1], e12=c1[row][j*4+2], e13=c1[row][j*4+3];
        int o0 = lg, o1 = lg + 16;
        float a0 = gbias[o0], a1 = gbias[o1];
        a0 = fmaf(e00, Ws[0][0][o0], a0); a0 = fmaf(e10, Ws[0][1][o0], a0);
        a0 = fmaf(e01, Ws[1][0][o0], a0); a0 = fmaf(e11, Ws[1][1][o0], a0);
        a0 = fmaf(e02, Ws[2][0][o0], a0); a0 = fmaf(e12, Ws[2][1][o0], a0);
        a0 = fmaf(e03, Ws[3][0][o0], a0); a0 = fmaf(e13, Ws[3][1][o0], a0);
        a1 = fmaf(e00, Ws[0][0][o1], a1); a1 = fmaf(e10, Ws[0][1][o1], a1);
        a1 = fmaf(e01, Ws[1][0][o1], a1); a1 = fmaf(e11, Ws[1][1][o1], a1);
        a1 = fmaf(e02, Ws[2][0][o1], a1); a1 = fmaf(e12, Ws[2][1][o1], a1);
        a1 = fmaf(e03, Ws[3][0][o1], a1); a1 = fmaf(e13, Ws[3][1][o1], a1);
        float ssum = a0 + a1;
        ssum += __shfl_xor(ssum, 1); ssum += __shfl_xor(ssum, 2);
        ssum += __shfl_xor(ssum, 4); ssum += __shfl_xor(ssum, 8);
        float mu = ssum * (1.f/32.f);
        float d0 = a0 - mu, d1 = a1 - mu;
        float vv = d0*d0 + d1*d1;
        vv += __shfl_xor(vv, 1); vv += __shfl_xor(vv, 2);
        vv += __shfl_xor(vv, 4); vv += __shfl_xor(vv, 8);
        float rstd = rsqrtf(vv*(1.f/32.f) + 1e-5f);
        int r = r0 + row, f = r % FF;
        const float* pe = pos_embed + (size_t)f*EE + j*32;
        float* dst = xe + (size_t)r*EE + j*32;
        dst[o0] = fmaxf(d0*rstd*lngs[o0] + lnbs[o0], 0.f) + pe[o0];
        dst[o1] = fmaxf(d1*rstd*lngs[o1] + lnbs[o1], 0.f) + pe[o1];
    }
}

// ---------------- LN1 + per-joint LN + pooling-score (wave per row, 4 rows/block) --
__global__ __launch_bounds__(256) void ln1_prelude_kernel(
    const float* __restrict__ xe,
    const float* __restrict__ g1, const float* __restrict__ b1,
    const float* __restrict__ ang, const float* __restrict__ anb,
    const float* __restrict__ apw, const float* __restrict__ apb,
    bf16* __restrict__ xr_out, float* __restrict__ s_out)
{
    __shared__ float rowbuf[4][561];     // joint-padded stride 33
    __shared__ float jm[4][17], jrs[4][17];
    __shared__ float angs[32], anbs[32], apws[32];
    int tid = threadIdx.x, w = tid >> 6, lane = tid & 63;
    int r = blockIdx.x*4 + w;
    if (tid < 32) { angs[tid]=ang[tid]; anbs[tid]=anb[tid]; apws[tid]=apw[tid]; }
    float vals[9];
    float ls = 0.f;
    #pragma unroll
    for (int s=0;s<9;++s){ int e=s*64+lane; if(e<EE){ float v=xe[(size_t)r*EE+e]; vals[s]=v; ls+=v; } else vals[s]=0.f; }
    #pragma unroll
    for (int m=1;m<64;m<<=1) ls += __shfl_xor(ls, m);
    float mean = ls*(1.f/544.f);
    float lv = 0.f;
    #pragma unroll
    for (int s=0;s<9;++s){ int e=s*64+lane; if(e<EE){ float d=vals[s]-mean; lv+=d*d; } }
    #pragma unroll
    for (int m=1;m<64;m<<=1) lv += __shfl_xor(lv, m);
    float rstd = rsqrtf(lv*(1.f/544.f)+1e-6f);
    #pragma unroll
    for (int s=0;s<9;++s){ int e=s*64+lane; if(e<EE)
        rowbuf[w][(e>>5)*33+(e&31)] = (vals[s]-mean)*rstd*g1[e] + b1[e]; }
    __syncthreads();
    if (lane < 17) {
        float s0=0.f, s1=0.f;
        for (int o=0;o<32;++o){ float v=rowbuf[w][lane*33+o]; s0+=v; s1+=v*v; }
        float mu = s0*(1.f/32.f);
        jm[w][lane]=mu; jrs[w][lane]=rsqrtf(s1*(1.f/32.f)-mu*mu+1e-5f);
    }
    __syncthreads();
    #pragma unroll
    for (int s=0;s<9;++s){ int e=s*64+lane; if(e<EE){
        int j=e>>5, o=e&31;
        float v = (rowbuf[w][j*33+o]-jm[w][j])*jrs[w][j]*angs[o] + anbs[o];
        xr_out[(size_t)r*EE+e] = f2b(v);
        rowbuf[w][j*33+o] = v; } }
    __syncthreads();
    if (lane < 17) {
        float acc = apb[0];
        for (int o=0;o<32;++o) acc += rowbuf[w][lane*33+o]*apws[o];
        s_out[(size_t)r*JJ+lane] = acc;
    }
}

// ---------------- softmax over frames (wave per (b,joint)) ----------------
__global__ __launch_bounds__(256) void softmax_frames_kernel(float* __restrict__ s)
{
    int tid = threadIdx.x, w = tid >> 6, lane = tid & 63;
    int bid = blockIdx.x*4 + w; int b = bid/JJ, j = bid%JJ;
    float* base = s + (size_t)b*FF*JJ + j;
    float v[4]; float m = -1e30f;
    #pragma unroll
    for (int s2=0;s2<4;++s2){ int e=s2*64+lane;
        v[s2] = (e<FF) ? base[(size_t)e*JJ] : -1e30f;
        m = fmaxf(m, v[s2]); }
    #pragma unroll
    for (int mm=1;mm<64;mm<<=1) m = fmaxf(m, __shfl_xor(m, mm));
    float lsum = 0.f;
    #pragma unroll
    for (int s2=0;s2<4;++s2){ int e=s2*64+lane;
        if (e<FF){ v[s2] = __expf(v[s2]-m); lsum += v[s2]; } }
    #pragma unroll
    for (int mm=1;mm<64;mm<<=1) lsum += __shfl_xor(lsum, mm);
    float inv = 1.f/lsum;
    #pragma unroll
    for (int s2=0;s2<4;++s2){ int e=s2*64+lane;
        if (e<FF) base[(size_t)e*JJ] = v[s2]*inv; }
}

// ---------------- xa = LN544(xr * wf) (wave per row) ----------------
__global__ __launch_bounds__(256) void lnC_kernel(
    const bf16* __restrict__ xr, const float* __restrict__ wf,
    const float* __restrict__ g, const float* __restrict__ b,
    bf16* __restrict__ xa)
{
    __shared__ float wfb[4][17];
    int tid = threadIdx.x, w = tid >> 6, lane = tid & 63;
    int r = blockIdx.x*4 + w;
    if (lane < 17) wfb[w][lane] = wf[(size_t)r*JJ + lane];
    __syncthreads();
    float vals[9]; float ls = 0.f;
    #pragma unroll
    for (int s=0;s<9;++s){ int e=s*64+lane; if(e<EE){
        float v = b2f(xr[(size_t)r*EE+e])*wfb[w][e>>5]; vals[s]=v; ls+=v; } else vals[s]=0.f; }
    #pragma unroll
    for (int m=1;m<64;m<<=1) ls += __shfl_xor(ls, m);
    float mean = ls*(1.f/544.f);
    float lv = 0.f;
    #pragma unroll
    for (int s=0;s<9;++s){ int e=s*64+lane; if(e<EE){ float d=vals[s]-mean; lv+=d*d; } }
    #pragma unroll
    for (int m=1;m<64;m<<=1) lv += __shfl_xor(lv, m);
    float rstd = rsqrtf(lv*(1.f/544.f)+1e-5f);
    #pragma unroll
    for (int s=0;s<9;++s){ int e=s*64+lane; if(e<EE)
        xa[(size_t)r*EE+e] = f2b((vals[s]-mean)*rstd*g[e] + b[e]); }
}

// ---------------- generic LN over 544 (wave per row, no LDS) ----------------
__global__ __launch_bounds__(256) void ln_row_kernel(
    const float* __restrict__ in, const float* __restrict__ g,
    const float* __restrict__ b, bf16* __restrict__ out, float eps)
{
    int tid = threadIdx.x, w = tid >> 6, lane = tid & 63;
    int r = blockIdx.x*4 + w;
    float vals[9]; float ls = 0.f;
    #pragma unroll
    for (int s=0;s<9;++s){ int e=s*64+lane; if(e<EE){ float v=in[(size_t)r*EE+e]; vals[s]=v; ls+=v; } else vals[s]=0.f; }
    #pragma unroll
    for (int m=1;m<64;m<<=1) ls += __shfl_xor(ls, m);
    float mean = ls*(1.f/544.f);
    float lv = 0.f;
    #pragma unroll
    for (int s=0;s<9;++s){ int e=s*64+lane; if(e<EE){ float d=vals[s]-mean; lv+=d*d; } }
    #pragma unroll
    for (int m=1;m<64;m<<=1) lv += __shfl_xor(lv, m);
    float rstd = rsqrtf(lv*(1.f/544.f)+eps);
    #pragma unroll
    for (int s=0;s<9;++s){ int e=s*64+lane; if(e<EE)
        out[(size_t)r*EE+e] = f2b((vals[s]-mean)*rstd*g[e] + b[e]); }
}

// ---------------- weight transpose-convert, coalesced via LDS 32x32 tiles ---------
// W fp32 [K][N] -> out bf16 [Npad][K]; zero-pad n >= N.
__global__ __launch_bounds__(256) void wconvT_kernel(
    const float* __restrict__ W, unsigned short* __restrict__ out,
    int N, int K, int Npad)
{
    __shared__ float tile[32][33];
    int bn = blockIdx.x * 32, bk = blockIdx.y * 32;
    int tx = threadIdx.x & 31, ty = threadIdx.x >> 5;   // 32 x 8
    #pragma unroll
    for (int i = 0; i < 4; ++i) {
        int k = bk + ty + i*8, n = bn + tx;
        tile[ty + i*8][tx] = (k < K && n < N) ? W[(size_t)k*N + n] : 0.f;
    }
    __syncthreads();
    #pragma unroll
    for (int i = 0; i < 4; ++i) {
        int n = bn + ty + i*8, k = bk + tx;
        if (n < Npad && k < K) out[(size_t)n*K + k] = f2bu(tile[tx][ty + i*8]);
    }
}

// ---------------- MFMA GEMM with async staging ----------------
// swizzle f(r) = (r>>1)&3: 2-way residual LDS aliasing (free) vs 4-way before.
__global__ __launch_bounds__(256) void mgemm_kernel(
    const unsigned short* __restrict__ A, const unsigned short* __restrict__ Bt,
    const float* __restrict__ bias,
    float* __restrict__ out_f32, unsigned short* __restrict__ out_bf,
    int N, int K, int mode)
{
    __shared__ unsigned short As[128][32];
    __shared__ unsigned short Bs[128][32];
    int tid = threadIdx.x;
    int bm0 = blockIdx.y * 128, bn0 = blockIdx.x * 128;
    int wave = tid >> 6, lane = tid & 63;
    int wm = (wave >> 1) * 64, wn = (wave & 1) * 64;
    int quad = lane >> 4, l16 = lane & 15;
    int srow0 = wave * 32;
    int lr = lane >> 2, lc = lane & 3;
    floatx4 acc[4][4] = {};

    for (int k0 = 0; k0 < K; k0 += 32) {
        #pragma unroll
        for (int i = 0; i < 2; ++i) {
            int row = srow0 + i*16 + lr;
            int gch = lc ^ ((row >> 1) & 3);
            async16(&As[srow0 + i*16][0], &A [(size_t)(bm0 + row)*K + k0 + gch*8]);
            async16(&Bs[srow0 + i*16][0], &Bt[(size_t)(bn0 + row)*K + k0 + gch*8]);
        }
        __syncthreads();
        bf16x8 af[4], bfr[4];
        #pragma unroll
        for (int mi=0;mi<4;++mi) {
            int r = wm + mi*16 + l16;
            af[mi] = *(const bf16x8*)&As[r][(quad ^ ((r >> 1) & 3))*8];
        }
        #pragma unroll
        for (int ni=0;ni<4;++ni) {
            int r = wn + ni*16 + l16;
            bfr[ni] = *(const bf16x8*)&Bs[r][(quad ^ ((r >> 1) & 3))*8];
        }
        #pragma unroll
        for (int mi=0;mi<4;++mi)
            #pragma unroll
            for (int ni=0;ni<4;++ni)
                acc[mi][ni] = __builtin_amdgcn_mfma_f32_16x16x32_bf16(af[mi], bfr[ni], acc[mi][ni], 0, 0, 0);
        __syncthreads();
    }

    #pragma unroll
    for (int mi=0;mi<4;++mi) {
        #pragma unroll
        for (int ni=0;ni<4;++ni) {
            #pragma unroll
            for (int r4=0;r4<4;++r4) {
                int gm = bm0 + wm + mi*16 + quad*4 + r4;
                int gn = bn0 + wn + ni*16 + l16;
                if (gn >= N) continue;
                float v = acc[mi][ni][r4] + bias[gn];
                if (mode == 1) {
                    out_bf[(size_t)gm*N + gn] = f2bu(v);
                } else if (mode == 2) {
                    out_f32[(size_t)gm*N + gn] += v;
                } else if (mode == 3) {
                    float g = 0.5f * v * (1.0f + erff(v * 0.70710678118654752f));
                    out_bf[(size_t)gm*N + gn] = f2bu(g);
                } else {
                    out_f32[(size_t)gm*N + gn] = v;
                }
            }
        }
    }
}

// ---------------- MFMA flash attention v3: one block per (b,h) ----------------
__global__ __launch_bounds__(256) void fattn_kernel(
    const unsigned short* __restrict__ qkv,
    const float* __restrict__ scaling_ptr, bf16* __restrict__ ao)
{
    __shared__ unsigned short Ks[256][104];
    __shared__ unsigned short Vt[80][264];    // V transposed [dim][key]
    __shared__ unsigned short Ps[64][264];    // per-wave disjoint rows
    __shared__ float ps_s[256];

    int bh = blockIdx.x, tid = threadIdx.x;
    int b = bh >> 3, h = bh & 7;
    float scaling = scaling_ptr[0];
    const float SCALE = 0.12126781251816648f;  // 68^-0.5

    const unsigned short* base = qkv + (size_t)(b*FF)*EE3;
    const unsigned short* qb_ = base + h*HDD;
    const unsigned short* kb_ = base + EE + h*HDD;
    const unsigned short* vb_ = base + 2*EE + h*HDD;

    if (tid < 256) {
        float pos = tid * (1.0f/242.0f) - 0.5f;
        ps_s[tid] = (tid < FF) ? SCALE * __expf(-scaling * pos * pos) : 0.f;
    }
    for (int idx = tid; idx < 256*18; idx += 256) {
        int r = idx / 18, c2 = idx % 18;
        *(unsigned*)&Ks[r][68 + c2*2] = 0u;
    }
    for (int idx = tid; idx < 80*13; idx += 256) {
        int dd = idx / 13, kk2 = 243 + idx % 13;
        Vt[dd][kk2] = 0;
    }
    for (int idx = tid; idx < FF*34; idx += 256) {
        int r = idx / 34, c2 = idx % 34;
        *(unsigned*)&Ks[r][c2*2] = *(const unsigned*)&kb_[(size_t)r*EE3 + c2*2];
    }
    for (int idx = tid; idx < FF*34; idx += 256) {
        int r = idx / 34, c2 = idx % 34;
        unsigned uv = *(const unsigned*)&vb_[(size_t)r*EE3 + c2*2];
        Vt[c2*2][r]   = (unsigned short)(uv & 0xffffu);
        Vt[c2*2+1][r] = (unsigned short)(uv >> 16);
    }
    __syncthreads();   // the only barrier

    int wave = tid >> 6, lane = tid & 63;
    int quad = lane >> 4, l16 = lane & 15;

    for (int t = 0; t < 4; ++t) {
        int q0 = t * 64;
        int qi = q0 + wave*16 + l16;
        int qc = (qi < FF) ? qi : (FF-1);
        const unsigned short* qrow = qb_ + (size_t)qc*EE3;
        union { bf16x8 v; uint2 u2[2]; unsigned u[4]; } t0, t1, t2;
        t0.u2[0] = *(const uint2*)&qrow[quad*8];
        t0.u2[1] = *(const uint2*)&qrow[quad*8 + 4];
        t1.u2[0] = *(const uint2*)&qrow[32 + quad*8];
        t1.u2[1] = *(const uint2*)&qrow[32 + quad*8 + 4];
        t2.u[0] = 0; t2.u[1] = 0; t2.u[2] = 0; t2.u[3] = 0;
        if (quad == 0) {
            t2.u[0] = *(const unsigned*)&qrow[64];
            t2.u[1] = *(const unsigned*)&qrow[66];
        }
        bf16x8 aq0 = t0.v, aq1 = t1.v, aq2 = t2.v;

        floatx4 sacc[16];
        #pragma unroll
        for (int nt = 0; nt < 16; ++nt) {
            floatx4 c = {};
            c = __builtin_amdgcn_mfma_f32_16x16x32_bf16(aq0, *(const bf16x8*)&Ks[nt*16 + l16][quad*8], c, 0, 0, 0);
            c = __builtin_amdgcn_mfma_f32_16x16x32_bf16(aq1, *(const bf16x8*)&Ks[nt*16 + l16][32 + quad*8], c, 0, 0, 0);
            c = __builtin_amdgcn_mfma_f32_16x16x32_bf16(aq2, *(const bf16x8*)&Ks[nt*16 + l16][64 + quad*8], c, 0, 0, 0);
            sacc[nt] = c;
        }

        float rmax[4] = {-1e30f, -1e30f, -1e30f, -1e30f};
        #pragma unroll
        for (int nt = 0; nt < 16; ++nt) {
            float psc = ps_s[nt*16 + l16];
            bool maskc = (nt*16 + l16) >= FF;
            #pragma unroll
            for (int rg = 0; rg < 4; ++rg) {
                float s = maskc ? -1e30f : sacc[nt][rg] * psc;
                sacc[nt][rg] = s;
                rmax[rg] = fmaxf(rmax[rg], s);
            }
        }
        #pragma unroll
        for (int rg = 0; rg < 4; ++rg) {
            float m0 = rmax[rg];
            m0 = fmaxf(m0, __shfl_xor(m0, 1));
            m0 = fmaxf(m0, __shfl_xor(m0, 2));
            m0 = fmaxf(m0, __shfl_xor(m0, 4));
            m0 = fmaxf(m0, __shfl_xor(m0, 8));
            rmax[rg] = m0;
        }
        float rs[4] = {0.f, 0.f, 0.f, 0.f};
        #pragma unroll
        for (int nt = 0; nt < 16; ++nt)
            #pragma unroll
            for (int rg = 0; rg < 4; ++rg) {
                float p = __expf(sacc[nt][rg] - rmax[rg]);
                sacc[nt][rg] = p;
                rs[rg] += p;
            }
        #pragma unroll
        for (int rg = 0; rg < 4; ++rg) {
            float s0 = rs[rg];
            s0 += __shfl_xor(s0, 1);
            s0 += __shfl_xor(s0, 2);
            s0 += __shfl_xor(s0, 4);
            s0 += __shfl_xor(s0, 8);
            rs[rg] = 1.f / s0;
        }

        #pragma unroll
        for (int nt = 0; nt < 16; ++nt)
            #pragma unroll
            for (int rg = 0; rg < 4; ++rg)
                Ps[wave*16 + quad*4 + rg][nt*16 + l16] = f2bu(sacc[nt][rg] * rs[rg]);

        bf16x8 ap[8];
        #pragma unroll
        for (int kk = 0; kk < 8; ++kk)
            ap[kk] = *(const bf16x8*)&Ps[wave*16 + l16][kk*32 + quad*8];
        #pragma unroll
        for (int nt = 0; nt < 5; ++nt) {
            floatx4 c = {};
            #pragma unroll
            for (int kk = 0; kk < 8; ++kk) {
                bf16x8 bv = *(const bf16x8*)&Vt[nt*16 + l16][kk*32 + quad*8];
                c = __builtin_amdgcn_mfma_f32_16x16x32_bf16(ap[kk], bv, c, 0, 0, 0);
            }
            int gn = nt*16 + l16;
            if (gn < HDD) {
                #pragma unroll
                for (int rg = 0; rg < 4; ++rg) {
                    int query = q0 + wave*16 + quad*4 + rg;
                    if (query < FF)
                        ao[((size_t)b*FF + query)*EE + h*HDD + gn] = f2b(c[rg]);
                }
            }
        }
    }
}

// ---------------- host launch ----------------
extern "C" void kernel_launch(void* const* d_in, const int* in_sizes, int n_in,
                              void* d_out, int out_size, void* d_ws, size_t ws_size,
                              hipStream_t stream) {
    typedef const float* fp;
    fp x          = (fp)d_in[0];
    fp gc_W       = (fp)d_in[2];
    fp gc_e       = (fp)d_in[3];
    fp gc_bias    = (fp)d_in[4];
    fp gc_q_w     = (fp)d_in[5];
    fp gc_q_b     = (fp)d_in[6];
    fp gc_k_w     = (fp)d_in[7];
    fp gc_k_b     = (fp)d_in[8];
    fp gc_attn_w  = (fp)d_in[9];
    fp gc_attn_b  = (fp)d_in[10];
    fp gc_ln_g    = (fp)d_in[11];
    fp gc_ln_b    = (fp)d_in[12];
    fp pos_embed  = (fp)d_in[13];
    fp blk1_g     = (fp)d_in[14];
    fp blk1_b     = (fp)d_in[15];
    fp at_g       = (fp)d_in[16];
    fp at_b       = (fp)d_in[17];
    fp at_pw      = (fp)d_in[18];
    fp at_pb      = (fp)d_in[19];
    fp at2_g      = (fp)d_in[20];
    fp at2_b      = (fp)d_in[21];
    fp at_scaling = (fp)d_in[22];
    fp qkv_w      = (fp)d_in[23];
    fp qkv_b      = (fp)d_in[24];
    fp proj_w     = (fp)d_in[25];
    fp proj_b     = (fp)d_in[26];
    fp blk2_g     = (fp)d_in[27];
    fp blk2_b     = (fp)d_in[28];
    fp fc1_w      = (fp)d_in[29];
    fp fc1_b      = (fp)d_in[30];
    fp fc2_w      = (fp)d_in[31];
    fp fc2_b      = (fp)d_in[32];
    fp fin_g      = (fp)d_in[33];
    fp fin_b      = (fp)d_in[34];
    fp head_w     = (fp)d_in[35];
    fp head_b     = (fp)d_in[36];

    char* wsb = (char*)d_ws;
    size_t off = 0;
    auto alloc = [&](size_t bytes) { size_t cur = off; off += (bytes + 255) & ~(size_t)255; return cur; };
    float* Aw   = (float*)(wsb + alloc(1156 * 4));
    float* Sg   = (float*)(wsb + alloc(288 * 4));
    float* xe   = (float*)(wsb + alloc(QSTRIDE * 4));
    float* sbuf = (float*)(wsb + alloc((size_t)ROWS*JJ * 4));
    bf16*  xr   = (bf16*) (wsb + alloc(QSTRIDE * 2));          // xr; reused as ao
    bf16*  xa   = (bf16*) (wsb + alloc(QSTRIDE * 2));          // xa; reused as xn2/xo
    bf16*  qkv  = (bf16*) (wsb + alloc(3 * QSTRIDE * 2));      // [ROWS][1632] row-major; reused as hm
    unsigned short* wq = (unsigned short*)(wsb + alloc((size_t)1664*544 * 2));
    unsigned short* wp = (unsigned short*)(wsb + alloc((size_t)640*544 * 2));
    unsigned short* w1 = (unsigned short*)(wsb + alloc((size_t)1152*544 * 2));
    unsigned short* w2 = (unsigned short*)(wsb + alloc((size_t)640*1088 * 2));
    (void)ws_size;

    prep_kernel<<<1, 256, 0, stream>>>(gc_e, gc_W, gc_q_w, gc_k_w, gc_q_b, gc_k_b, Aw, Sg);
    gc2_kernel<<<ROWS/GROWS, 256, 0, stream>>>(
        x, Aw, Sg, gc_W, gc_bias, gc_attn_w, gc_attn_b,
        gc_ln_g, gc_ln_b, pos_embed, xe);
    for (int d = 0; d < 4; ++d) {
        wconvT_kernel<<<dim3(52, 17), 256, 0, stream>>>(
            qkv_w + (size_t)d*EE*3*EE, wq, 1632, 544, 1664);
        wconvT_kernel<<<dim3(20, 17), 256, 0, stream>>>(
            proj_w + (size_t)d*EE*EE, wp, 544, 544, 640);
        wconvT_kernel<<<dim3(36, 17), 256, 0, stream>>>(
            fc1_w + (size_t)d*EE*HIDD, w1, 1088, 544, 1152);
        wconvT_kernel<<<dim3(20, 34), 256, 0, stream>>>(
            fc2_w + (size_t)d*HIDD*EE, w2, 544, 1088, 640);

        ln1_prelude_kernel<<<ROWS/4, 256, 0, stream>>>(
            xe, blk1_g + d*EE, blk1_b + d*EE, at_g + d*ERR, at_b + d*ERR,
            at_pw + d*ERR, at_pb + d, xr, sbuf);
        softmax_frames_kernel<<<BB*JJ/4, 256, 0, stream>>>(sbuf);
        lnC_kernel<<<ROWS/4, 256, 0, stream>>>(xr, sbuf, at2_g + d*EE, at2_b + d*EE, xa);
        mgemm_kernel<<<dim3(13, 243), 256, 0, stream>>>(
            (const unsigned short*)xa, wq, qkv_b + d*3*EE,
            nullptr, (unsigned short*)qkv, 1632, 544, 1);
        fattn_kernel<<<BB*NHH, 256, 0, stream>>>(
            (const unsigned short*)qkv, at_scaling + d, xr);
        mgemm_kernel<<<dim3(5, 243), 256, 0, stream>>>(
            (const unsigned short*)xr, wp, proj_b + d*EE,
            xe, nullptr, 544, 544, 2);
        ln_row_kernel<<<ROWS/4, 256, 0, stream>>>(xe, blk2_g + d*EE, blk2_b + d*EE, xa, 1e-6f);
        mgemm_kernel<<<dim3(9, 243), 256, 0, stream>>>(
            (const unsigned short*)xa, w1, fc1_b + d*HIDD,
            nullptr, (unsigned short*)qkv, 1088, 544, 3);   // hm into qkv region
        mgemm_kernel<<<dim3(5, 243), 256, 0, stream>>>(
            (const unsigned short*)qkv, w2, fc2_b + d*EE,
            xe, nullptr, 544, 1088, 2);
    }
    ln_row_kernel<<<ROWS/4, 256, 0, stream>>>(xe, fin_g, fin_b, xa, 1e-6f);
    wconvT_kernel<<<dim3(4, 17), 256, 0, stream>>>(head_w, wq, 51, 544, 128);
    mgemm_kernel<<<dim3(1, 243), 256, 0, stream>>>(
        (const unsigned short*)xa, wq, head_b,
        (float*)d_out, nullptr, 51, 544, 4);
}

// Round 12
// 2706.014 us; speedup vs baseline: 11.1447x; 1.0614x over previous
//
#include <hip/hip_runtime.h>
#include <hip/hip_bf16.h>
#include <math.h>

// ---------------- constants ----------------
#define BB 128
#define FF 243
#define JJ 17
#define ERR 32
#define EE 544
#define EE3 1632
#define NHH 8
#define HDD 68
#define HIDD 1088
#define ROWS 31104          // B*F
#define QSTRIDE 16920576ULL // ROWS*EE
#define GROWS 16            // rows per gc2 block
#define NTM 243             // M tiles (31104/128)

typedef __hip_bfloat16 bf16;
typedef __bf16 bf16x8 __attribute__((ext_vector_type(8)));
typedef float floatx4 __attribute__((ext_vector_type(4)));

static __device__ __forceinline__ float b2f(bf16 v) { return __bfloat162float(v); }
static __device__ __forceinline__ bf16 f2b(float v) { return __float2bfloat16(v); }
static __device__ __forceinline__ unsigned short f2bu(float v) {
    bf16 h = __float2bfloat16(v);
    return *(unsigned short*)&h;
}
// async global->LDS, 16B per lane; dest = wave-uniform base + lane*16
static __device__ __forceinline__ void async16(void* lds, const void* g) {
    __builtin_amdgcn_global_load_lds(
        (const __attribute__((address_space(1))) unsigned*)g,
        (__attribute__((address_space(3))) unsigned*)lds, 16, 0, 0);
}

// ---------------- prep: adjacency softmax + folded q/k projection (parallel) ------
__global__ __launch_bounds__(256) void prep_kernel(
    const float* __restrict__ gc_e, const float* __restrict__ gc_W,
    const float* __restrict__ qw, const float* __restrict__ kw,
    const float* __restrict__ qb, const float* __restrict__ kb,
    float* __restrict__ A, float* __restrict__ Sg)
{
    __shared__ float a1[17][17], a2[17][17], a3[17][17];
    int tid = threadIdx.x;
    const int parents[17] = {-1,0,1,2,0,4,5,0,7,8,9,8,11,12,8,14,15};
    for (int t = tid; t < 289; t += 256) {
        int i = t / 17, j = t % 17;
        bool e = (parents[i] == j) || (parents[j] == i);
        a1[i][j] = e ? 1.f : 0.f;
    }
    __syncthreads();
    for (int t = tid; t < 289; t += 256) {
        int i = t / 17, j = t % 17;
        float s = 0.f;
        #pragma unroll
        for (int k = 0; k < 17; ++k) s += a1[i][k] * a1[k][j];
        a2[i][j] = s;
    }
    __syncthreads();
    for (int t = tid; t < 289; t += 256) {
        int i = t / 17, j = t % 17;
        float s = 0.f;
        #pragma unroll
        for (int k = 0; k < 17; ++k) s += a2[i][k] * a1[k][j];
        a3[i][j] = s;
    }
    __syncthreads();
    for (int p = tid; p < 68; p += 256) {
        int n = p / 17, i = p % 17;
        bool msk[17];
        float m = -1e30f;
        for (int j=0;j<17;++j) {
            bool mm;
            if (n==0) mm = (i==j);
            else if (n==1) mm = a1[i][j] > 0.f;
            else if (n==2) mm = a2[i][j] > 0.f;
            else mm = a3[i][j] > 0.f;
            msk[j] = mm;
            if (mm) m = fmaxf(m, gc_e[(n*17+i)*17+j]);
        }
        float ex[17]; float s=0.f;
        for (int j=0;j<17;++j){ ex[j] = msk[j] ? expf(gc_e[(n*17+i)*17+j]-m) : 0.f; s+=ex[j]; }
        float inv = 1.f/s;
        for (int j=0;j<17;++j) A[(n*17+i)*17+j] = ex[j]*inv;
    }
    if (tid < 256) {
        int c = tid >> 7, n = (tid >> 5) & 3, o2 = tid & 31;
        float s = 0.f;
        for (int o = 0; o < 32; ++o)
            s += gc_W[(n*2+c)*32 + o] * (qw[o*32+o2] + kw[o*32+o2]);
        Sg[tid] = s;
    }
    if (tid < 32) Sg[256 + tid] = qb[tid] + kb[tid];
}

// ---------------- gc2: fused graph conv, 16 rows per block ----------------
__global__ __launch_bounds__(256) void gc2_kernel(
    const float* __restrict__ x, const float* __restrict__ A, const float* __restrict__ Sg,
    const float* __restrict__ gc_W, const float* __restrict__ gc_bias,
    const float* __restrict__ aw, const float* __restrict__ ab,
    const float* __restrict__ lng, const float* __restrict__ lnb,
    const float* __restrict__ pos_embed, float* __restrict__ xe)
{
    __shared__ float As[4][17][17];
    __shared__ float S0[4][33], S1[4][33], bqk[32];
    __shared__ float Ws[4][2][32];
    __shared__ float aws[32], lngs[32], lnbs[32], gbias[32];
    __shared__ float xf[GROWS][34];
    __shared__ float c0[GROWS][68], c1[GROWS][68];
    __shared__ float sc[GROWS][68];
    int tid = threadIdx.x;
    int r0 = blockIdx.x * GROWS;

    for (int i = tid; i < 1156; i += 256) ((float*)As)[i] = A[i];
    if (tid < 128) S0[tid>>5][tid&31] = Sg[tid];
    else           S1[(tid-128)>>5][(tid-128)&31] = Sg[tid];
    if (tid < 32) bqk[tid] = Sg[256+tid];
    if (tid >= 32 && tid < 64)  aws[tid-32]  = aw[tid-32];
    if (tid >= 64 && tid < 96)  lngs[tid-64] = lng[tid-64];
    if (tid >= 96 && tid < 128) lnbs[tid-96] = lnb[tid-96];
    if (tid >= 128 && tid < 160) gbias[tid-128] = gc_bias[tid-128];
    ((float*)Ws)[tid] = gc_W[tid];
    for (int i = tid; i < GROWS*34; i += 256) ((float*)xf)[i] = x[(size_t)r0*34 + i];
    __syncthreads();

    for (int u = tid; u < GROWS*68; u += 256) {
        int row = u / 68, t = u % 68, i = t >> 2, n = t & 3;
        float a0 = 0.f, a1v = 0.f;
        #pragma unroll
        for (int j = 0; j < 17; ++j) {
            float a = As[n][i][j];
            a0  = fmaf(a, xf[row][2*j],   a0);
            a1v = fmaf(a, xf[row][2*j+1], a1v);
        }
        c0[row][t] = a0; c1[row][t] = a1v;
    }
    __syncthreads();

    float abv = ab[0];
    for (int u = tid; u < GROWS*68; u += 256) {
        int row = u / 68, t = u % 68, n = t & 3;
        float v0 = c0[row][t], v1 = c1[row][t];
        float acc = abv;
        #pragma unroll
        for (int o2 = 0; o2 < 32; ++o2) {
            float z = fmaf(v0, S0[n][o2], fmaf(v1, S1[n][o2], bqk[o2]));
            acc = fmaf(tanhf(z), aws[o2], acc);
        }
        sc[row][t] = acc;
    }
    __syncthreads();

    if (tid < GROWS*4) {
        int row = tid >> 2, n = tid & 3;
        float m = -1e30f;
        for (int i = 0; i < 17; ++i) m = fmaxf(m, sc[row][i*4+n]);
        float w[17]; float s = 0.f;
        for (int i = 0; i < 17; ++i) { w[i] = expf(sc[row][i*4+n] - m); s += w[i]; }
        float inv = 1.f / s;
        for (int i = 0; i < 17; ++i) {
            float ww = w[i] * inv;
            c0[row][i*4+n] *= ww;
            c1[row][i*4+n] *= ww;
        }
    }
    __syncthreads();

    int g16 = tid >> 4, lg = tid & 15;
    for (int pair = g16; pair < GROWS*JJ; pair += 16) {
        int row = pair / JJ, j = pair % JJ;
        float e00=c0[row][j*4+0], e01=c0[row][j*4+1], e02=c0[row][j*4+2], e03=c0[row][j*4+3];
        float e10=c1[row][j*4+0], e11=c1[row][j*4+1], e12=c1[row][j*4+2], e13=c1[row][j*4+3];
        int o0 = lg, o1 = lg + 16;
        float a0 = gbias[o0], a1 = gbias[o1];
        a0 = fmaf(e00, Ws[0][0][o0], a0); a0 = fmaf(e10, Ws[0][1][o0], a0);
        a0 = fmaf(e01, Ws[1][0][o0], a0); a0 = fmaf(e11, Ws[1][1][o0], a0);
        a0 = fmaf(e02, Ws[2][0][o0], a0); a0 = fmaf(e12, Ws[2][1][o0], a0);
        a0 = fmaf(e03, Ws[3][0][o0], a0); a0 = fmaf(e13, Ws[3][1][o0], a0);
        a1 = fmaf(e00, Ws[0][0][o1], a1); a1 = fmaf(e10, Ws[0][1][o1], a1);
        a1 = fmaf(e01, Ws[1][0][o1], a1); a1 = fmaf(e11, Ws[1][1][o1], a1);
        a1 = fmaf(e02, Ws[2][0][o1], a1); a1 = fmaf(e12, Ws[2][1][o1], a1);
        a1 = fmaf(e03, Ws[3][0][o1], a1); a1 = fmaf(e13, Ws[3][1][o1], a1);
        float ssum = a0 + a1;
        ssum += __shfl_xor(ssum, 1); ssum += __shfl_xor(ssum, 2);
        ssum += __shfl_xor(ssum, 4); ssum += __shfl_xor(ssum, 8);
        float mu = ssum * (1.f/32.f);
        float d0 = a0 - mu, d1 = a1 - mu;
        float vv = d0*d0 + d1*d1;
        vv += __shfl_xor(vv, 1); vv += __shfl_xor(vv, 2);
        vv += __shfl_xor(vv, 4); vv += __shfl_xor(vv, 8);
        float rstd = rsqrtf(vv*(1.f/32.f) + 1e-5f);
        int r = r0 + row, f = r % FF;
        const float* pe = pos_embed + (size_t)f*EE + j*32;
        float* dst = xe + (size_t)r*EE + j*32;
        dst[o0] = fmaxf(d0*rstd*lngs[o0] + lnbs[o0], 0.f) + pe[o0];
        dst[o1] = fmaxf(d1*rstd*lngs[o1] + lnbs[o1], 0.f) + pe[o1];
    }
}

// ---------------- LN1 + per-joint LN + pooling-score (wave per row, 4 rows/block) --
__global__ __launch_bounds__(256) void ln1_prelude_kernel(
    const float* __restrict__ xe,
    const float* __restrict__ g1, const float* __restrict__ b1,
    const float* __restrict__ ang, const float* __restrict__ anb,
    const float* __restrict__ apw, const float* __restrict__ apb,
    bf16* __restrict__ xr_out, float* __restrict__ s_out)
{
    __shared__ float rowbuf[4][561];     // joint-padded stride 33
    __shared__ float jm[4][17], jrs[4][17];
    __shared__ float angs[32], anbs[32], apws[32];
    int tid = threadIdx.x, w = tid >> 6, lane = tid & 63;
    int r = blockIdx.x*4 + w;
    if (tid < 32) { angs[tid]=ang[tid]; anbs[tid]=anb[tid]; apws[tid]=apw[tid]; }
    float vals[9];
    float ls = 0.f;
    #pragma unroll
    for (int s=0;s<9;++s){ int e=s*64+lane; if(e<EE){ float v=xe[(size_t)r*EE+e]; vals[s]=v; ls+=v; } else vals[s]=0.f; }
    #pragma unroll
    for (int m=1;m<64;m<<=1) ls += __shfl_xor(ls, m);
    float mean = ls*(1.f/544.f);
    float lv = 0.f;
    #pragma unroll
    for (int s=0;s<9;++s){ int e=s*64+lane; if(e<EE){ float d=vals[s]-mean; lv+=d*d; } }
    #pragma unroll
    for (int m=1;m<64;m<<=1) lv += __shfl_xor(lv, m);
    float rstd = rsqrtf(lv*(1.f/544.f)+1e-6f);
    #pragma unroll
    for (int s=0;s<9;++s){ int e=s*64+lane; if(e<EE)
        rowbuf[w][(e>>5)*33+(e&31)] = (vals[s]-mean)*rstd*g1[e] + b1[e]; }
    __syncthreads();
    if (lane < 17) {
        float s0=0.f, s1=0.f;
        for (int o=0;o<32;++o){ float v=rowbuf[w][lane*33+o]; s0+=v; s1+=v*v; }
        float mu = s0*(1.f/32.f);
        jm[w][lane]=mu; jrs[w][lane]=rsqrtf(s1*(1.f/32.f)-mu*mu+1e-5f);
    }
    __syncthreads();
    #pragma unroll
    for (int s=0;s<9;++s){ int e=s*64+lane; if(e<EE){
        int j=e>>5, o=e&31;
        float v = (rowbuf[w][j*33+o]-jm[w][j])*jrs[w][j]*angs[o] + anbs[o];
        xr_out[(size_t)r*EE+e] = f2b(v);
        rowbuf[w][j*33+o] = v; } }
    __syncthreads();
    if (lane < 17) {
        float acc = apb[0];
        for (int o=0;o<32;++o) acc += rowbuf[w][lane*33+o]*apws[o];
        s_out[(size_t)r*JJ+lane] = acc;
    }
}

// ---------------- softmax over frames (wave per (b,joint)) ----------------
__global__ __launch_bounds__(256) void softmax_frames_kernel(float* __restrict__ s)
{
    int tid = threadIdx.x, w = tid >> 6, lane = tid & 63;
    int bid = blockIdx.x*4 + w; int b = bid/JJ, j = bid%JJ;
    float* base = s + (size_t)b*FF*JJ + j;
    float v[4]; float m = -1e30f;
    #pragma unroll
    for (int s2=0;s2<4;++s2){ int e=s2*64+lane;
        v[s2] = (e<FF) ? base[(size_t)e*JJ] : -1e30f;
        m = fmaxf(m, v[s2]); }
    #pragma unroll
    for (int mm=1;mm<64;mm<<=1) m = fmaxf(m, __shfl_xor(m, mm));
    float lsum = 0.f;
    #pragma unroll
    for (int s2=0;s2<4;++s2){ int e=s2*64+lane;
        if (e<FF){ v[s2] = __expf(v[s2]-m); lsum += v[s2]; } }
    #pragma unroll
    for (int mm=1;mm<64;mm<<=1) lsum += __shfl_xor(lsum, mm);
    float inv = 1.f/lsum;
    #pragma unroll
    for (int s2=0;s2<4;++s2){ int e=s2*64+lane;
        if (e<FF) base[(size_t)e*JJ] = v[s2]*inv; }
}

// ---------------- xa = LN544(xr * wf) (wave per row) ----------------
__global__ __launch_bounds__(256) void lnC_kernel(
    const bf16* __restrict__ xr, const float* __restrict__ wf,
    const float* __restrict__ g, const float* __restrict__ b,
    bf16* __restrict__ xa)
{
    __shared__ float wfb[4][17];
    int tid = threadIdx.x, w = tid >> 6, lane = tid & 63;
    int r = blockIdx.x*4 + w;
    if (lane < 17) wfb[w][lane] = wf[(size_t)r*JJ + lane];
    __syncthreads();
    float vals[9]; float ls = 0.f;
    #pragma unroll
    for (int s=0;s<9;++s){ int e=s*64+lane; if(e<EE){
        float v = b2f(xr[(size_t)r*EE+e])*wfb[w][e>>5]; vals[s]=v; ls+=v; } else vals[s]=0.f; }
    #pragma unroll
    for (int m=1;m<64;m<<=1) ls += __shfl_xor(ls, m);
    float mean = ls*(1.f/544.f);
    float lv = 0.f;
    #pragma unroll
    for (int s=0;s<9;++s){ int e=s*64+lane; if(e<EE){ float d=vals[s]-mean; lv+=d*d; } }
    #pragma unroll
    for (int m=1;m<64;m<<=1) lv += __shfl_xor(lv, m);
    float rstd = rsqrtf(lv*(1.f/544.f)+1e-5f);
    #pragma unroll
    for (int s=0;s<9;++s){ int e=s*64+lane; if(e<EE)
        xa[(size_t)r*EE+e] = f2b((vals[s]-mean)*rstd*g[e] + b[e]); }
}

// ---------------- generic LN over 544 (wave per row, no LDS) ----------------
__global__ __launch_bounds__(256) void ln_row_kernel(
    const float* __restrict__ in, const float* __restrict__ g,
    const float* __restrict__ b, bf16* __restrict__ out, float eps)
{
    int tid = threadIdx.x, w = tid >> 6, lane = tid & 63;
    int r = blockIdx.x*4 + w;
    float vals[9]; float ls = 0.f;
    #pragma unroll
    for (int s=0;s<9;++s){ int e=s*64+lane; if(e<EE){ float v=in[(size_t)r*EE+e]; vals[s]=v; ls+=v; } else vals[s]=0.f; }
    #pragma unroll
    for (int m=1;m<64;m<<=1) ls += __shfl_xor(ls, m);
    float mean = ls*(1.f/544.f);
    float lv = 0.f;
    #pragma unroll
    for (int s=0;s<9;++s){ int e=s*64+lane; if(e<EE){ float d=vals[s]-mean; lv+=d*d; } }
    #pragma unroll
    for (int m=1;m<64;m<<=1) lv += __shfl_xor(lv, m);
    float rstd = rsqrtf(lv*(1.f/544.f)+eps);
    #pragma unroll
    for (int s=0;s<9;++s){ int e=s*64+lane; if(e<EE)
        out[(size_t)r*EE+e] = f2b((vals[s]-mean)*rstd*g[e] + b[e]); }
}

// ---------------- weight transpose-convert, coalesced via LDS 32x32 tiles ---------
__global__ __launch_bounds__(256) void wconvT_kernel(
    const float* __restrict__ W, unsigned short* __restrict__ out,
    int N, int K, int Npad)
{
    __shared__ float tile[32][33];
    int bn = blockIdx.x * 32, bk = blockIdx.y * 32;
    int tx = threadIdx.x & 31, ty = threadIdx.x >> 5;   // 32 x 8
    #pragma unroll
    for (int i = 0; i < 4; ++i) {
        int k = bk + ty + i*8, n = bn + tx;
        tile[ty + i*8][tx] = (k < K && n < N) ? W[(size_t)k*N + n] : 0.f;
    }
    __syncthreads();
    #pragma unroll
    for (int i = 0; i < 4; ++i) {
        int n = bn + ty + i*8, k = bk + tx;
        if (n < Npad && k < K) out[(size_t)n*K + k] = f2bu(tile[tx][ty + i*8]);
    }
}

// ---------------- MFMA GEMM, XCD-clustered 1-D grid ----------------
// grid = ceil(NTM/8)*8*ntn blocks; decode keeps all N-tiles of an M-tile on one
// XCD (blockIdx%8 == m_tile&7 under round-robin XCD dispatch) so the A-tile is
// fetched into exactly one L2.
__global__ __launch_bounds__(256) void mgemm_kernel(
    const unsigned short* __restrict__ A, const unsigned short* __restrict__ Bt,
    const float* __restrict__ bias,
    float* __restrict__ out_f32, unsigned short* __restrict__ out_bf,
    int N, int K, int ntn, int mode)
{
    __shared__ unsigned short As[128][32];
    __shared__ unsigned short Bs[128][32];
    int g = blockIdx.x;
    int grp = 8 * ntn;
    int w_ = g % grp, chunk = g / grp;
    int mt = chunk*8 + (w_ & 7), nt = w_ >> 3;
    if (mt >= NTM) return;
    int bm0 = mt * 128, bn0 = nt * 128;
    int tid = threadIdx.x;
    int wave = tid >> 6, lane = tid & 63;
    int wm = (wave >> 1) * 64, wn = (wave & 1) * 64;
    int quad = lane >> 4, l16 = lane & 15;
    int srow0 = wave * 32;
    int lr = lane >> 2, lc = lane & 3;
    floatx4 acc[4][4] = {};

    for (int k0 = 0; k0 < K; k0 += 32) {
        #pragma unroll
        for (int i = 0; i < 2; ++i) {
            int row = srow0 + i*16 + lr;
            int gch = lc ^ ((row >> 1) & 3);
            async16(&As[srow0 + i*16][0], &A [(size_t)(bm0 + row)*K + k0 + gch*8]);
            async16(&Bs[srow0 + i*16][0], &Bt[(size_t)(bn0 + row)*K + k0 + gch*8]);
        }
        __syncthreads();
        bf16x8 af[4], bfr[4];
        #pragma unroll
        for (int mi=0;mi<4;++mi) {
            int r = wm + mi*16 + l16;
            af[mi] = *(const bf16x8*)&As[r][(quad ^ ((r >> 1) & 3))*8];
        }
        #pragma unroll
        for (int ni=0;ni<4;++ni) {
            int r = wn + ni*16 + l16;
            bfr[ni] = *(const bf16x8*)&Bs[r][(quad ^ ((r >> 1) & 3))*8];
        }
        #pragma unroll
        for (int mi=0;mi<4;++mi)
            #pragma unroll
            for (int ni=0;ni<4;++ni)
                acc[mi][ni] = __builtin_amdgcn_mfma_f32_16x16x32_bf16(af[mi], bfr[ni], acc[mi][ni], 0, 0, 0);
        __syncthreads();
    }

    #pragma unroll
    for (int mi=0;mi<4;++mi) {
        #pragma unroll
        for (int ni=0;ni<4;++ni) {
            #pragma unroll
            for (int r4=0;r4<4;++r4) {
                int gm = bm0 + wm + mi*16 + quad*4 + r4;
                int gn = bn0 + wn + ni*16 + l16;
                if (gn >= N) continue;
                float v = acc[mi][ni][r4] + bias[gn];
                if (mode == 1) {
                    out_bf[(size_t)gm*N + gn] = f2bu(v);
                } else if (mode == 2) {
                    out_f32[(size_t)gm*N + gn] += v;
                } else if (mode == 3) {
                    float g2 = 0.5f * v * (1.0f + erff(v * 0.70710678118654752f));
                    out_bf[(size_t)gm*N + gn] = f2bu(g2);
                } else {
                    out_f32[(size_t)gm*N + gn] = v;
                }
            }
        }
    }
}

// ---------------- MFMA flash attention v3: one block per (b,h) ----------------
__global__ __launch_bounds__(256) void fattn_kernel(
    const unsigned short* __restrict__ qkv,
    const float* __restrict__ scaling_ptr, bf16* __restrict__ ao)
{
    __shared__ unsigned short Ks[256][104];
    __shared__ unsigned short Vt[80][264];    // V transposed [dim][key]
    __shared__ unsigned short Ps[64][264];    // per-wave disjoint rows
    __shared__ float ps_s[256];

    int bh = blockIdx.x, tid = threadIdx.x;
    int b = bh >> 3, h = bh & 7;
    float scaling = scaling_ptr[0];
    const float SCALE = 0.12126781251816648f;  // 68^-0.5

    const unsigned short* base = qkv + (size_t)(b*FF)*EE3;
    const unsigned short* qb_ = base + h*HDD;
    const unsigned short* kb_ = base + EE + h*HDD;
    const unsigned short* vb_ = base + 2*EE + h*HDD;

    if (tid < 256) {
        float pos = tid * (1.0f/242.0f) - 0.5f;
        ps_s[tid] = (tid < FF) ? SCALE * __expf(-scaling * pos * pos) : 0.f;
    }
    for (int idx = tid; idx < 256*18; idx += 256) {
        int r = idx / 18, c2 = idx % 18;
        *(unsigned*)&Ks[r][68 + c2*2] = 0u;
    }
    for (int idx = tid; idx < 80*13; idx += 256) {
        int dd = idx / 13, kk2 = 243 + idx % 13;
        Vt[dd][kk2] = 0;
    }
    for (int idx = tid; idx < FF*34; idx += 256) {
        int r = idx / 34, c2 = idx % 34;
        *(unsigned*)&Ks[r][c2*2] = *(const unsigned*)&kb_[(size_t)r*EE3 + c2*2];
    }
    for (int idx = tid; idx < FF*34; idx += 256) {
        int r = idx / 34, c2 = idx % 34;
        unsigned uv = *(const unsigned*)&vb_[(size_t)r*EE3 + c2*2];
        Vt[c2*2][r]   = (unsigned short)(uv & 0xffffu);
        Vt[c2*2+1][r] = (unsigned short)(uv >> 16);
    }
    __syncthreads();   // the only barrier

    int wave = tid >> 6, lane = tid & 63;
    int quad = lane >> 4, l16 = lane & 15;

    for (int t = 0; t < 4; ++t) {
        int q0 = t * 64;
        int qi = q0 + wave*16 + l16;
        int qc = (qi < FF) ? qi : (FF-1);
        const unsigned short* qrow = qb_ + (size_t)qc*EE3;
        union { bf16x8 v; uint2 u2[2]; unsigned u[4]; } t0, t1, t2;
        t0.u2[0] = *(const uint2*)&qrow[quad*8];
        t0.u2[1] = *(const uint2*)&qrow[quad*8 + 4];
        t1.u2[0] = *(const uint2*)&qrow[32 + quad*8];
        t1.u2[1] = *(const uint2*)&qrow[32 + quad*8 + 4];
        t2.u[0] = 0; t2.u[1] = 0; t2.u[2] = 0; t2.u[3] = 0;
        if (quad == 0) {
            t2.u[0] = *(const unsigned*)&qrow[64];
            t2.u[1] = *(const unsigned*)&qrow[66];
        }
        bf16x8 aq0 = t0.v, aq1 = t1.v, aq2 = t2.v;

        floatx4 sacc[16];
        #pragma unroll
        for (int nt = 0; nt < 16; ++nt) {
            floatx4 c = {};
            c = __builtin_amdgcn_mfma_f32_16x16x32_bf16(aq0, *(const bf16x8*)&Ks[nt*16 + l16][quad*8], c, 0, 0, 0);
            c = __builtin_amdgcn_mfma_f32_16x16x32_bf16(aq1, *(const bf16x8*)&Ks[nt*16 + l16][32 + quad*8], c, 0, 0, 0);
            c = __builtin_amdgcn_mfma_f32_16x16x32_bf16(aq2, *(const bf16x8*)&Ks[nt*16 + l16][64 + quad*8], c, 0, 0, 0);
            sacc[nt] = c;
        }

        float rmax[4] = {-1e30f, -1e30f, -1e30f, -1e30f};
        #pragma unroll
        for (int nt = 0; nt < 16; ++nt) {
            float psc = ps_s[nt*16 + l16];
            bool maskc = (nt*16 + l16) >= FF;
            #pragma unroll
            for (int rg = 0; rg < 4; ++rg) {
                float s = maskc ? -1e30f : sacc[nt][rg] * psc;
                sacc[nt][rg] = s;
                rmax[rg] = fmaxf(rmax[rg], s);
            }
        }
        #pragma unroll
        for (int rg = 0; rg < 4; ++rg) {
            float m0 = rmax[rg];
            m0 = fmaxf(m0, __shfl_xor(m0, 1));
            m0 = fmaxf(m0, __shfl_xor(m0, 2));
            m0 = fmaxf(m0, __shfl_xor(m0, 4));
            m0 = fmaxf(m0, __shfl_xor(m0, 8));
            rmax[rg] = m0;
        }
        float rs[4] = {0.f, 0.f, 0.f, 0.f};
        #pragma unroll
        for (int nt = 0; nt < 16; ++nt)
            #pragma unroll
            for (int rg = 0; rg < 4; ++rg) {
                float p = __expf(sacc[nt][rg] - rmax[rg]);
                sacc[nt][rg] = p;
                rs[rg] += p;
            }
        #pragma unroll
        for (int rg = 0; rg < 4; ++rg) {
            float s0 = rs[rg];
            s0 += __shfl_xor(s0, 1);
            s0 += __shfl_xor(s0, 2);
            s0 += __shfl_xor(s0, 4);
            s0 += __shfl_xor(s0, 8);
            rs[rg] = 1.f / s0;
        }

        #pragma unroll
        for (int nt = 0; nt < 16; ++nt)
            #pragma unroll
            for (int rg = 0; rg < 4; ++rg)
                Ps[wave*16 + quad*4 + rg][nt*16 + l16] = f2bu(sacc[nt][rg] * rs[rg]);

        bf16x8 ap[8];
        #pragma unroll
        for (int kk = 0; kk < 8; ++kk)
            ap[kk] = *(const bf16x8*)&Ps[wave*16 + l16][kk*32 + quad*8];
        #pragma unroll
        for (int nt = 0; nt < 5; ++nt) {
            floatx4 c = {};
            #pragma unroll
            for (int kk = 0; kk < 8; ++kk) {
                bf16x8 bv = *(const bf16x8*)&Vt[nt*16 + l16][kk*32 + quad*8];
                c = __builtin_amdgcn_mfma_f32_16x16x32_bf16(ap[kk], bv, c, 0, 0, 0);
            }
            int gn = nt*16 + l16;
            if (gn < HDD) {
                #pragma unroll
                for (int rg = 0; rg < 4; ++rg) {
                    int query = q0 + wave*16 + quad*4 + rg;
                    if (query < FF)
                        ao[((size_t)b*FF + query)*EE + h*HDD + gn] = f2b(c[rg]);
                }
            }
        }
    }
}

// ---------------- host launch ----------------
extern "C" void kernel_launch(void* const* d_in, const int* in_sizes, int n_in,
                              void* d_out, int out_size, void* d_ws, size_t ws_size,
                              hipStream_t stream) {
    typedef const float* fp;
    fp x          = (fp)d_in[0];
    fp gc_W       = (fp)d_in[2];
    fp gc_e       = (fp)d_in[3];
    fp gc_bias    = (fp)d_in[4];
    fp gc_q_w     = (fp)d_in[5];
    fp gc_q_b     = (fp)d_in[6];
    fp gc_k_w     = (fp)d_in[7];
    fp gc_k_b     = (fp)d_in[8];
    fp gc_attn_w  = (fp)d_in[9];
    fp gc_attn_b  = (fp)d_in[10];
    fp gc_ln_g    = (fp)d_in[11];
    fp gc_ln_b    = (fp)d_in[12];
    fp pos_embed  = (fp)d_in[13];
    fp blk1_g     = (fp)d_in[14];
    fp blk1_b     = (fp)d_in[15];
    fp at_g       = (fp)d_in[16];
    fp at_b       = (fp)d_in[17];
    fp at_pw      = (fp)d_in[18];
    fp at_pb      = (fp)d_in[19];
    fp at2_g      = (fp)d_in[20];
    fp at2_b      = (fp)d_in[21];
    fp at_scaling = (fp)d_in[22];
    fp qkv_w      = (fp)d_in[23];
    fp qkv_b      = (fp)d_in[24];
    fp proj_w     = (fp)d_in[25];
    fp proj_b     = (fp)d_in[26];
    fp blk2_g     = (fp)d_in[27];
    fp blk2_b     = (fp)d_in[28];
    fp fc1_w      = (fp)d_in[29];
    fp fc1_b      = (fp)d_in[30];
    fp fc2_w      = (fp)d_in[31];
    fp fc2_b      = (fp)d_in[32];
    fp fin_g      = (fp)d_in[33];
    fp fin_b      = (fp)d_in[34];
    fp head_w     = (fp)d_in[35];
    fp head_b     = (fp)d_in[36];

    char* wsb = (char*)d_ws;
    size_t off = 0;
    auto alloc = [&](size_t bytes) { size_t cur = off; off += (bytes + 255) & ~(size_t)255; return cur; };
    float* Aw   = (float*)(wsb + alloc(1156 * 4));
    float* Sg   = (float*)(wsb + alloc(288 * 4));
    float* xe   = (float*)(wsb + alloc(QSTRIDE * 4));
    float* sbuf = (float*)(wsb + alloc((size_t)ROWS*JJ * 4));
    bf16*  xr   = (bf16*) (wsb + alloc(QSTRIDE * 2));          // xr; reused as ao
    bf16*  xa   = (bf16*) (wsb + alloc(QSTRIDE * 2));          // xa; reused as xn2/xo
    bf16*  qkv  = (bf16*) (wsb + alloc(3 * QSTRIDE * 2));      // [ROWS][1632] row-major; reused as hm
    unsigned short* wq = (unsigned short*)(wsb + alloc((size_t)1664*544 * 2));
    unsigned short* wp = (unsigned short*)(wsb + alloc((size_t)640*544 * 2));
    unsigned short* w1 = (unsigned short*)(wsb + alloc((size_t)1152*544 * 2));
    unsigned short* w2 = (unsigned short*)(wsb + alloc((size_t)640*1088 * 2));
    (void)ws_size;

    const int CH = 31 * 8;   // ceil(243/8)*8 M-slots

    prep_kernel<<<1, 256, 0, stream>>>(gc_e, gc_W, gc_q_w, gc_k_w, gc_q_b, gc_k_b, Aw, Sg);
    gc2_kernel<<<ROWS/GROWS, 256, 0, stream>>>(
        x, Aw, Sg, gc_W, gc_bias, gc_attn_w, gc_attn_b,
        gc_ln_g, gc_ln_b, pos_embed, xe);
    for (int d = 0; d < 4; ++d) {
        wconvT_kernel<<<dim3(52, 17), 256, 0, stream>>>(
            qkv_w + (size_t)d*EE*3*EE, wq, 1632, 544, 1664);
        wconvT_kernel<<<dim3(20, 17), 256, 0, stream>>>(
            proj_w + (size_t)d*EE*EE, wp, 544, 544, 640);
        wconvT_kernel<<<dim3(36, 17), 256, 0, stream>>>(
            fc1_w + (size_t)d*EE*HIDD, w1, 1088, 544, 1152);
        wconvT_kernel<<<dim3(20, 34), 256, 0, stream>>>(
            fc2_w + (size_t)d*HIDD*EE, w2, 544, 1088, 640);

        ln1_prelude_kernel<<<ROWS/4, 256, 0, stream>>>(
            xe, blk1_g + d*EE, blk1_b + d*EE, at_g + d*ERR, at_b + d*ERR,
            at_pw + d*ERR, at_pb + d, xr, sbuf);
        softmax_frames_kernel<<<BB*JJ/4, 256, 0, stream>>>(sbuf);
        lnC_kernel<<<ROWS/4, 256, 0, stream>>>(xr, sbuf, at2_g + d*EE, at2_b + d*EE, xa);
        mgemm_kernel<<<CH*13, 256, 0, stream>>>(
            (const unsigned short*)xa, wq, qkv_b + d*3*EE,
            nullptr, (unsigned short*)qkv, 1632, 544, 13, 1);
        fattn_kernel<<<BB*NHH, 256, 0, stream>>>(
            (const unsigned short*)qkv, at_scaling + d, xr);
        mgemm_kernel<<<CH*5, 256, 0, stream>>>(
            (const unsigned short*)xr, wp, proj_b + d*EE,
            xe, nullptr, 544, 544, 5, 2);
        ln_row_kernel<<<ROWS/4, 256, 0, stream>>>(xe, blk2_g + d*EE, blk2_b + d*EE, xa, 1e-6f);
        mgemm_kernel<<<CH*9, 256, 0, stream>>>(
            (const unsigned short*)xa, w1, fc1_b + d*HIDD,
            nullptr, (unsigned short*)qkv, 1088, 544, 9, 3);   // hm into qkv region
        mgemm_kernel<<<CH*5, 256, 0, stream>>>(
            (const unsigned short*)qkv, w2, fc2_b + d*EE,
            xe, nullptr, 544, 1088, 5, 2);
    }
    ln_row_kernel<<<ROWS/4, 256, 0, stream>>>(xe, fin_g, fin_b, xa, 1e-6f);
    wconvT_kernel<<<dim3(4, 17), 256, 0, stream>>>(head_w, wq, 51, 544, 128);
    mgemm_kernel<<<CH*1, 256, 0, stream>>>(
        (const unsigned short*)xa, wq, head_b,
        (float*)d_out, nullptr, 51, 544, 1, 4);
}